// Round 1
// baseline (8163.486 us; speedup 1.0000x reference)
//
#include <hip/hip_runtime.h>
#include <math.h>

// MicroEncoder: 4-layer bidirectional Mamba2.
// B=8, L=2048, D_MODEL=256, D_INNER=512, NHEADS=8, HEADDIM=64, D_STATE=64,
// CONV_DIM=640, D_IN_PROJ=1160.
// Round 0: full fp32, correctness-first baseline.

#define L_SEQ 2048

__device__ __forceinline__ float siluf(float x) { return x / (1.f + expf(-x)); }

// ---------------------------------------------------------------------------
// Generic fp32 GEMM: C = A(row-remapped) @ W^T.
// A: M x K row-major with leading dim lda; rows are logical (b*2048 + t); if
// arev, the A row actually read is (b*2048 + (2047-t)) (time reversal).
// W: N x K row-major.
// mode 0: in_proj epilogue -> split into z (512) / xbc (640) / dtraw (8).
// mode 1: out_proj epilogue -> write/accumulate to Cout (ldc=256), with
//         optional time-reversed row write (crev).
// BM=BN=128, BK=16, 256 threads, 8x8 microtile (4+4 split to dodge bank conflicts).
// ---------------------------------------------------------------------------
__global__ __launch_bounds__(256) void k_gemm(
    const float* __restrict__ A, int lda, int arev,
    const float* __restrict__ W, int N, int K,
    int mode,
    float* __restrict__ zb, float* __restrict__ xbc, float* __restrict__ dtraw,
    float* __restrict__ Cout, int crev, int accflag)
{
  __shared__ float As[16][128];
  __shared__ float Bs[16][128];
  const int tid = threadIdx.x;
  const int m0 = blockIdx.x * 128, n0 = blockIdx.y * 128;
  const int lr = tid >> 1;
  const int kc = (tid & 1) << 3;
  const int mrow = m0 + lr;
  const int bb = mrow >> 11, tt = mrow & 2047;
  const int tphys = arev ? (2047 - tt) : tt;
  const float* Arow = A + (size_t)((bb << 11) + tphys) * lda;
  const int wr = n0 + lr;
  const float* Wrow = W + (size_t)wr * K;
  const int tm = tid & 15, tn = tid >> 4;
  float acc[8][8];
#pragma unroll
  for (int i = 0; i < 8; ++i)
#pragma unroll
    for (int j = 0; j < 8; ++j) acc[i][j] = 0.f;

  for (int k0 = 0; k0 < K; k0 += 16) {
    const float4 a0 = *(const float4*)(Arow + k0 + kc);
    const float4 a1 = *(const float4*)(Arow + k0 + kc + 4);
    float4 b0 = make_float4(0.f, 0.f, 0.f, 0.f);
    float4 b1 = make_float4(0.f, 0.f, 0.f, 0.f);
    if (wr < N) {
      b0 = *(const float4*)(Wrow + k0 + kc);
      b1 = *(const float4*)(Wrow + k0 + kc + 4);
    }
    __syncthreads();
    As[kc + 0][lr] = a0.x; As[kc + 1][lr] = a0.y;
    As[kc + 2][lr] = a0.z; As[kc + 3][lr] = a0.w;
    As[kc + 4][lr] = a1.x; As[kc + 5][lr] = a1.y;
    As[kc + 6][lr] = a1.z; As[kc + 7][lr] = a1.w;
    Bs[kc + 0][lr] = b0.x; Bs[kc + 1][lr] = b0.y;
    Bs[kc + 2][lr] = b0.z; Bs[kc + 3][lr] = b0.w;
    Bs[kc + 4][lr] = b1.x; Bs[kc + 5][lr] = b1.y;
    Bs[kc + 6][lr] = b1.z; Bs[kc + 7][lr] = b1.w;
    __syncthreads();
#pragma unroll
    for (int kk = 0; kk < 16; ++kk) {
      const float4 av0 = *(const float4*)&As[kk][tm * 4];
      const float4 av1 = *(const float4*)&As[kk][tm * 4 + 64];
      const float4 bv0 = *(const float4*)&Bs[kk][tn * 4];
      const float4 bv1 = *(const float4*)&Bs[kk][tn * 4 + 64];
      const float am[8] = {av0.x, av0.y, av0.z, av0.w, av1.x, av1.y, av1.z, av1.w};
      const float bn_[8] = {bv0.x, bv0.y, bv0.z, bv0.w, bv1.x, bv1.y, bv1.z, bv1.w};
#pragma unroll
      for (int i = 0; i < 8; ++i)
#pragma unroll
        for (int j = 0; j < 8; ++j)
          acc[i][j] = fmaf(am[i], bn_[j], acc[i][j]);
    }
  }
#pragma unroll
  for (int i = 0; i < 8; ++i) {
    const int mi = m0 + tm * 4 + (i & 3) + ((i >> 2) << 6);
    const int b2 = mi >> 11, t2 = mi & 2047;
#pragma unroll
    for (int j = 0; j < 8; ++j) {
      const int cj = n0 + tn * 4 + (j & 3) + ((j >> 2) << 6);
      if (cj >= N) continue;
      const float v = acc[i][j];
      if (mode == 0) {
        if (cj < 512)       zb[(size_t)mi * 512 + cj] = v;
        else if (cj < 1152) xbc[(size_t)mi * 640 + (cj - 512)] = v;
        else                dtraw[(size_t)mi * 8 + (cj - 1152)] = v;
      } else {
        const int tw = crev ? (2047 - t2) : t2;
        const size_t idx = ((size_t)((b2 << 11) + tw)) * 256 + cj;
        if (accflag) Cout[idx] += v; else Cout[idx] = v;
      }
    }
  }
}

// dt = softplus(dtraw + dt_bias); dA = exp(-dt * exp(A_log))
__global__ __launch_bounds__(256) void k_dt(
    const float* __restrict__ dtraw, const float* __restrict__ dt_bias,
    const float* __restrict__ A_log, float* __restrict__ dt,
    float* __restrict__ dA)
{
  const int i = blockIdx.x * 256 + threadIdx.x;  // < 8*2048*8
  const int h = i & 7;
  const float v = dtraw[i] + dt_bias[h];
  const float sp = (v > 20.f) ? v : log1pf(expf(v));
  dt[i] = sp;
  dA[i] = expf(-sp * expf(A_log[h]));
}

// causal depthwise conv (k=4) + bias + silu
__global__ __launch_bounds__(256) void k_conv(
    const float* __restrict__ xbc, const float* __restrict__ Wc,
    const float* __restrict__ bc, float* __restrict__ xcout)
{
  const int idx = blockIdx.x * 256 + threadIdx.x;  // < 8*2048*640
  const int c = idx % 640;
  const int rowbase = idx / 640;       // b*2048 + l
  const int l = rowbase & 2047;
  float acc = bc[c];
#pragma unroll
  for (int k = 0; k < 4; ++k) {
    const int lt = l - 3 + k;
    if (lt >= 0) acc += xbc[(size_t)(rowbase - 3 + k) * 640 + c] * Wc[c * 4 + k];
  }
  xcout[idx] = siluf(acc);
}

// Selective scan, fused with +Dp*x and silu(z) gating. In-place: reads the
// conv-activated x from xc[.., 0:512], writes the gated y back to the same
// slots. One block per (b, h, p-quarter): 16 p's, 256 threads (16 p x 16 n-grp).
__global__ __launch_bounds__(256) void k_scan(
    float* __restrict__ xc, const float* __restrict__ z,
    const float* __restrict__ dt, const float* __restrict__ dA,
    const float* __restrict__ Dp)
{
  const int blk = blockIdx.x;              // B*H*4 = 256
  const int pb = blk & 3, h = (blk >> 2) & 7, b = blk >> 5;
  const int tid = threadIdx.x;
  const int pl = tid >> 4, ng = tid & 15, n0 = ng << 2;
  __shared__ float Bsh[32][64], Csh[32][64], xsh[32][16], zsh[32][16];
  __shared__ float dts[32], das[32];
  float h0 = 0.f, h1 = 0.f, h2 = 0.f, h3 = 0.f;
  const float dpv = Dp[h];
  const size_t baseRow = (size_t)b * 2048;
  const int cx = h * 64 + pb * 16;
  for (int tc = 0; tc < 2048; tc += 32) {
    for (int f = tid; f < 2048; f += 256) {
      const int t = f >> 6, n = f & 63;
      const size_t r = baseRow + tc + t;
      Bsh[t][n] = xc[r * 640 + 512 + n];
      Csh[t][n] = xc[r * 640 + 576 + n];
    }
    for (int f = tid; f < 512; f += 256) {
      const int t = f >> 4, pp = f & 15;
      const size_t r = baseRow + tc + t;
      xsh[t][pp] = xc[r * 640 + cx + pp];
      zsh[t][pp] = z[r * 512 + cx + pp];
    }
    if (tid < 32) {
      const size_t r = baseRow + tc + tid;
      dts[tid] = dt[r * 8 + h];
      das[tid] = dA[r * 8 + h];
    }
    __syncthreads();
    for (int t = 0; t < 32; ++t) {
      const float4 Bv = *(const float4*)&Bsh[t][n0];
      const float4 Cv = *(const float4*)&Csh[t][n0];
      const float xv = xsh[t][pl];
      const float s = dts[t] * xv;
      const float da = das[t];
      h0 = fmaf(da, h0, s * Bv.x);
      h1 = fmaf(da, h1, s * Bv.y);
      h2 = fmaf(da, h2, s * Bv.z);
      h3 = fmaf(da, h3, s * Bv.w);
      float yp = h0 * Cv.x + h1 * Cv.y + h2 * Cv.z + h3 * Cv.w;
      yp += __shfl_xor(yp, 1);
      yp += __shfl_xor(yp, 2);
      yp += __shfl_xor(yp, 4);
      yp += __shfl_xor(yp, 8);
      if (ng == 0) {
        const float yv = yp + dpv * xv;
        const float zv = zsh[t][pl];
        xc[(baseRow + tc + t) * 640 + cx + pl] = yv * siluf(zv);
      }
    }
    __syncthreads();
  }
}

// RMSNorm over the 512-wide gated y living in xc[.., 0:512] (stride 640), in place.
__global__ __launch_bounds__(256) void k_rms(
    float* __restrict__ xc, const float* __restrict__ w)
{
  const int row = blockIdx.x;              // B*L
  float* y = xc + (size_t)row * 640;
  const int tid = threadIdx.x;
  const float v0 = y[tid], v1 = y[tid + 256];
  float ss = v0 * v0 + v1 * v1;
#pragma unroll
  for (int o = 32; o > 0; o >>= 1) ss += __shfl_xor(ss, o);
  __shared__ float red[4];
  if ((tid & 63) == 0) red[tid >> 6] = ss;
  __syncthreads();
  const float tot = red[0] + red[1] + red[2] + red[3];
  const float sc = rsqrtf(tot * (1.f / 512.f) + 1e-5f);
  y[tid]       = v0 * sc * w[tid];
  y[tid + 256] = v1 * sc * w[tid + 256];
}

// H = mean over L of (h_fwd + h_bwd): two-stage deterministic reduction.
__global__ __launch_bounds__(256) void k_hpart(
    const float* __restrict__ hf, const float* __restrict__ hb,
    float* __restrict__ part)
{
  const int g = blockIdx.x;        // B*32
  const int b = g >> 5, seg = g & 31;
  const int m = threadIdx.x;
  float s = 0.f;
  for (int l = seg * 64; l < seg * 64 + 64; ++l) {
    const size_t idx = ((size_t)b * 2048 + l) * 256 + m;
    s += hf[idx] + hb[idx];
  }
  part[(size_t)g * 256 + m] = s;
}

__global__ __launch_bounds__(256) void k_hfinal(
    const float* __restrict__ part, float* __restrict__ H)
{
  const int b = blockIdx.x;
  const int m = threadIdx.x;
  float s = 0.f;
  for (int g = 0; g < 32; ++g) s += part[(size_t)(b * 32 + g) * 256 + m];
  H[b * 256 + m] = s * (1.f / 2048.f);
}

extern "C" void kernel_launch(void* const* d_in, const int* in_sizes, int n_in,
                              void* d_out, int out_size, void* d_ws, size_t ws_size,
                              hipStream_t stream) {
  const float* x_in = (const float*)d_in[0];
  const float* Win[2]    = {(const float*)d_in[1],  (const float*)d_in[9]};
  const float* Wconv[2]  = {(const float*)d_in[2],  (const float*)d_in[10]};
  const float* bconv[2]  = {(const float*)d_in[3],  (const float*)d_in[11]};
  const float* dtbias[2] = {(const float*)d_in[4],  (const float*)d_in[12]};
  const float* Alog[2]   = {(const float*)d_in[5],  (const float*)d_in[13]};
  const float* Dpar[2]   = {(const float*)d_in[6],  (const float*)d_in[14]};
  const float* normw[2]  = {(const float*)d_in[7],  (const float*)d_in[15]};
  const float* Wout[2]   = {(const float*)d_in[8],  (const float*)d_in[16]};

  float* ws = (float*)d_ws;
  float* zb     = ws;                                    //  8,388,608
  float* xbcraw = zb     + (size_t)8 * 2048 * 512;       // 10,485,760
  float* xc     = xbcraw + (size_t)8 * 2048 * 640;       // 10,485,760
  float* dtraw  = xc     + (size_t)8 * 2048 * 640;       //    131,072
  float* dtb    = dtraw  + (size_t)8 * 2048 * 8;
  float* dab    = dtb    + (size_t)8 * 2048 * 8;
  float* xA     = dab    + (size_t)8 * 2048 * 8;         //  4,194,304
  float* xB     = xA     + (size_t)8 * 2048 * 256;       //  4,194,304
  float* part   = xB     + (size_t)8 * 2048 * 256;       //     65,536
  // total ~38.2M floats = ~153 MB

  float* hF = (float*)d_out;
  float* hB = hF + (size_t)8 * 2048 * 256;
  float* Hm = hB + (size_t)8 * 2048 * 256;

  const float* cur = x_in;
  for (int layer = 0; layer < 4; ++layer) {
    float* nxt = (layer == 0) ? xA : (layer == 1) ? xB : (layer == 2) ? xA : nullptr;
    for (int dir = 0; dir < 2; ++dir) {
      const float* Wi = Win[dir]    + (size_t)layer * 1160 * 256;
      const float* Wc = Wconv[dir]  + (size_t)layer * 640 * 4;
      const float* bc = bconv[dir]  + (size_t)layer * 640;
      const float* db = dtbias[dir] + (size_t)layer * 8;
      const float* Al = Alog[dir]   + (size_t)layer * 8;
      const float* Dl = Dpar[dir]   + (size_t)layer * 8;
      const float* nw = normw[dir]  + (size_t)layer * 512;
      const float* Wo = Wout[dir]   + (size_t)layer * 256 * 512;

      dim3 g1(128, 10);
      k_gemm<<<g1, 256, 0, stream>>>(cur, 256, dir, Wi, 1160, 256, 0,
                                     zb, xbcraw, dtraw, nullptr, 0, 0);
      k_dt<<<512, 256, 0, stream>>>(dtraw, db, Al, dtb, dab);
      k_conv<<<40960, 256, 0, stream>>>(xbcraw, Wc, bc, xc);
      k_scan<<<256, 256, 0, stream>>>(xc, zb, dtb, dab, Dl);
      k_rms<<<16384, 256, 0, stream>>>(xc, nw);
      float* outp;
      int accf;
      if (layer < 3) { outp = nxt; accf = dir; }
      else           { outp = dir ? hB : hF; accf = 0; }
      dim3 g2(128, 2);
      k_gemm<<<g2, 256, 0, stream>>>(xc, 640, 0, Wo, 256, 512, 1,
                                     nullptr, nullptr, nullptr, outp, dir, accf);
    }
    cur = nxt;
  }
  k_hpart<<<256, 256, 0, stream>>>(hF, hB, part);
  k_hfinal<<<8, 256, 0, stream>>>(part, Hm);
}

// Round 2
// 3646.847 us; speedup vs baseline: 2.2385x; 2.2385x over previous
//
#include <hip/hip_runtime.h>
#include <math.h>

// MicroEncoder: 4-layer bidirectional Mamba2.
// B=8, L=2048, D_MODEL=256, D_INNER=512, NHEADS=8, HEADDIM=64, D_STATE=64,
// CONV_DIM=640, D_IN_PROJ=1160.
// Round 1: chunked SSD scan (Tc=64) replaces the sequential scan.
//   Pass1: per-chunk local matmuls (G=C.B^T, decay mask, Y_local, state contrib)
//   Pass2: cross-chunk scalar-decay state propagation
//   Pass3: add incoming-state term + Dp*x + silu(z) gating
// All fp32.

#define TC 64
#define NC 32   // 2048 / TC

__device__ __forceinline__ float siluf(float x) { return x / (1.f + expf(-x)); }

// ---------------------------------------------------------------------------
// Generic fp32 GEMM: C = A(row-remapped) @ W^T.  (unchanged from round 0)
// ---------------------------------------------------------------------------
__global__ __launch_bounds__(256) void k_gemm(
    const float* __restrict__ A, int lda, int arev,
    const float* __restrict__ W, int N, int K,
    int mode,
    float* __restrict__ zb, float* __restrict__ xbc, float* __restrict__ dtraw,
    float* __restrict__ Cout, int crev, int accflag)
{
  __shared__ float As[16][128];
  __shared__ float Bs[16][128];
  const int tid = threadIdx.x;
  const int m0 = blockIdx.x * 128, n0 = blockIdx.y * 128;
  const int lr = tid >> 1;
  const int kc = (tid & 1) << 3;
  const int mrow = m0 + lr;
  const int bb = mrow >> 11, tt = mrow & 2047;
  const int tphys = arev ? (2047 - tt) : tt;
  const float* Arow = A + (size_t)((bb << 11) + tphys) * lda;
  const int wr = n0 + lr;
  const float* Wrow = W + (size_t)wr * K;
  const int tm = tid & 15, tn = tid >> 4;
  float acc[8][8];
#pragma unroll
  for (int i = 0; i < 8; ++i)
#pragma unroll
    for (int j = 0; j < 8; ++j) acc[i][j] = 0.f;

  for (int k0 = 0; k0 < K; k0 += 16) {
    const float4 a0 = *(const float4*)(Arow + k0 + kc);
    const float4 a1 = *(const float4*)(Arow + k0 + kc + 4);
    float4 b0 = make_float4(0.f, 0.f, 0.f, 0.f);
    float4 b1 = make_float4(0.f, 0.f, 0.f, 0.f);
    if (wr < N) {
      b0 = *(const float4*)(Wrow + k0 + kc);
      b1 = *(const float4*)(Wrow + k0 + kc + 4);
    }
    __syncthreads();
    As[kc + 0][lr] = a0.x; As[kc + 1][lr] = a0.y;
    As[kc + 2][lr] = a0.z; As[kc + 3][lr] = a0.w;
    As[kc + 4][lr] = a1.x; As[kc + 5][lr] = a1.y;
    As[kc + 6][lr] = a1.z; As[kc + 7][lr] = a1.w;
    Bs[kc + 0][lr] = b0.x; Bs[kc + 1][lr] = b0.y;
    Bs[kc + 2][lr] = b0.z; Bs[kc + 3][lr] = b0.w;
    Bs[kc + 4][lr] = b1.x; Bs[kc + 5][lr] = b1.y;
    Bs[kc + 6][lr] = b1.z; Bs[kc + 7][lr] = b1.w;
    __syncthreads();
#pragma unroll
    for (int kk = 0; kk < 16; ++kk) {
      const float4 av0 = *(const float4*)&As[kk][tm * 4];
      const float4 av1 = *(const float4*)&As[kk][tm * 4 + 64];
      const float4 bv0 = *(const float4*)&Bs[kk][tn * 4];
      const float4 bv1 = *(const float4*)&Bs[kk][tn * 4 + 64];
      const float am[8] = {av0.x, av0.y, av0.z, av0.w, av1.x, av1.y, av1.z, av1.w};
      const float bn_[8] = {bv0.x, bv0.y, bv0.z, bv0.w, bv1.x, bv1.y, bv1.z, bv1.w};
#pragma unroll
      for (int i = 0; i < 8; ++i)
#pragma unroll
        for (int j = 0; j < 8; ++j)
          acc[i][j] = fmaf(am[i], bn_[j], acc[i][j]);
    }
  }
#pragma unroll
  for (int i = 0; i < 8; ++i) {
    const int mi = m0 + tm * 4 + (i & 3) + ((i >> 2) << 6);
    const int b2 = mi >> 11, t2 = mi & 2047;
#pragma unroll
    for (int j = 0; j < 8; ++j) {
      const int cj = n0 + tn * 4 + (j & 3) + ((j >> 2) << 6);
      if (cj >= N) continue;
      const float v = acc[i][j];
      if (mode == 0) {
        if (cj < 512)       zb[(size_t)mi * 512 + cj] = v;
        else if (cj < 1152) xbc[(size_t)mi * 640 + (cj - 512)] = v;
        else                dtraw[(size_t)mi * 8 + (cj - 1152)] = v;
      } else {
        const int tw = crev ? (2047 - t2) : t2;
        const size_t idx = ((size_t)((b2 << 11) + tw)) * 256 + cj;
        if (accflag) Cout[idx] += v; else Cout[idx] = v;
      }
    }
  }
}

// dt = softplus(dtraw + dt_bias); dtA = dt * exp(A_log)   (NOTE: dtA, not dA)
__global__ __launch_bounds__(256) void k_dt(
    const float* __restrict__ dtraw, const float* __restrict__ dt_bias,
    const float* __restrict__ A_log, float* __restrict__ dt,
    float* __restrict__ dtA)
{
  const int i = blockIdx.x * 256 + threadIdx.x;  // < 8*2048*8
  const int h = i & 7;
  const float v = dtraw[i] + dt_bias[h];
  const float sp = (v > 20.f) ? v : log1pf(expf(v));
  dt[i] = sp;
  dtA[i] = sp * expf(A_log[h]);
}

// causal depthwise conv (k=4) + bias + silu
__global__ __launch_bounds__(256) void k_conv(
    const float* __restrict__ xbc, const float* __restrict__ Wc,
    const float* __restrict__ bc, float* __restrict__ xcout)
{
  const int idx = blockIdx.x * 256 + threadIdx.x;  // < 8*2048*640
  const int c = idx % 640;
  const int rowbase = idx / 640;       // b*2048 + l
  const int l = rowbase & 2047;
  float acc = bc[c];
#pragma unroll
  for (int k = 0; k < 4; ++k) {
    const int lt = l - 3 + k;
    if (lt >= 0) acc += xbc[(size_t)(rowbase - 3 + k) * 640 + c] * Wc[c * 4 + k];
  }
  xcout[idx] = siluf(acc);
}

// ---------------------------------------------------------------------------
// Chunked SSD pass 1. One block per (b, h, chunk): 8*8*32 = 2048 blocks.
// Computes, within the chunk (local time i,j in [0,64)):
//   S_i  = inclusive prefix sum of dtA   (log-space decay)
//   G_ij = C_i . B_j ;  Gw_ij = (j<=i) ? exp(S_j-S_i)*dt_j*G_ij : 0
//   Ylocal[i,p] = sum_j Gw_ij * x_j[p]  (+ Dp*x, written in place to xc)
//   contrib[p,n] = sum_j exp(S_j-S_last)*dt_j * x_j[p] * B_j[n]
//   PT[chunk] = exp(-S_last), Sbuf[t] = S_i
// ---------------------------------------------------------------------------
__global__ __launch_bounds__(256) void k_scan1(
    float* __restrict__ xc, const float* __restrict__ dt,
    const float* __restrict__ dtA, const float* __restrict__ Dp,
    float* __restrict__ contrib, float* __restrict__ Sbuf,
    float* __restrict__ PT)
{
  const int c = blockIdx.x & (NC - 1);
  const int bh = blockIdx.x >> 5;
  const int b = bh >> 3, h = bh & 7;
  const int tid = threadIdx.x;
  const int r0 = b * 2048 + c * TC;
  const int hbase = h * 64;
  __shared__ float Bs[64][65], Cs[64][65], Xs[64][65], Gw[64][65];
  __shared__ float Ssh[64], dtsh[64], vsh[64];

  for (int f = tid; f < 1024; f += 256) {
    const int i = f >> 4, q = (f & 15) << 2;
    const float* rowp = xc + (size_t)(r0 + i) * 640;
    const float4 bv = *(const float4*)(rowp + 512 + q);
    const float4 cv = *(const float4*)(rowp + 576 + q);
    const float4 xv = *(const float4*)(rowp + hbase + q);
    Bs[i][q] = bv.x; Bs[i][q + 1] = bv.y; Bs[i][q + 2] = bv.z; Bs[i][q + 3] = bv.w;
    Cs[i][q] = cv.x; Cs[i][q + 1] = cv.y; Cs[i][q + 2] = cv.z; Cs[i][q + 3] = cv.w;
    Xs[i][q] = xv.x; Xs[i][q + 1] = xv.y; Xs[i][q + 2] = xv.z; Xs[i][q + 3] = xv.w;
  }
  if (tid < 64) {
    float a = dtA[(size_t)(r0 + tid) * 8 + h];
    const float d = dt[(size_t)(r0 + tid) * 8 + h];
#pragma unroll
    for (int off = 1; off < 64; off <<= 1) {
      const float t = __shfl_up(a, off);
      if (tid >= off) a += t;
    }
    const float slast = __shfl(a, 63);
    Ssh[tid] = a;
    dtsh[tid] = d;
    vsh[tid] = expf(a - slast) * d;
    Sbuf[(size_t)bh * 2048 + c * TC + tid] = a;
    if (tid == 63) PT[bh * NC + c] = expf(-slast);
  }
  __syncthreads();

  const int i = tid >> 2, j0 = tid & 3;

  // --- G = C.B^T, then decay-mask ---
  float accG[16];
#pragma unroll
  for (int k = 0; k < 16; ++k) accG[k] = 0.f;
  for (int n = 0; n < 64; ++n) {
    const float ci = Cs[i][n];
#pragma unroll
    for (int k = 0; k < 16; ++k) accG[k] = fmaf(ci, Bs[j0 + 4 * k][n], accG[k]);
  }
  const float si = Ssh[i];
#pragma unroll
  for (int k = 0; k < 16; ++k) {
    const int j = j0 + 4 * k;
    const float w = (j <= i) ? expf(Ssh[j] - si) * dtsh[j] : 0.f;
    Gw[i][j] = accG[k] * w;
  }
  __syncthreads();

  // --- Ylocal = Gw . X  (+ Dp*x) ---
  const float dpv = Dp[h];
  float accY[16];
#pragma unroll
  for (int k = 0; k < 16; ++k) accY[k] = 0.f;
  for (int jj = 0; jj < 64; ++jj) {
    const float g = Gw[i][jj];
#pragma unroll
    for (int k = 0; k < 16; ++k) accY[k] = fmaf(g, Xs[jj][j0 + 4 * k], accY[k]);
  }
  __syncthreads();                 // Gw free; reuse as Y staging
#pragma unroll
  for (int k = 0; k < 16; ++k) {
    const int p = j0 + 4 * k;
    Gw[i][p] = accY[k] + dpv * Xs[i][p];
  }
  __syncthreads();
  for (int f = tid; f < 1024; f += 256) {
    const int ii = f >> 4, q = (f & 15) << 2;
    const float4 yv = make_float4(Gw[ii][q], Gw[ii][q + 1], Gw[ii][q + 2], Gw[ii][q + 3]);
    *(float4*)(xc + (size_t)(r0 + ii) * 640 + hbase + q) = yv;
  }

  // --- contrib[p,n] = sum_j v_j * x_j[p] * B_j[n] ---
  const int p = i;
  float accC[16];
#pragma unroll
  for (int k = 0; k < 16; ++k) accC[k] = 0.f;
  for (int jj = 0; jj < 64; ++jj) {
    const float t = vsh[jj] * Xs[jj][p];
#pragma unroll
    for (int k = 0; k < 16; ++k) accC[k] = fmaf(t, Bs[jj][j0 + 4 * k], accC[k]);
  }
  __syncthreads();                 // Cs free; reuse as contrib staging
#pragma unroll
  for (int k = 0; k < 16; ++k) Cs[p][j0 + 4 * k] = accC[k];
  __syncthreads();
  float* cbase = contrib + (((size_t)(bh * NC + c)) << 12);
  for (int f = tid; f < 1024; f += 256) {
    const int pp = f >> 4, q = (f & 15) << 2;
    const float4 cv = make_float4(Cs[pp][q], Cs[pp][q + 1], Cs[pp][q + 2], Cs[pp][q + 3]);
    *(float4*)(cbase + pp * 64 + q) = cv;
  }
}

// ---------------------------------------------------------------------------
// Pass 2: cross-chunk state propagation. In-place exclusive scan over chunks:
// contrib[c] (local) -> h_in[c];  h_in[c+1] = PT[c]*h_in[c] + local[c].
// Grid: 64 bh * 4 quarters = 256 blocks.
// ---------------------------------------------------------------------------
__global__ __launch_bounds__(256) void k_scan2(
    float* __restrict__ contrib, const float* __restrict__ PT)
{
  const int bh = blockIdx.x >> 2, qr = blockIdx.x & 3;
  const int tid = threadIdx.x;
  float hv[4] = {0.f, 0.f, 0.f, 0.f};
  for (int c = 0; c < NC; ++c) {
    float* base = contrib + (((size_t)(bh * NC + c)) << 12) + (qr << 10);
    const float pt = PT[bh * NC + c];
#pragma unroll
    for (int k = 0; k < 4; ++k) {
      const int idx = tid + (k << 8);
      const float tmp = base[idx];
      base[idx] = hv[k];
      hv[k] = fmaf(pt, hv[k], tmp);
    }
  }
}

// ---------------------------------------------------------------------------
// Pass 3: y[i,p] = ylocal[i,p] + exp(-S_i) * sum_n h_in[p,n]*C_i[n],
// then gate with silu(z). In place over xc's x region.
// ---------------------------------------------------------------------------
__global__ __launch_bounds__(256) void k_scan3(
    float* __restrict__ xc, const float* __restrict__ z,
    const float* __restrict__ hin, const float* __restrict__ Sbuf)
{
  const int c = blockIdx.x & (NC - 1);
  const int bh = blockIdx.x >> 5;
  const int b = bh >> 3, h = bh & 7;
  const int tid = threadIdx.x;
  const int r0 = b * 2048 + c * TC;
  const int hbase = h * 64;
  __shared__ float Hs[64][65], Cs[64][65];
  __shared__ float Esh[64];
  const float* hp = hin + (((size_t)(bh * NC + c)) << 12);
  for (int f = tid; f < 1024; f += 256) {
    const int p2 = f >> 4, q = (f & 15) << 2;
    const float4 hv = *(const float4*)(hp + p2 * 64 + q);
    Hs[p2][q] = hv.x; Hs[p2][q + 1] = hv.y; Hs[p2][q + 2] = hv.z; Hs[p2][q + 3] = hv.w;
    const float4 cv = *(const float4*)(xc + (size_t)(r0 + p2) * 640 + 576 + q);
    Cs[p2][q] = cv.x; Cs[p2][q + 1] = cv.y; Cs[p2][q + 2] = cv.z; Cs[p2][q + 3] = cv.w;
  }
  if (tid < 64) Esh[tid] = expf(-Sbuf[(size_t)bh * 2048 + c * TC + tid]);
  __syncthreads();
  const int i = tid >> 2, j0 = tid & 3;
  float acc[16];
#pragma unroll
  for (int k = 0; k < 16; ++k) acc[k] = 0.f;
  for (int n = 0; n < 64; ++n) {
    const float ci = Cs[i][n];
#pragma unroll
    for (int k = 0; k < 16; ++k) acc[k] = fmaf(ci, Hs[j0 + 4 * k][n], acc[k]);
  }
  const float ei = Esh[i];
  __syncthreads();                 // Cs free; stage state term (transposed: [i][p])
#pragma unroll
  for (int k = 0; k < 16; ++k) Cs[i][j0 + 4 * k] = acc[k] * ei;
  __syncthreads();
  for (int f = tid; f < 1024; f += 256) {
    const int ii = f >> 4, q = (f & 15) << 2;
    float* yp = xc + (size_t)(r0 + ii) * 640 + hbase + q;
    const float4 yl = *(const float4*)yp;
    const float4 zv = *(const float4*)(z + (size_t)(r0 + ii) * 512 + hbase + q);
    float4 o;
    o.x = (yl.x + Cs[ii][q + 0]) * siluf(zv.x);
    o.y = (yl.y + Cs[ii][q + 1]) * siluf(zv.y);
    o.z = (yl.z + Cs[ii][q + 2]) * siluf(zv.z);
    o.w = (yl.w + Cs[ii][q + 3]) * siluf(zv.w);
    *(float4*)yp = o;
  }
}

// RMSNorm over the 512-wide gated y living in xc[.., 0:512] (stride 640), in place.
__global__ __launch_bounds__(256) void k_rms(
    float* __restrict__ xc, const float* __restrict__ w)
{
  const int row = blockIdx.x;              // B*L
  float* y = xc + (size_t)row * 640;
  const int tid = threadIdx.x;
  const float v0 = y[tid], v1 = y[tid + 256];
  float ss = v0 * v0 + v1 * v1;
#pragma unroll
  for (int o = 32; o > 0; o >>= 1) ss += __shfl_xor(ss, o);
  __shared__ float red[4];
  if ((tid & 63) == 0) red[tid >> 6] = ss;
  __syncthreads();
  const float tot = red[0] + red[1] + red[2] + red[3];
  const float sc = rsqrtf(tot * (1.f / 512.f) + 1e-5f);
  y[tid]       = v0 * sc * w[tid];
  y[tid + 256] = v1 * sc * w[tid + 256];
}

// H = mean over L of (h_fwd + h_bwd): two-stage deterministic reduction.
__global__ __launch_bounds__(256) void k_hpart(
    const float* __restrict__ hf, const float* __restrict__ hb,
    float* __restrict__ part)
{
  const int g = blockIdx.x;        // B*32
  const int b = g >> 5, seg = g & 31;
  const int m = threadIdx.x;
  float s = 0.f;
  for (int l = seg * 64; l < seg * 64 + 64; ++l) {
    const size_t idx = ((size_t)b * 2048 + l) * 256 + m;
    s += hf[idx] + hb[idx];
  }
  part[(size_t)g * 256 + m] = s;
}

__global__ __launch_bounds__(256) void k_hfinal(
    const float* __restrict__ part, float* __restrict__ H)
{
  const int b = blockIdx.x;
  const int m = threadIdx.x;
  float s = 0.f;
  for (int g = 0; g < 32; ++g) s += part[(size_t)(b * 32 + g) * 256 + m];
  H[b * 256 + m] = s * (1.f / 2048.f);
}

extern "C" void kernel_launch(void* const* d_in, const int* in_sizes, int n_in,
                              void* d_out, int out_size, void* d_ws, size_t ws_size,
                              hipStream_t stream) {
  const float* x_in = (const float*)d_in[0];
  const float* Win[2]    = {(const float*)d_in[1],  (const float*)d_in[9]};
  const float* Wconv[2]  = {(const float*)d_in[2],  (const float*)d_in[10]};
  const float* bconv[2]  = {(const float*)d_in[3],  (const float*)d_in[11]};
  const float* dtbias[2] = {(const float*)d_in[4],  (const float*)d_in[12]};
  const float* Alog[2]   = {(const float*)d_in[5],  (const float*)d_in[13]};
  const float* Dpar[2]   = {(const float*)d_in[6],  (const float*)d_in[14]};
  const float* normw[2]  = {(const float*)d_in[7],  (const float*)d_in[15]};
  const float* Wout[2]   = {(const float*)d_in[8],  (const float*)d_in[16]};

  float* ws = (float*)d_ws;
  float* zb     = ws;                                    //  8,388,608
  float* xbcraw = zb     + (size_t)8 * 2048 * 512;       // 10,485,760
  float* xc     = xbcraw + (size_t)8 * 2048 * 640;       // 10,485,760
  float* dtraw  = xc     + (size_t)8 * 2048 * 640;       //    131,072
  float* dtb    = dtraw  + (size_t)8 * 2048 * 8;
  float* dab    = dtb    + (size_t)8 * 2048 * 8;
  float* xA     = dab    + (size_t)8 * 2048 * 8;         //  4,194,304
  float* xB     = xA     + (size_t)8 * 2048 * 256;       //  4,194,304
  float* part   = xB     + (size_t)8 * 2048 * 256;       //     65,536
  // total ~38.2M floats = ~153 MB
  // Reuse (per layer-dir, after the producers are done):
  //   contrib (8.4M)  -> xbcraw  (dead after k_conv)
  //   Sbuf    (131K)  -> dtraw   (dead after k_dt)
  //   PT      (2K)    -> part    (only used after the layer loop)

  float* hF = (float*)d_out;
  float* hB = hF + (size_t)8 * 2048 * 256;
  float* Hm = hB + (size_t)8 * 2048 * 256;

  const float* cur = x_in;
  for (int layer = 0; layer < 4; ++layer) {
    float* nxt = (layer == 0) ? xA : (layer == 1) ? xB : (layer == 2) ? xA : nullptr;
    for (int dir = 0; dir < 2; ++dir) {
      const float* Wi = Win[dir]    + (size_t)layer * 1160 * 256;
      const float* Wc = Wconv[dir]  + (size_t)layer * 640 * 4;
      const float* bc = bconv[dir]  + (size_t)layer * 640;
      const float* db = dtbias[dir] + (size_t)layer * 8;
      const float* Al = Alog[dir]   + (size_t)layer * 8;
      const float* Dl = Dpar[dir]   + (size_t)layer * 8;
      const float* nw = normw[dir]  + (size_t)layer * 512;
      const float* Wo = Wout[dir]   + (size_t)layer * 256 * 512;

      dim3 g1(128, 10);
      k_gemm<<<g1, 256, 0, stream>>>(cur, 256, dir, Wi, 1160, 256, 0,
                                     zb, xbcraw, dtraw, nullptr, 0, 0);
      k_dt<<<512, 256, 0, stream>>>(dtraw, db, Al, dtb, dab);
      k_conv<<<40960, 256, 0, stream>>>(xbcraw, Wc, bc, xc);
      k_scan1<<<2048, 256, 0, stream>>>(xc, dtb, dab, Dl, xbcraw, dtraw, part);
      k_scan2<<<256, 256, 0, stream>>>(xbcraw, part);
      k_scan3<<<2048, 256, 0, stream>>>(xc, zb, xbcraw, dtraw);
      k_rms<<<16384, 256, 0, stream>>>(xc, nw);
      float* outp;
      int accf;
      if (layer < 3) { outp = nxt; accf = dir; }
      else           { outp = dir ? hB : hF; accf = 0; }
      dim3 g2(128, 2);
      k_gemm<<<g2, 256, 0, stream>>>(xc, 640, 0, Wo, 256, 512, 1,
                                     nullptr, nullptr, nullptr, outp, dir, accf);
    }
    cur = nxt;
  }
  k_hpart<<<256, 256, 0, stream>>>(hF, hB, part);
  k_hfinal<<<8, 256, 0, stream>>>(part, Hm);
}

// Round 3
// 2365.985 us; speedup vs baseline: 3.4504x; 1.5414x over previous
//
#include <hip/hip_runtime.h>
#include <math.h>

// MicroEncoder: 4-layer bidirectional Mamba2.
// B=8, L=2048, D_MODEL=256, D_INNER=512, NHEADS=8, HEADDIM=64, D_STATE=64,
// CONV_DIM=640, D_IN_PROJ=1160.
// Round 2: bf16 MFMA GEMMs (16x16x32), bf16 z/xBC intermediates, vectorized
// conv. Scan pipeline stays fp32.

#define TC 64
#define NC 32

typedef __attribute__((ext_vector_type(4))) float f32x4;
typedef __attribute__((ext_vector_type(8))) short s16x8;

__device__ __forceinline__ float siluf(float x) { return x / (1.f + expf(-x)); }

// fp32 -> bf16 round-to-nearest-even (finite inputs)
__device__ __forceinline__ ushort f2b(float f) {
  union { float f; uint u; } v; v.f = f;
  return (ushort)((v.u + 0x7FFFu + ((v.u >> 16) & 1u)) >> 16);
}
__device__ __forceinline__ float b2f(ushort u) {
  union { uint u; float f; } v; v.u = ((uint)u) << 16; return v.f;
}
// LDS chunk swizzle: 16 rows x same-chunk reads land 2-way per bank (free).
__device__ __forceinline__ int swz(int r, int c) { return c ^ (r & 3) ^ ((r >> 2) & 3); }

// ---------------------------------------------------------------------------
// bf16 MFMA GEMM: C = A @ W^T.  A: fp32 MxK (lda, optional row time-reversal).
// W: fp32 NxK. 128x128 tile, BK=32, 4 waves (2x2), 4x4 16x16x32 fragments.
// mode 0 (in_proj): N-block routes to z(bf16) / xBC(bf16) / dtraw(fp32).
// mode 1 (out_proj): fp32 write/accumulate with optional reversed row write.
// ---------------------------------------------------------------------------
__global__ __launch_bounds__(256) void k_gemmb(
    const float* __restrict__ A, int lda, int arev,
    const float* __restrict__ W, int N, int K,
    int mode,
    ushort* __restrict__ zb, ushort* __restrict__ xbc, float* __restrict__ dtraw,
    float* __restrict__ Cout, int crev, int accflag)
{
  __shared__ __align__(16) ushort lds[17408];  // A[0:4096) B[4096:8192); epi C 128x136
  const int tid = threadIdx.x;
  const int lane = tid & 63;
  const int wid = tid >> 6;
  const int wr = wid >> 1, wc = wid & 1;
  const int m0 = blockIdx.x * 128, n0 = blockIdx.y * 128;

  // staging coords: thread -> (tile row, K half)
  const int tr = tid >> 1;
  const int th = tid & 1;
  const int gm = m0 + tr;
  const int bb = gm >> 11, tt = gm & 2047;
  const int tphys = arev ? (2047 - tt) : tt;
  const float* Arow = A + (size_t)((bb << 11) + tphys) * lda + th * 16;
  const int wn = n0 + tr;
  const float* Wrow = (wn < N) ? (W + (size_t)wn * K + th * 16) : nullptr;

  const int asw0 = tr * 32 + swz(tr, th * 2) * 8;
  const int asw1 = tr * 32 + swz(tr, th * 2 + 1) * 8;

  f32x4 acc[4][4];
#pragma unroll
  for (int i = 0; i < 4; ++i)
#pragma unroll
    for (int j = 0; j < 4; ++j) acc[i][j] = (f32x4){0.f, 0.f, 0.f, 0.f};

  int aoff[4], boff[4];
#pragma unroll
  for (int f = 0; f < 4; ++f) {
    const int ar = wr * 64 + f * 16 + (lane & 15);
    aoff[f] = ar * 32 + swz(ar, lane >> 4) * 8;
    const int br = wc * 64 + f * 16 + (lane & 15);
    boff[f] = 4096 + br * 32 + swz(br, lane >> 4) * 8;
  }

  float4 a0, a1, a2, a3;
  float4 b0 = make_float4(0.f, 0.f, 0.f, 0.f), b1 = b0, b2 = b0, b3 = b0;
  a0 = *(const float4*)(Arow + 0); a1 = *(const float4*)(Arow + 4);
  a2 = *(const float4*)(Arow + 8); a3 = *(const float4*)(Arow + 12);
  if (Wrow) {
    b0 = *(const float4*)(Wrow + 0); b1 = *(const float4*)(Wrow + 4);
    b2 = *(const float4*)(Wrow + 8); b3 = *(const float4*)(Wrow + 12);
  }

  for (int k0 = 0; k0 < K; k0 += 32) {
    __syncthreads();
    {
      s16x8 pa0, pa1, pb0, pb1;
      pa0[0] = (short)f2b(a0.x); pa0[1] = (short)f2b(a0.y);
      pa0[2] = (short)f2b(a0.z); pa0[3] = (short)f2b(a0.w);
      pa0[4] = (short)f2b(a1.x); pa0[5] = (short)f2b(a1.y);
      pa0[6] = (short)f2b(a1.z); pa0[7] = (short)f2b(a1.w);
      pa1[0] = (short)f2b(a2.x); pa1[1] = (short)f2b(a2.y);
      pa1[2] = (short)f2b(a2.z); pa1[3] = (short)f2b(a2.w);
      pa1[4] = (short)f2b(a3.x); pa1[5] = (short)f2b(a3.y);
      pa1[6] = (short)f2b(a3.z); pa1[7] = (short)f2b(a3.w);
      pb0[0] = (short)f2b(b0.x); pb0[1] = (short)f2b(b0.y);
      pb0[2] = (short)f2b(b0.z); pb0[3] = (short)f2b(b0.w);
      pb0[4] = (short)f2b(b1.x); pb0[5] = (short)f2b(b1.y);
      pb0[6] = (short)f2b(b1.z); pb0[7] = (short)f2b(b1.w);
      pb1[0] = (short)f2b(b2.x); pb1[1] = (short)f2b(b2.y);
      pb1[2] = (short)f2b(b2.z); pb1[3] = (short)f2b(b2.w);
      pb1[4] = (short)f2b(b3.x); pb1[5] = (short)f2b(b3.y);
      pb1[6] = (short)f2b(b3.z); pb1[7] = (short)f2b(b3.w);
      *(s16x8*)&lds[asw0] = pa0;
      *(s16x8*)&lds[asw1] = pa1;
      *(s16x8*)&lds[4096 + asw0] = pb0;
      *(s16x8*)&lds[4096 + asw1] = pb1;
    }
    __syncthreads();
    if (k0 + 32 < K) {
      const float* Ap = Arow + k0 + 32;
      a0 = *(const float4*)(Ap + 0); a1 = *(const float4*)(Ap + 4);
      a2 = *(const float4*)(Ap + 8); a3 = *(const float4*)(Ap + 12);
      if (Wrow) {
        const float* Wp = Wrow + k0 + 32;
        b0 = *(const float4*)(Wp + 0); b1 = *(const float4*)(Wp + 4);
        b2 = *(const float4*)(Wp + 8); b3 = *(const float4*)(Wp + 12);
      }
    }
    s16x8 af[4], bf[4];
#pragma unroll
    for (int f = 0; f < 4; ++f) {
      af[f] = *(const s16x8*)&lds[aoff[f]];
      bf[f] = *(const s16x8*)&lds[boff[f]];
    }
#pragma unroll
    for (int i = 0; i < 4; ++i)
#pragma unroll
      for (int j = 0; j < 4; ++j)
        acc[i][j] = __builtin_amdgcn_mfma_f32_16x16x32_bf16(af[i], bf[j], acc[i][j], 0, 0, 0);
  }

  if (mode == 0) {
    const int by = blockIdx.y;
    if (by == 9) {             // dt columns 1152..1159 only
      if (wc == 0 && (lane & 15) < 8) {
        const int cl = lane & 15;
#pragma unroll
        for (int i = 0; i < 4; ++i) {
          const int r = m0 + wr * 64 + i * 16 + (lane >> 4) * 4;
#pragma unroll
          for (int g = 0; g < 4; ++g)
            dtraw[(size_t)(r + g) * 8 + cl] = acc[i][0][g];
        }
      }
      return;
    }
    __syncthreads();           // LDS tiles dead; reuse as 128x136 bf16 C-stage
#pragma unroll
    for (int i = 0; i < 4; ++i) {
      const int r = wr * 64 + i * 16 + (lane >> 4) * 4;
#pragma unroll
      for (int j = 0; j < 4; ++j) {
        const int ccol = wc * 64 + j * 16 + (lane & 15);
#pragma unroll
        for (int g = 0; g < 4; ++g)
          lds[(r + g) * 136 + ccol] = f2b(acc[i][j][g]);
      }
    }
    __syncthreads();
    const int rr = tid >> 1, hf = tid & 1;
    const int grow = m0 + rr;
    ushort* dst; int stride, colb;
    if (by < 4) { dst = zb;  stride = 512; colb = n0; }
    else        { dst = xbc; stride = 640; colb = n0 - 512; }
    ushort* dp = dst + (size_t)grow * stride + colb + hf * 64;
    const ushort* sp = &lds[rr * 136 + hf * 64];
#pragma unroll
    for (int q = 0; q < 8; ++q)
      *(s16x8*)(dp + q * 8) = *(const s16x8*)(sp + q * 8);
  } else {
#pragma unroll
    for (int i = 0; i < 4; ++i) {
      const int rb = m0 + wr * 64 + i * 16 + (lane >> 4) * 4;
#pragma unroll
      for (int g = 0; g < 4; ++g) {
        const int row = rb + g;
        const int b2 = row >> 11, t2 = row & 2047;
        const int tw = crev ? (2047 - t2) : t2;
        float* crow = Cout + ((size_t)((b2 << 11) + tw)) * 256 + n0 + wc * 64 + (lane & 15);
#pragma unroll
        for (int j = 0; j < 4; ++j) {
          const float v = acc[i][j][g];
          if (accflag) crow[j * 16] += v; else crow[j * 16] = v;
        }
      }
    }
  }
}

// dt = softplus(dtraw + dt_bias); dtA = dt * exp(A_log)
__global__ __launch_bounds__(256) void k_dt(
    const float* __restrict__ dtraw, const float* __restrict__ dt_bias,
    const float* __restrict__ A_log, float* __restrict__ dt,
    float* __restrict__ dtA)
{
  const int i = blockIdx.x * 256 + threadIdx.x;
  const int h = i & 7;
  const float v = dtraw[i] + dt_bias[h];
  const float sp = (v > 20.f) ? v : log1pf(expf(v));
  dt[i] = sp;
  dtA[i] = sp * expf(A_log[h]);
}

// causal depthwise conv (k=4, bf16 in) + bias + silu -> fp32 xc
// grid (10, 512): 8 channel-groups x 32 rows per block.
__global__ __launch_bounds__(256) void k_conv(
    const ushort* __restrict__ xbc, const float* __restrict__ Wc,
    const float* __restrict__ bc, float* __restrict__ xc)
{
  const int t = threadIdx.x;
  const int cg = blockIdx.x * 8 + (t & 7);
  const int rowt = blockIdx.y * 32 + (t >> 3);
  const int l = rowt & 2047;
  const int c0 = cg * 8;
  float4 wv[8];
  const float4* wp = (const float4*)(Wc + c0 * 4);
#pragma unroll
  for (int e = 0; e < 8; ++e) wv[e] = wp[e];
  float acc[8];
#pragma unroll
  for (int e = 0; e < 8; ++e) acc[e] = bc[c0 + e];
#pragma unroll
  for (int k = 0; k < 4; ++k) {
    const int lt = l - 3 + k;
    if (lt < 0) continue;
    const s16x8 v = *(const s16x8*)(xbc + (size_t)(rowt - 3 + k) * 640 + c0);
#pragma unroll
    for (int e = 0; e < 8; ++e)
      acc[e] = fmaf(b2f((ushort)v[e]), ((const float*)&wv[e])[k], acc[e]);
  }
  float* op = xc + (size_t)rowt * 640 + c0;
  float4 o0, o1;
  o0.x = siluf(acc[0]); o0.y = siluf(acc[1]); o0.z = siluf(acc[2]); o0.w = siluf(acc[3]);
  o1.x = siluf(acc[4]); o1.y = siluf(acc[5]); o1.z = siluf(acc[6]); o1.w = siluf(acc[7]);
  *(float4*)op = o0; *(float4*)(op + 4) = o1;
}

// ---------------------------------------------------------------------------
// Chunked SSD pass 1 (fp32, unchanged from round 1).
// ---------------------------------------------------------------------------
__global__ __launch_bounds__(256) void k_scan1(
    float* __restrict__ xc, const float* __restrict__ dt,
    const float* __restrict__ dtA, const float* __restrict__ Dp,
    float* __restrict__ contrib, float* __restrict__ Sbuf,
    float* __restrict__ PT)
{
  const int c = blockIdx.x & (NC - 1);
  const int bh = blockIdx.x >> 5;
  const int b = bh >> 3, h = bh & 7;
  const int tid = threadIdx.x;
  const int r0 = b * 2048 + c * TC;
  const int hbase = h * 64;
  __shared__ float Bs[64][65], Cs[64][65], Xs[64][65], Gw[64][65];
  __shared__ float Ssh[64], dtsh[64], vsh[64];

  for (int f = tid; f < 1024; f += 256) {
    const int i = f >> 4, q = (f & 15) << 2;
    const float* rowp = xc + (size_t)(r0 + i) * 640;
    const float4 bv = *(const float4*)(rowp + 512 + q);
    const float4 cv = *(const float4*)(rowp + 576 + q);
    const float4 xv = *(const float4*)(rowp + hbase + q);
    Bs[i][q] = bv.x; Bs[i][q + 1] = bv.y; Bs[i][q + 2] = bv.z; Bs[i][q + 3] = bv.w;
    Cs[i][q] = cv.x; Cs[i][q + 1] = cv.y; Cs[i][q + 2] = cv.z; Cs[i][q + 3] = cv.w;
    Xs[i][q] = xv.x; Xs[i][q + 1] = xv.y; Xs[i][q + 2] = xv.z; Xs[i][q + 3] = xv.w;
  }
  if (tid < 64) {
    float a = dtA[(size_t)(r0 + tid) * 8 + h];
    const float d = dt[(size_t)(r0 + tid) * 8 + h];
#pragma unroll
    for (int off = 1; off < 64; off <<= 1) {
      const float t = __shfl_up(a, off);
      if (tid >= off) a += t;
    }
    const float slast = __shfl(a, 63);
    Ssh[tid] = a;
    dtsh[tid] = d;
    vsh[tid] = expf(a - slast) * d;
    Sbuf[(size_t)bh * 2048 + c * TC + tid] = a;
    if (tid == 63) PT[bh * NC + c] = expf(-slast);
  }
  __syncthreads();

  const int i = tid >> 2, j0 = tid & 3;

  float accG[16];
#pragma unroll
  for (int k = 0; k < 16; ++k) accG[k] = 0.f;
  for (int n = 0; n < 64; ++n) {
    const float ci = Cs[i][n];
#pragma unroll
    for (int k = 0; k < 16; ++k) accG[k] = fmaf(ci, Bs[j0 + 4 * k][n], accG[k]);
  }
  const float si = Ssh[i];
#pragma unroll
  for (int k = 0; k < 16; ++k) {
    const int j = j0 + 4 * k;
    const float w = (j <= i) ? expf(Ssh[j] - si) * dtsh[j] : 0.f;
    Gw[i][j] = accG[k] * w;
  }
  __syncthreads();

  const float dpv = Dp[h];
  float accY[16];
#pragma unroll
  for (int k = 0; k < 16; ++k) accY[k] = 0.f;
  for (int jj = 0; jj < 64; ++jj) {
    const float g = Gw[i][jj];
#pragma unroll
    for (int k = 0; k < 16; ++k) accY[k] = fmaf(g, Xs[jj][j0 + 4 * k], accY[k]);
  }
  __syncthreads();
#pragma unroll
  for (int k = 0; k < 16; ++k) {
    const int p = j0 + 4 * k;
    Gw[i][p] = accY[k] + dpv * Xs[i][p];
  }
  __syncthreads();
  for (int f = tid; f < 1024; f += 256) {
    const int ii = f >> 4, q = (f & 15) << 2;
    const float4 yv = make_float4(Gw[ii][q], Gw[ii][q + 1], Gw[ii][q + 2], Gw[ii][q + 3]);
    *(float4*)(xc + (size_t)(r0 + ii) * 640 + hbase + q) = yv;
  }

  const int p = i;
  float accC[16];
#pragma unroll
  for (int k = 0; k < 16; ++k) accC[k] = 0.f;
  for (int jj = 0; jj < 64; ++jj) {
    const float t = vsh[jj] * Xs[jj][p];
#pragma unroll
    for (int k = 0; k < 16; ++k) accC[k] = fmaf(t, Bs[jj][j0 + 4 * k], accC[k]);
  }
  __syncthreads();
#pragma unroll
  for (int k = 0; k < 16; ++k) Cs[p][j0 + 4 * k] = accC[k];
  __syncthreads();
  float* cbase = contrib + (((size_t)(bh * NC + c)) << 12);
  for (int f = tid; f < 1024; f += 256) {
    const int pp = f >> 4, q = (f & 15) << 2;
    const float4 cv = make_float4(Cs[pp][q], Cs[pp][q + 1], Cs[pp][q + 2], Cs[pp][q + 3]);
    *(float4*)(cbase + pp * 64 + q) = cv;
  }
}

// Pass 2: cross-chunk state propagation (exclusive scan over chunks).
__global__ __launch_bounds__(256) void k_scan2(
    float* __restrict__ contrib, const float* __restrict__ PT)
{
  const int bh = blockIdx.x >> 2, qr = blockIdx.x & 3;
  const int tid = threadIdx.x;
  float hv[4] = {0.f, 0.f, 0.f, 0.f};
  for (int c = 0; c < NC; ++c) {
    float* base = contrib + (((size_t)(bh * NC + c)) << 12) + (qr << 10);
    const float pt = PT[bh * NC + c];
#pragma unroll
    for (int k = 0; k < 4; ++k) {
      const int idx = tid + (k << 8);
      const float tmp = base[idx];
      base[idx] = hv[k];
      hv[k] = fmaf(pt, hv[k], tmp);
    }
  }
}

// Pass 3: add incoming-state term, then silu(z) gate (z is bf16 now).
__global__ __launch_bounds__(256) void k_scan3(
    float* __restrict__ xc, const ushort* __restrict__ z,
    const float* __restrict__ hin, const float* __restrict__ Sbuf)
{
  const int c = blockIdx.x & (NC - 1);
  const int bh = blockIdx.x >> 5;
  const int b = bh >> 3, h = bh & 7;
  const int tid = threadIdx.x;
  const int r0 = b * 2048 + c * TC;
  const int hbase = h * 64;
  __shared__ float Hs[64][65], Cs[64][65];
  __shared__ float Esh[64];
  const float* hp = hin + (((size_t)(bh * NC + c)) << 12);
  for (int f = tid; f < 1024; f += 256) {
    const int p2 = f >> 4, q = (f & 15) << 2;
    const float4 hv = *(const float4*)(hp + p2 * 64 + q);
    Hs[p2][q] = hv.x; Hs[p2][q + 1] = hv.y; Hs[p2][q + 2] = hv.z; Hs[p2][q + 3] = hv.w;
    const float4 cv = *(const float4*)(xc + (size_t)(r0 + p2) * 640 + 576 + q);
    Cs[p2][q] = cv.x; Cs[p2][q + 1] = cv.y; Cs[p2][q + 2] = cv.z; Cs[p2][q + 3] = cv.w;
  }
  if (tid < 64) Esh[tid] = expf(-Sbuf[(size_t)bh * 2048 + c * TC + tid]);
  __syncthreads();
  const int i = tid >> 2, j0 = tid & 3;
  float acc[16];
#pragma unroll
  for (int k = 0; k < 16; ++k) acc[k] = 0.f;
  for (int n = 0; n < 64; ++n) {
    const float ci = Cs[i][n];
#pragma unroll
    for (int k = 0; k < 16; ++k) acc[k] = fmaf(ci, Hs[j0 + 4 * k][n], acc[k]);
  }
  const float ei = Esh[i];
  __syncthreads();
#pragma unroll
  for (int k = 0; k < 16; ++k) Cs[i][j0 + 4 * k] = acc[k] * ei;
  __syncthreads();
  for (int f = tid; f < 1024; f += 256) {
    const int ii = f >> 4, q = (f & 15) << 2;
    float* yp = xc + (size_t)(r0 + ii) * 640 + hbase + q;
    const float4 yl = *(const float4*)yp;
    const ushort4 zv = *(const ushort4*)(z + (size_t)(r0 + ii) * 512 + hbase + q);
    float4 o;
    o.x = (yl.x + Cs[ii][q + 0]) * siluf(b2f(zv.x));
    o.y = (yl.y + Cs[ii][q + 1]) * siluf(b2f(zv.y));
    o.z = (yl.z + Cs[ii][q + 2]) * siluf(b2f(zv.z));
    o.w = (yl.w + Cs[ii][q + 3]) * siluf(b2f(zv.w));
    *(float4*)yp = o;
  }
}

// RMSNorm (in place over xc[.., 0:512], stride 640).
__global__ __launch_bounds__(256) void k_rms(
    float* __restrict__ xc, const float* __restrict__ w)
{
  const int row = blockIdx.x;
  float* y = xc + (size_t)row * 640;
  const int tid = threadIdx.x;
  const float v0 = y[tid], v1 = y[tid + 256];
  float ss = v0 * v0 + v1 * v1;
#pragma unroll
  for (int o = 32; o > 0; o >>= 1) ss += __shfl_xor(ss, o);
  __shared__ float red[4];
  if ((tid & 63) == 0) red[tid >> 6] = ss;
  __syncthreads();
  const float tot = red[0] + red[1] + red[2] + red[3];
  const float sc = rsqrtf(tot * (1.f / 512.f) + 1e-5f);
  y[tid]       = v0 * sc * w[tid];
  y[tid + 256] = v1 * sc * w[tid + 256];
}

__global__ __launch_bounds__(256) void k_hpart(
    const float* __restrict__ hf, const float* __restrict__ hb,
    float* __restrict__ part)
{
  const int g = blockIdx.x;
  const int b = g >> 5, seg = g & 31;
  const int m = threadIdx.x;
  float s = 0.f;
  for (int l = seg * 64; l < seg * 64 + 64; ++l) {
    const size_t idx = ((size_t)b * 2048 + l) * 256 + m;
    s += hf[idx] + hb[idx];
  }
  part[(size_t)g * 256 + m] = s;
}

__global__ __launch_bounds__(256) void k_hfinal(
    const float* __restrict__ part, float* __restrict__ H)
{
  const int b = blockIdx.x;
  const int m = threadIdx.x;
  float s = 0.f;
  for (int g = 0; g < 32; ++g) s += part[(size_t)(b * 32 + g) * 256 + m];
  H[b * 256 + m] = s * (1.f / 2048.f);
}

extern "C" void kernel_launch(void* const* d_in, const int* in_sizes, int n_in,
                              void* d_out, int out_size, void* d_ws, size_t ws_size,
                              hipStream_t stream) {
  const float* x_in = (const float*)d_in[0];
  const float* Win[2]    = {(const float*)d_in[1],  (const float*)d_in[9]};
  const float* Wconv[2]  = {(const float*)d_in[2],  (const float*)d_in[10]};
  const float* bconv[2]  = {(const float*)d_in[3],  (const float*)d_in[11]};
  const float* dtbias[2] = {(const float*)d_in[4],  (const float*)d_in[12]};
  const float* Alog[2]   = {(const float*)d_in[5],  (const float*)d_in[13]};
  const float* Dpar[2]   = {(const float*)d_in[6],  (const float*)d_in[14]};
  const float* normw[2]  = {(const float*)d_in[7],  (const float*)d_in[15]};
  const float* Wout[2]   = {(const float*)d_in[8],  (const float*)d_in[16]};

  float* ws = (float*)d_ws;
  ushort* zb    = (ushort*)ws;                       // 16384x512 bf16  [0, 4194304)
  ushort* xbcb  = (ushort*)(ws + 4194304);           // 16384x640 bf16  [4194304, 9437184)
  float* contrib = ws + 9437184;                     // 8388608
  float* xc      = ws + 17825792;                    // 10485760
  float* dtraw   = ws + 28311552;                    // 131072
  float* dtb     = dtraw + 131072;
  float* dab     = dtb + 131072;
  float* Sbuf    = dab + 131072;                     // 131072
  float* xA      = Sbuf + 131072;                    // 4194304
  float* xB      = xA + 4194304;                     // 4194304
  float* part    = xB + 4194304;                     // 65536 (PT in first 2048)
  // total ~37.3M floats = ~149 MB

  float* hF = (float*)d_out;
  float* hB = hF + (size_t)8 * 2048 * 256;
  float* Hm = hB + (size_t)8 * 2048 * 256;

  const float* cur = x_in;
  for (int layer = 0; layer < 4; ++layer) {
    float* nxt = (layer == 0) ? xA : (layer == 1) ? xB : (layer == 2) ? xA : nullptr;
    for (int dir = 0; dir < 2; ++dir) {
      const float* Wi = Win[dir]    + (size_t)layer * 1160 * 256;
      const float* Wc = Wconv[dir]  + (size_t)layer * 640 * 4;
      const float* bc = bconv[dir]  + (size_t)layer * 640;
      const float* db = dtbias[dir] + (size_t)layer * 8;
      const float* Al = Alog[dir]   + (size_t)layer * 8;
      const float* Dl = Dpar[dir]   + (size_t)layer * 8;
      const float* nw = normw[dir]  + (size_t)layer * 512;
      const float* Wo = Wout[dir]   + (size_t)layer * 256 * 512;

      k_gemmb<<<dim3(128, 10), 256, 0, stream>>>(cur, 256, dir, Wi, 1160, 256, 0,
                                                 zb, xbcb, dtraw, nullptr, 0, 0);
      k_dt<<<512, 256, 0, stream>>>(dtraw, db, Al, dtb, dab);
      k_conv<<<dim3(10, 512), 256, 0, stream>>>(xbcb, Wc, bc, xc);
      k_scan1<<<2048, 256, 0, stream>>>(xc, dtb, dab, Dl, contrib, Sbuf, part);
      k_scan2<<<256, 256, 0, stream>>>(contrib, part);
      k_scan3<<<2048, 256, 0, stream>>>(xc, zb, contrib, Sbuf);
      k_rms<<<16384, 256, 0, stream>>>(xc, nw);
      float* outp;
      int accf;
      if (layer < 3) { outp = nxt; accf = dir; }
      else           { outp = dir ? hB : hF; accf = 0; }
      k_gemmb<<<dim3(128, 2), 256, 0, stream>>>(xc, 640, 0, Wo, 256, 512, 1,
                                                nullptr, nullptr, nullptr, outp, dir, accf);
    }
    cur = nxt;
  }
  k_hpart<<<256, 256, 0, stream>>>(hF, hB, part);
  k_hfinal<<<8, 256, 0, stream>>>(part, Hm);
}

// Round 4
// 1709.457 us; speedup vs baseline: 4.7755x; 1.3841x over previous
//
#include <hip/hip_runtime.h>
#include <math.h>

// MicroEncoder: 4-layer bidirectional Mamba2.
// B=8, L=2048, D_MODEL=256, D_INNER=512, NHEADS=8, HEADDIM=64, D_STATE=64,
// CONV_DIM=640, D_IN_PROJ=1160.
// Round 4: k_scan1 rewritten with split-bf16 (hi+lo) MFMA for the three
// 64x64x64 matmuls (fp32-grade accuracy at bf16 matrix-core rate).
// Everything else identical to round 3.

#define TC 64
#define NC 32
#define SPITCH 72

typedef __attribute__((ext_vector_type(4))) float f32x4;
typedef __attribute__((ext_vector_type(8))) short s16x8;

#define MFMA __builtin_amdgcn_mfma_f32_16x16x32_bf16

__device__ __forceinline__ float siluf(float x) { return x / (1.f + expf(-x)); }

// fp32 -> bf16 round-to-nearest-even (finite inputs)
__device__ __forceinline__ ushort f2b(float f) {
  union { float f; uint u; } v; v.f = f;
  return (ushort)((v.u + 0x7FFFu + ((v.u >> 16) & 1u)) >> 16);
}
__device__ __forceinline__ float b2f(ushort u) {
  union { uint u; float f; } v; v.u = ((uint)u) << 16; return v.f;
}
// LDS chunk swizzle: 16 rows x same-chunk reads land 2-way per bank (free).
__device__ __forceinline__ int swz(int r, int c) { return c ^ (r & 3) ^ ((r >> 2) & 3); }

// scan1 LDS tile addressing: pitch-72 ushort rows, 8-elem (16B) chunks
// XOR-swizzled by row bits so both row-major b128 reads and column-gather
// u16 reads stay <=4-way on banks. Returns ushort offset.
__device__ __forceinline__ int soff(int base, int r, int cc) {
  return base + r * SPITCH + ((((cc >> 3) ^ (r & 7) ^ ((r >> 3) & 7)) << 3) | (cc & 7));
}

__device__ __forceinline__ void cvt8(const float4 v0, const float4 v1, s16x8& hh, s16x8& ll) {
  const float a[8] = {v0.x, v0.y, v0.z, v0.w, v1.x, v1.y, v1.z, v1.w};
#pragma unroll
  for (int e = 0; e < 8; ++e) {
    const ushort hb = f2b(a[e]);
    hh[e] = (short)hb;
    ll[e] = (short)f2b(a[e] - b2f(hb));
  }
}

__device__ __forceinline__ void stage16(ushort* tiles, const float* src,
                                        int bh_, int bl_, int r, int c0) {
  const float4 v0 = *(const float4*)(src + c0);
  const float4 v1 = *(const float4*)(src + c0 + 4);
  const float4 v2 = *(const float4*)(src + c0 + 8);
  const float4 v3 = *(const float4*)(src + c0 + 12);
  s16x8 h0, l0, h1, l1;
  cvt8(v0, v1, h0, l0);
  cvt8(v2, v3, h1, l1);
  *(s16x8*)&tiles[soff(bh_, r, c0)]     = h0;
  *(s16x8*)&tiles[soff(bl_, r, c0)]     = l0;
  *(s16x8*)&tiles[soff(bh_, r, c0 + 8)] = h1;
  *(s16x8*)&tiles[soff(bl_, r, c0 + 8)] = l1;
}

// ---------------------------------------------------------------------------
// bf16 MFMA GEMM: C = A @ W^T.  (unchanged from round 3)
// ---------------------------------------------------------------------------
__global__ __launch_bounds__(256) void k_gemmb(
    const float* __restrict__ A, int lda, int arev,
    const float* __restrict__ W, int N, int K,
    int mode,
    ushort* __restrict__ zb, ushort* __restrict__ xbc, float* __restrict__ dtraw,
    float* __restrict__ Cout, int crev, int accflag)
{
  __shared__ __align__(16) ushort lds[17408];
  const int tid = threadIdx.x;
  const int lane = tid & 63;
  const int wid = tid >> 6;
  const int wr = wid >> 1, wc = wid & 1;
  const int m0 = blockIdx.x * 128, n0 = blockIdx.y * 128;

  const int tr = tid >> 1;
  const int th = tid & 1;
  const int gm = m0 + tr;
  const int bb = gm >> 11, tt = gm & 2047;
  const int tphys = arev ? (2047 - tt) : tt;
  const float* Arow = A + (size_t)((bb << 11) + tphys) * lda + th * 16;
  const int wn = n0 + tr;
  const float* Wrow = (wn < N) ? (W + (size_t)wn * K + th * 16) : nullptr;

  const int asw0 = tr * 32 + swz(tr, th * 2) * 8;
  const int asw1 = tr * 32 + swz(tr, th * 2 + 1) * 8;

  f32x4 acc[4][4];
#pragma unroll
  for (int i = 0; i < 4; ++i)
#pragma unroll
    for (int j = 0; j < 4; ++j) acc[i][j] = (f32x4){0.f, 0.f, 0.f, 0.f};

  int aoff[4], boff[4];
#pragma unroll
  for (int f = 0; f < 4; ++f) {
    const int ar = wr * 64 + f * 16 + (lane & 15);
    aoff[f] = ar * 32 + swz(ar, lane >> 4) * 8;
    const int br = wc * 64 + f * 16 + (lane & 15);
    boff[f] = 4096 + br * 32 + swz(br, lane >> 4) * 8;
  }

  float4 a0, a1, a2, a3;
  float4 b0 = make_float4(0.f, 0.f, 0.f, 0.f), b1 = b0, b2 = b0, b3 = b0;
  a0 = *(const float4*)(Arow + 0); a1 = *(const float4*)(Arow + 4);
  a2 = *(const float4*)(Arow + 8); a3 = *(const float4*)(Arow + 12);
  if (Wrow) {
    b0 = *(const float4*)(Wrow + 0); b1 = *(const float4*)(Wrow + 4);
    b2 = *(const float4*)(Wrow + 8); b3 = *(const float4*)(Wrow + 12);
  }

  for (int k0 = 0; k0 < K; k0 += 32) {
    __syncthreads();
    {
      s16x8 pa0, pa1, pb0, pb1;
      pa0[0] = (short)f2b(a0.x); pa0[1] = (short)f2b(a0.y);
      pa0[2] = (short)f2b(a0.z); pa0[3] = (short)f2b(a0.w);
      pa0[4] = (short)f2b(a1.x); pa0[5] = (short)f2b(a1.y);
      pa0[6] = (short)f2b(a1.z); pa0[7] = (short)f2b(a1.w);
      pa1[0] = (short)f2b(a2.x); pa1[1] = (short)f2b(a2.y);
      pa1[2] = (short)f2b(a2.z); pa1[3] = (short)f2b(a2.w);
      pa1[4] = (short)f2b(a3.x); pa1[5] = (short)f2b(a3.y);
      pa1[6] = (short)f2b(a3.z); pa1[7] = (short)f2b(a3.w);
      pb0[0] = (short)f2b(b0.x); pb0[1] = (short)f2b(b0.y);
      pb0[2] = (short)f2b(b0.z); pb0[3] = (short)f2b(b0.w);
      pb0[4] = (short)f2b(b1.x); pb0[5] = (short)f2b(b1.y);
      pb0[6] = (short)f2b(b1.z); pb0[7] = (short)f2b(b1.w);
      pb1[0] = (short)f2b(b2.x); pb1[1] = (short)f2b(b2.y);
      pb1[2] = (short)f2b(b2.z); pb1[3] = (short)f2b(b2.w);
      pb1[4] = (short)f2b(b3.x); pb1[5] = (short)f2b(b3.y);
      pb1[6] = (short)f2b(b3.z); pb1[7] = (short)f2b(b3.w);
      *(s16x8*)&lds[asw0] = pa0;
      *(s16x8*)&lds[asw1] = pa1;
      *(s16x8*)&lds[4096 + asw0] = pb0;
      *(s16x8*)&lds[4096 + asw1] = pb1;
    }
    __syncthreads();
    if (k0 + 32 < K) {
      const float* Ap = Arow + k0 + 32;
      a0 = *(const float4*)(Ap + 0); a1 = *(const float4*)(Ap + 4);
      a2 = *(const float4*)(Ap + 8); a3 = *(const float4*)(Ap + 12);
      if (Wrow) {
        const float* Wp = Wrow + k0 + 32;
        b0 = *(const float4*)(Wp + 0); b1 = *(const float4*)(Wp + 4);
        b2 = *(const float4*)(Wp + 8); b3 = *(const float4*)(Wp + 12);
      }
    }
    s16x8 af[4], bf[4];
#pragma unroll
    for (int f = 0; f < 4; ++f) {
      af[f] = *(const s16x8*)&lds[aoff[f]];
      bf[f] = *(const s16x8*)&lds[boff[f]];
    }
#pragma unroll
    for (int i = 0; i < 4; ++i)
#pragma unroll
      for (int j = 0; j < 4; ++j)
        acc[i][j] = MFMA(af[i], bf[j], acc[i][j], 0, 0, 0);
  }

  if (mode == 0) {
    const int by = blockIdx.y;
    if (by == 9) {
      if (wc == 0 && (lane & 15) < 8) {
        const int cl = lane & 15;
#pragma unroll
        for (int i = 0; i < 4; ++i) {
          const int r = m0 + wr * 64 + i * 16 + (lane >> 4) * 4;
#pragma unroll
          for (int g = 0; g < 4; ++g)
            dtraw[(size_t)(r + g) * 8 + cl] = acc[i][0][g];
        }
      }
      return;
    }
    __syncthreads();
#pragma unroll
    for (int i = 0; i < 4; ++i) {
      const int r = wr * 64 + i * 16 + (lane >> 4) * 4;
#pragma unroll
      for (int j = 0; j < 4; ++j) {
        const int ccol = wc * 64 + j * 16 + (lane & 15);
#pragma unroll
        for (int g = 0; g < 4; ++g)
          lds[(r + g) * 136 + ccol] = f2b(acc[i][j][g]);
      }
    }
    __syncthreads();
    const int rr = tid >> 1, hf = tid & 1;
    const int grow = m0 + rr;
    ushort* dst; int stride, colb;
    if (by < 4) { dst = zb;  stride = 512; colb = n0; }
    else        { dst = xbc; stride = 640; colb = n0 - 512; }
    ushort* dp = dst + (size_t)grow * stride + colb + hf * 64;
    const ushort* sp = &lds[rr * 136 + hf * 64];
#pragma unroll
    for (int q = 0; q < 8; ++q)
      *(s16x8*)(dp + q * 8) = *(const s16x8*)(sp + q * 8);
  } else {
#pragma unroll
    for (int i = 0; i < 4; ++i) {
      const int rb = m0 + wr * 64 + i * 16 + (lane >> 4) * 4;
#pragma unroll
      for (int g = 0; g < 4; ++g) {
        const int row = rb + g;
        const int b2 = row >> 11, t2 = row & 2047;
        const int tw = crev ? (2047 - t2) : t2;
        float* crow = Cout + ((size_t)((b2 << 11) + tw)) * 256 + n0 + wc * 64 + (lane & 15);
#pragma unroll
        for (int j = 0; j < 4; ++j) {
          const float v = acc[i][j][g];
          if (accflag) crow[j * 16] += v; else crow[j * 16] = v;
        }
      }
    }
  }
}

// dt = softplus(dtraw + dt_bias); dtA = dt * exp(A_log)
__global__ __launch_bounds__(256) void k_dt(
    const float* __restrict__ dtraw, const float* __restrict__ dt_bias,
    const float* __restrict__ A_log, float* __restrict__ dt,
    float* __restrict__ dtA)
{
  const int i = blockIdx.x * 256 + threadIdx.x;
  const int h = i & 7;
  const float v = dtraw[i] + dt_bias[h];
  const float sp = (v > 20.f) ? v : log1pf(expf(v));
  dt[i] = sp;
  dtA[i] = sp * expf(A_log[h]);
}

// causal depthwise conv (k=4, bf16 in) + bias + silu -> fp32 xc
__global__ __launch_bounds__(256) void k_conv(
    const ushort* __restrict__ xbc, const float* __restrict__ Wc,
    const float* __restrict__ bc, float* __restrict__ xc)
{
  const int t = threadIdx.x;
  const int cg = blockIdx.x * 8 + (t & 7);
  const int rowt = blockIdx.y * 32 + (t >> 3);
  const int l = rowt & 2047;
  const int c0 = cg * 8;
  float4 wv[8];
  const float4* wp = (const float4*)(Wc + c0 * 4);
#pragma unroll
  for (int e = 0; e < 8; ++e) wv[e] = wp[e];
  float acc[8];
#pragma unroll
  for (int e = 0; e < 8; ++e) acc[e] = bc[c0 + e];
#pragma unroll
  for (int k = 0; k < 4; ++k) {
    const int lt = l - 3 + k;
    if (lt < 0) continue;
    const s16x8 v = *(const s16x8*)(xbc + (size_t)(rowt - 3 + k) * 640 + c0);
#pragma unroll
    for (int e = 0; e < 8; ++e)
      acc[e] = fmaf(b2f((ushort)v[e]), ((const float*)&wv[e])[k], acc[e]);
  }
  float* op = xc + (size_t)rowt * 640 + c0;
  float4 o0, o1;
  o0.x = siluf(acc[0]); o0.y = siluf(acc[1]); o0.z = siluf(acc[2]); o0.w = siluf(acc[3]);
  o1.x = siluf(acc[4]); o1.y = siluf(acc[5]); o1.z = siluf(acc[6]); o1.w = siluf(acc[7]);
  *(float4*)op = o0; *(float4*)(op + 4) = o1;
}

// ---------------------------------------------------------------------------
// Chunked SSD pass 1, split-bf16 MFMA version.
// One block per (b,h,chunk). 4 waves; wave w owns 16-row slab of each output.
//   P1: stage B,C,X as hi/lo bf16 planes (swizzled) + prefix sums
//   P2: G = C.B^T (3-product split MFMA), decay/dt weight, restage G~ hi/lo
//   P3: Ylocal = G~.X (X gathered transposed), +Dp*x via global RMW
//   P4: contrib[p][n] = sum_j (v_j X[j][p]) B[j][n] (both gathered transposed)
// ---------------------------------------------------------------------------
__global__ __launch_bounds__(256) void k_scan1(
    float* __restrict__ xc, const float* __restrict__ dt,
    const float* __restrict__ dtA, const float* __restrict__ Dp,
    float* __restrict__ contrib, float* __restrict__ Sbuf,
    float* __restrict__ PT)
{
  const int c = blockIdx.x & (NC - 1);
  const int bhi = blockIdx.x >> 5;
  const int b = bhi >> 3, h = bhi & 7;
  const int tid = threadIdx.x;
  const int lane = tid & 63;
  const int wid = tid >> 6;
  const int r0 = b * 2048 + c * TC;
  const int hbase = h * 64;
  __shared__ __align__(16) ushort tiles[27648];
  __shared__ float Ssh[64], dtsh[64], vsh[64];
  const int OBH = 0, OBL = 4608, OCH = 9216, OCL = 13824, OXH = 18432;

  // P0: prefix sums over dtA (log-space decay), v_j weights
  if (tid < 64) {
    float a = dtA[(size_t)(r0 + tid) * 8 + h];
    const float d = dt[(size_t)(r0 + tid) * 8 + h];
#pragma unroll
    for (int off = 1; off < 64; off <<= 1) {
      const float t = __shfl_up(a, off);
      if (tid >= off) a += t;
    }
    const float slast = __shfl(a, 63);
    Ssh[tid] = a;
    dtsh[tid] = d;
    vsh[tid] = expf(a - slast) * d;
    Sbuf[(size_t)bhi * 2048 + c * TC + tid] = a;
    if (tid == 63) PT[bhi * NC + c] = expf(-slast);
  }
  // P1: stage B, C, X hi/lo
  {
    const int r = tid >> 2, c0 = (tid & 3) * 16;
    const float* rowp = xc + (size_t)(r0 + r) * 640;
    stage16(tiles, rowp + 512, OBH, OBL, r, c0);
    stage16(tiles, rowp + 576, OCH, OCL, r, c0);
    stage16(tiles, rowp + hbase, OXH, OXH + 4608, r, c0);
  }
  __syncthreads();

  const int ib = wid * 16;          // wave's row-tile base (i / p rows)
  const int frow = lane & 15;       // fragment row within tile
  const int fk = (lane >> 4) * 8;   // fragment k-chunk base

  // ---- P2: G = C.B^T, weight, restage G~ over C space ----
  s16x8 pah[2], pal[2];
#pragma unroll
  for (int ks = 0; ks < 2; ++ks) {
    pah[ks] = *(const s16x8*)&tiles[soff(OCH, ib + frow, ks * 32 + fk)];
    pal[ks] = *(const s16x8*)&tiles[soff(OCL, ib + frow, ks * 32 + fk)];
  }
  f32x4 acc[4];
#pragma unroll
  for (int jt = 0; jt < 4; ++jt) acc[jt] = (f32x4){0.f, 0.f, 0.f, 0.f};
#pragma unroll
  for (int jt = 0; jt < 4; ++jt) {
#pragma unroll
    for (int ks = 0; ks < 2; ++ks) {
      const s16x8 tbh = *(const s16x8*)&tiles[soff(OBH, jt * 16 + frow, ks * 32 + fk)];
      const s16x8 tbl = *(const s16x8*)&tiles[soff(OBL, jt * 16 + frow, ks * 32 + fk)];
      acc[jt] = MFMA(pah[ks], tbh, acc[jt], 0, 0, 0);
      acc[jt] = MFMA(pah[ks], tbl, acc[jt], 0, 0, 0);
      acc[jt] = MFMA(pal[ks], tbh, acc[jt], 0, 0, 0);
    }
  }
  float Si[4];
#pragma unroll
  for (int g = 0; g < 4; ++g) Si[g] = Ssh[ib + (lane >> 4) * 4 + g];
#pragma unroll
  for (int jt = 0; jt < 4; ++jt) {
    const int j = jt * 16 + frow;
    const float Sj = Ssh[j], dj = dtsh[j];
#pragma unroll
    for (int g = 0; g < 4; ++g) {
      const int i = ib + (lane >> 4) * 4 + g;
      const float w = (j <= i) ? __expf(Sj - Si[g]) * dj : 0.f;
      const float gt = acc[jt][g] * w;
      const ushort gh = f2b(gt);
      tiles[soff(OCH, i, j)] = gh;
      tiles[soff(OCL, i, j)] = f2b(gt - b2f(gh));
    }
  }
  __syncthreads();

  // ---- P3: Ylocal = G~.X  (+ Dp*x via RMW) ----
  s16x8 gah[2], gal[2];
#pragma unroll
  for (int ks = 0; ks < 2; ++ks) {
    gah[ks] = *(const s16x8*)&tiles[soff(OCH, ib + frow, ks * 32 + fk)];
    gal[ks] = *(const s16x8*)&tiles[soff(OCL, ib + frow, ks * 32 + fk)];
  }
  const float dpv = Dp[h];
#pragma unroll
  for (int pt = 0; pt < 4; ++pt) {
    f32x4 accY = (f32x4){0.f, 0.f, 0.f, 0.f};
    const int p = pt * 16 + frow;
#pragma unroll
    for (int ks = 0; ks < 2; ++ks) {
      const int J0 = ks * 32 + fk;
      const int cb = OXH + J0 * SPITCH + (p & 7);
      const int g0 = (((p >> 3) ^ ((J0 >> 3) & 7)) << 3);
      s16x8 xh, xl;
#pragma unroll
      for (int e = 0; e < 8; ++e) {
        const int ad = cb + e * SPITCH + (g0 ^ (e << 3));
        xh[e] = (short)tiles[ad];
        xl[e] = (short)tiles[ad + 4608];
      }
      accY = MFMA(gah[ks], xh, accY, 0, 0, 0);
      accY = MFMA(gah[ks], xl, accY, 0, 0, 0);
      accY = MFMA(gal[ks], xh, accY, 0, 0, 0);
    }
#pragma unroll
    for (int g = 0; g < 4; ++g) {
      const int i = ib + (lane >> 4) * 4 + g;
      float* ap = xc + (size_t)(r0 + i) * 640 + hbase + p;
      *ap = accY[g] + dpv * (*ap);
    }
  }

  // ---- P4: contrib[p][n] = sum_j (v_j X[j][p]) B[j][n] ----
  s16x8 xvh[2], xvl[2];
#pragma unroll
  for (int ks = 0; ks < 2; ++ks) {
    const int J0 = ks * 32 + fk;
    const int p = ib + frow;
    const int cb = OXH + J0 * SPITCH + (p & 7);
    const int g0 = (((p >> 3) ^ ((J0 >> 3) & 7)) << 3);
#pragma unroll
    for (int e = 0; e < 8; ++e) {
      const int ad = cb + e * SPITCH + (g0 ^ (e << 3));
      const float xf = (b2f(tiles[ad]) + b2f(tiles[ad + 4608])) * vsh[J0 + e];
      const ushort nh = f2b(xf);
      xvh[ks][e] = (short)nh;
      xvl[ks][e] = (short)f2b(xf - b2f(nh));
    }
  }
  float* cbp = contrib + (((size_t)(bhi * NC + c)) << 12);
#pragma unroll
  for (int nt = 0; nt < 4; ++nt) {
    f32x4 accC = (f32x4){0.f, 0.f, 0.f, 0.f};
    const int n = nt * 16 + frow;
#pragma unroll
    for (int ks = 0; ks < 2; ++ks) {
      const int J0 = ks * 32 + fk;
      const int cb = OBH + J0 * SPITCH + (n & 7);
      const int g0 = (((n >> 3) ^ ((J0 >> 3) & 7)) << 3);
      s16x8 tbh, tbl;
#pragma unroll
      for (int e = 0; e < 8; ++e) {
        const int ad = cb + e * SPITCH + (g0 ^ (e << 3));
        tbh[e] = (short)tiles[ad];
        tbl[e] = (short)tiles[ad + 4608];
      }
      accC = MFMA(xvh[ks], tbh, accC, 0, 0, 0);
      accC = MFMA(xvh[ks], tbl, accC, 0, 0, 0);
      accC = MFMA(xvl[ks], tbh, accC, 0, 0, 0);
    }
#pragma unroll
    for (int g = 0; g < 4; ++g) {
      const int p = ib + (lane >> 4) * 4 + g;
      cbp[p * 64 + n] = accC[g];
    }
  }
}

// Pass 2: cross-chunk state propagation (exclusive scan over chunks).
__global__ __launch_bounds__(256) void k_scan2(
    float* __restrict__ contrib, const float* __restrict__ PT)
{
  const int bh = blockIdx.x >> 2, qr = blockIdx.x & 3;
  const int tid = threadIdx.x;
  float hv[4] = {0.f, 0.f, 0.f, 0.f};
  for (int c = 0; c < NC; ++c) {
    float* base = contrib + (((size_t)(bh * NC + c)) << 12) + (qr << 10);
    const float pt = PT[bh * NC + c];
#pragma unroll
    for (int k = 0; k < 4; ++k) {
      const int idx = tid + (k << 8);
      const float tmp = base[idx];
      base[idx] = hv[k];
      hv[k] = fmaf(pt, hv[k], tmp);
    }
  }
}

// Pass 3: add incoming-state term, then silu(z) gate (z is bf16).
__global__ __launch_bounds__(256) void k_scan3(
    float* __restrict__ xc, const ushort* __restrict__ z,
    const float* __restrict__ hin, const float* __restrict__ Sbuf)
{
  const int c = blockIdx.x & (NC - 1);
  const int bh = blockIdx.x >> 5;
  const int b = bh >> 3, h = bh & 7;
  const int tid = threadIdx.x;
  const int r0 = b * 2048 + c * TC;
  const int hbase = h * 64;
  __shared__ float Hs[64][65], Cs[64][65];
  __shared__ float Esh[64];
  const float* hp = hin + (((size_t)(bh * NC + c)) << 12);
  for (int f = tid; f < 1024; f += 256) {
    const int p2 = f >> 4, q = (f & 15) << 2;
    const float4 hv = *(const float4*)(hp + p2 * 64 + q);
    Hs[p2][q] = hv.x; Hs[p2][q + 1] = hv.y; Hs[p2][q + 2] = hv.z; Hs[p2][q + 3] = hv.w;
    const float4 cv = *(const float4*)(xc + (size_t)(r0 + p2) * 640 + 576 + q);
    Cs[p2][q] = cv.x; Cs[p2][q + 1] = cv.y; Cs[p2][q + 2] = cv.z; Cs[p2][q + 3] = cv.w;
  }
  if (tid < 64) Esh[tid] = expf(-Sbuf[(size_t)bh * 2048 + c * TC + tid]);
  __syncthreads();
  const int i = tid >> 2, j0 = tid & 3;
  float acc[16];
#pragma unroll
  for (int k = 0; k < 16; ++k) acc[k] = 0.f;
  for (int n = 0; n < 64; ++n) {
    const float ci = Cs[i][n];
#pragma unroll
    for (int k = 0; k < 16; ++k) acc[k] = fmaf(ci, Hs[j0 + 4 * k][n], acc[k]);
  }
  const float ei = Esh[i];
  __syncthreads();
#pragma unroll
  for (int k = 0; k < 16; ++k) Cs[i][j0 + 4 * k] = acc[k] * ei;
  __syncthreads();
  for (int f = tid; f < 1024; f += 256) {
    const int ii = f >> 4, q = (f & 15) << 2;
    float* yp = xc + (size_t)(r0 + ii) * 640 + hbase + q;
    const float4 yl = *(const float4*)yp;
    const ushort4 zv = *(const ushort4*)(z + (size_t)(r0 + ii) * 512 + hbase + q);
    float4 o;
    o.x = (yl.x + Cs[ii][q + 0]) * siluf(b2f(zv.x));
    o.y = (yl.y + Cs[ii][q + 1]) * siluf(b2f(zv.y));
    o.z = (yl.z + Cs[ii][q + 2]) * siluf(b2f(zv.z));
    o.w = (yl.w + Cs[ii][q + 3]) * siluf(b2f(zv.w));
    *(float4*)yp = o;
  }
}

// RMSNorm (in place over xc[.., 0:512], stride 640).
__global__ __launch_bounds__(256) void k_rms(
    float* __restrict__ xc, const float* __restrict__ w)
{
  const int row = blockIdx.x;
  float* y = xc + (size_t)row * 640;
  const int tid = threadIdx.x;
  const float v0 = y[tid], v1 = y[tid + 256];
  float ss = v0 * v0 + v1 * v1;
#pragma unroll
  for (int o = 32; o > 0; o >>= 1) ss += __shfl_xor(ss, o);
  __shared__ float red[4];
  if ((tid & 63) == 0) red[tid >> 6] = ss;
  __syncthreads();
  const float tot = red[0] + red[1] + red[2] + red[3];
  const float sc = rsqrtf(tot * (1.f / 512.f) + 1e-5f);
  y[tid]       = v0 * sc * w[tid];
  y[tid + 256] = v1 * sc * w[tid + 256];
}

__global__ __launch_bounds__(256) void k_hpart(
    const float* __restrict__ hf, const float* __restrict__ hb,
    float* __restrict__ part)
{
  const int g = blockIdx.x;
  const int b = g >> 5, seg = g & 31;
  const int m = threadIdx.x;
  float s = 0.f;
  for (int l = seg * 64; l < seg * 64 + 64; ++l) {
    const size_t idx = ((size_t)b * 2048 + l) * 256 + m;
    s += hf[idx] + hb[idx];
  }
  part[(size_t)g * 256 + m] = s;
}

__global__ __launch_bounds__(256) void k_hfinal(
    const float* __restrict__ part, float* __restrict__ H)
{
  const int b = blockIdx.x;
  const int m = threadIdx.x;
  float s = 0.f;
  for (int g = 0; g < 32; ++g) s += part[(size_t)(b * 32 + g) * 256 + m];
  H[b * 256 + m] = s * (1.f / 2048.f);
}

extern "C" void kernel_launch(void* const* d_in, const int* in_sizes, int n_in,
                              void* d_out, int out_size, void* d_ws, size_t ws_size,
                              hipStream_t stream) {
  const float* x_in = (const float*)d_in[0];
  const float* Win[2]    = {(const float*)d_in[1],  (const float*)d_in[9]};
  const float* Wconv[2]  = {(const float*)d_in[2],  (const float*)d_in[10]};
  const float* bconv[2]  = {(const float*)d_in[3],  (const float*)d_in[11]};
  const float* dtbias[2] = {(const float*)d_in[4],  (const float*)d_in[12]};
  const float* Alog[2]   = {(const float*)d_in[5],  (const float*)d_in[13]};
  const float* Dpar[2]   = {(const float*)d_in[6],  (const float*)d_in[14]};
  const float* normw[2]  = {(const float*)d_in[7],  (const float*)d_in[15]};
  const float* Wout[2]   = {(const float*)d_in[8],  (const float*)d_in[16]};

  float* ws = (float*)d_ws;
  ushort* zb    = (ushort*)ws;                       // 16384x512 bf16
  ushort* xbcb  = (ushort*)(ws + 4194304);           // 16384x640 bf16
  float* contrib = ws + 9437184;                     // 8388608
  float* xc      = ws + 17825792;                    // 10485760
  float* dtraw   = ws + 28311552;                    // 131072
  float* dtb     = dtraw + 131072;
  float* dab     = dtb + 131072;
  float* Sbuf    = dab + 131072;                     // 131072
  float* xA      = Sbuf + 131072;                    // 4194304
  float* xB      = xA + 4194304;                     // 4194304
  float* part    = xB + 4194304;                     // 65536 (PT in first 2048)

  float* hF = (float*)d_out;
  float* hB = hF + (size_t)8 * 2048 * 256;
  float* Hm = hB + (size_t)8 * 2048 * 256;

  const float* cur = x_in;
  for (int layer = 0; layer < 4; ++layer) {
    float* nxt = (layer == 0) ? xA : (layer == 1) ? xB : (layer == 2) ? xA : nullptr;
    for (int dir = 0; dir < 2; ++dir) {
      const float* Wi = Win[dir]    + (size_t)layer * 1160 * 256;
      const float* Wc = Wconv[dir]  + (size_t)layer * 640 * 4;
      const float* bc = bconv[dir]  + (size_t)layer * 640;
      const float* db = dtbias[dir] + (size_t)layer * 8;
      const float* Al = Alog[dir]   + (size_t)layer * 8;
      const float* Dl = Dpar[dir]   + (size_t)layer * 8;
      const float* nw = normw[dir]  + (size_t)layer * 512;
      const float* Wo = Wout[dir]   + (size_t)layer * 256 * 512;

      k_gemmb<<<dim3(128, 10), 256, 0, stream>>>(cur, 256, dir, Wi, 1160, 256, 0,
                                                 zb, xbcb, dtraw, nullptr, 0, 0);
      k_dt<<<512, 256, 0, stream>>>(dtraw, db, Al, dtb, dab);
      k_conv<<<dim3(10, 512), 256, 0, stream>>>(xbcb, Wc, bc, xc);
      k_scan1<<<2048, 256, 0, stream>>>(xc, dtb, dab, Dl, contrib, Sbuf, part);
      k_scan2<<<256, 256, 0, stream>>>(contrib, part);
      k_scan3<<<2048, 256, 0, stream>>>(xc, zb, contrib, Sbuf);
      k_rms<<<16384, 256, 0, stream>>>(xc, nw);
      float* outp;
      int accf;
      if (layer < 3) { outp = nxt; accf = dir; }
      else           { outp = dir ? hB : hF; accf = 0; }
      k_gemmb<<<dim3(128, 2), 256, 0, stream>>>(xc, 640, 0, Wo, 256, 512, 1,
                                                nullptr, nullptr, nullptr, outp, dir, accf);
    }
    cur = nxt;
  }
  k_hpart<<<256, 256, 0, stream>>>(hF, hB, part);
  k_hfinal<<<8, 256, 0, stream>>>(part, Hm);
}

// Round 5
// 1466.891 us; speedup vs baseline: 5.5652x; 1.1654x over previous
//
#include <hip/hip_runtime.h>
#include <math.h>

// MicroEncoder: 4-layer bidirectional Mamba2.
// B=8, L=2048, D_MODEL=256, D_INNER=512, NHEADS=8, HEADDIM=64, D_STATE=64,
// CONV_DIM=640, D_IN_PROJ=1160.
// Round 5: fused scan3 (state MFMA + gate + RMSNorm + bf16 out) over (b,chunk)
// blocks; contrib/hin in packed split-bf16 MFMA-fragment layout; out-proj
// GEMM takes bf16 A directly. k_rms eliminated.

#define TC 64
#define NC 32
#define SPITCH 72
#define HIOFF 8388608   // ushort offset of the lo plane in packed hin

typedef __attribute__((ext_vector_type(4))) float f32x4;
typedef __attribute__((ext_vector_type(8))) short s16x8;

#define MFMA __builtin_amdgcn_mfma_f32_16x16x32_bf16

__device__ __forceinline__ float siluf(float x) { return x / (1.f + expf(-x)); }

// fp32 -> bf16 round-to-nearest-even (finite inputs)
__device__ __forceinline__ ushort f2b(float f) {
  union { float f; uint u; } v; v.f = f;
  return (ushort)((v.u + 0x7FFFu + ((v.u >> 16) & 1u)) >> 16);
}
__device__ __forceinline__ float b2f(ushort u) {
  union { uint u; float f; } v; v.u = ((uint)u) << 16; return v.f;
}
__device__ __forceinline__ int swz(int r, int c) { return c ^ (r & 3) ^ ((r >> 2) & 3); }

// scan LDS tile addressing: pitch-72 ushort rows, 8-elem (16B) chunks
// XOR-swizzled by row bits.
__device__ __forceinline__ int soff(int base, int r, int cc) {
  return base + r * SPITCH + ((((cc >> 3) ^ (r & 7) ^ ((r >> 3) & 7)) << 3) | (cc & 7));
}

__device__ __forceinline__ void cvt8(const float4 v0, const float4 v1, s16x8& hh, s16x8& ll) {
  const float a[8] = {v0.x, v0.y, v0.z, v0.w, v1.x, v1.y, v1.z, v1.w};
#pragma unroll
  for (int e = 0; e < 8; ++e) {
    const ushort hb = f2b(a[e]);
    hh[e] = (short)hb;
    ll[e] = (short)f2b(a[e] - b2f(hb));
  }
}

__device__ __forceinline__ void stage16(ushort* tiles, const float* src,
                                        int bh_, int bl_, int r, int c0) {
  const float4 v0 = *(const float4*)(src + c0);
  const float4 v1 = *(const float4*)(src + c0 + 4);
  const float4 v2 = *(const float4*)(src + c0 + 8);
  const float4 v3 = *(const float4*)(src + c0 + 12);
  s16x8 h0, l0, h1, l1;
  cvt8(v0, v1, h0, l0);
  cvt8(v2, v3, h1, l1);
  *(s16x8*)&tiles[soff(bh_, r, c0)]     = h0;
  *(s16x8*)&tiles[soff(bl_, r, c0)]     = l0;
  *(s16x8*)&tiles[soff(bh_, r, c0 + 8)] = h1;
  *(s16x8*)&tiles[soff(bl_, r, c0 + 8)] = l1;
}

// ---------------------------------------------------------------------------
// bf16 MFMA GEMM (in_proj): C = A @ W^T, A fp32 (optional row reversal).
// Epilogue routes z (bf16) / xBC (bf16) / dtraw (fp32).
// ---------------------------------------------------------------------------
__global__ __launch_bounds__(256) void k_gemmb(
    const float* __restrict__ A, int lda, int arev,
    const float* __restrict__ W, int N, int K,
    ushort* __restrict__ zb, ushort* __restrict__ xbc, float* __restrict__ dtraw)
{
  __shared__ __align__(16) ushort lds[17408];
  const int tid = threadIdx.x;
  const int lane = tid & 63;
  const int wid = tid >> 6;
  const int wr = wid >> 1, wc = wid & 1;
  const int m0 = blockIdx.x * 128, n0 = blockIdx.y * 128;

  const int tr = tid >> 1;
  const int th = tid & 1;
  const int gm = m0 + tr;
  const int bb = gm >> 11, tt = gm & 2047;
  const int tphys = arev ? (2047 - tt) : tt;
  const float* Arow = A + (size_t)((bb << 11) + tphys) * lda + th * 16;
  const int wn = n0 + tr;
  const float* Wrow = (wn < N) ? (W + (size_t)wn * K + th * 16) : nullptr;

  const int asw0 = tr * 32 + swz(tr, th * 2) * 8;
  const int asw1 = tr * 32 + swz(tr, th * 2 + 1) * 8;

  f32x4 acc[4][4];
#pragma unroll
  for (int i = 0; i < 4; ++i)
#pragma unroll
    for (int j = 0; j < 4; ++j) acc[i][j] = (f32x4){0.f, 0.f, 0.f, 0.f};

  int aoff[4], boff[4];
#pragma unroll
  for (int f = 0; f < 4; ++f) {
    const int ar = wr * 64 + f * 16 + (lane & 15);
    aoff[f] = ar * 32 + swz(ar, lane >> 4) * 8;
    const int br = wc * 64 + f * 16 + (lane & 15);
    boff[f] = 4096 + br * 32 + swz(br, lane >> 4) * 8;
  }

  float4 a0, a1, a2, a3;
  float4 b0 = make_float4(0.f, 0.f, 0.f, 0.f), b1 = b0, b2 = b0, b3 = b0;
  a0 = *(const float4*)(Arow + 0); a1 = *(const float4*)(Arow + 4);
  a2 = *(const float4*)(Arow + 8); a3 = *(const float4*)(Arow + 12);
  if (Wrow) {
    b0 = *(const float4*)(Wrow + 0); b1 = *(const float4*)(Wrow + 4);
    b2 = *(const float4*)(Wrow + 8); b3 = *(const float4*)(Wrow + 12);
  }

  for (int k0 = 0; k0 < K; k0 += 32) {
    __syncthreads();
    {
      s16x8 pa0, pa1, pb0, pb1;
      s16x8 d0, d1;
      cvt8(a0, a1, pa0, d0); cvt8(a2, a3, pa1, d1);
      cvt8(b0, b1, pb0, d0); cvt8(b2, b3, pb1, d1);
      *(s16x8*)&lds[asw0] = pa0;
      *(s16x8*)&lds[asw1] = pa1;
      *(s16x8*)&lds[4096 + asw0] = pb0;
      *(s16x8*)&lds[4096 + asw1] = pb1;
    }
    __syncthreads();
    if (k0 + 32 < K) {
      const float* Ap = Arow + k0 + 32;
      a0 = *(const float4*)(Ap + 0); a1 = *(const float4*)(Ap + 4);
      a2 = *(const float4*)(Ap + 8); a3 = *(const float4*)(Ap + 12);
      if (Wrow) {
        const float* Wp = Wrow + k0 + 32;
        b0 = *(const float4*)(Wp + 0); b1 = *(const float4*)(Wp + 4);
        b2 = *(const float4*)(Wp + 8); b3 = *(const float4*)(Wp + 12);
      }
    }
    s16x8 af[4], bf[4];
#pragma unroll
    for (int f = 0; f < 4; ++f) {
      af[f] = *(const s16x8*)&lds[aoff[f]];
      bf[f] = *(const s16x8*)&lds[boff[f]];
    }
#pragma unroll
    for (int i = 0; i < 4; ++i)
#pragma unroll
      for (int j = 0; j < 4; ++j)
        acc[i][j] = MFMA(af[i], bf[j], acc[i][j], 0, 0, 0);
  }

  const int by = blockIdx.y;
  if (by == 9) {
    if (wc == 0 && (lane & 15) < 8) {
      const int cl = lane & 15;
#pragma unroll
      for (int i = 0; i < 4; ++i) {
        const int r = m0 + wr * 64 + i * 16 + (lane >> 4) * 4;
#pragma unroll
        for (int g = 0; g < 4; ++g)
          dtraw[(size_t)(r + g) * 8 + cl] = acc[i][0][g];
      }
    }
    return;
  }
  __syncthreads();
#pragma unroll
  for (int i = 0; i < 4; ++i) {
    const int r = wr * 64 + i * 16 + (lane >> 4) * 4;
#pragma unroll
    for (int j = 0; j < 4; ++j) {
      const int ccol = wc * 64 + j * 16 + (lane & 15);
#pragma unroll
      for (int g = 0; g < 4; ++g)
        lds[(r + g) * 136 + ccol] = f2b(acc[i][j][g]);
    }
  }
  __syncthreads();
  const int rr = tid >> 1, hf = tid & 1;
  const int grow = m0 + rr;
  ushort* dst; int stride, colb;
  if (by < 4) { dst = zb;  stride = 512; colb = n0; }
  else        { dst = xbc; stride = 640; colb = n0 - 512; }
  ushort* dp = dst + (size_t)grow * stride + colb + hf * 64;
  const ushort* sp = &lds[rr * 136 + hf * 64];
#pragma unroll
  for (int q = 0; q < 8; ++q)
    *(s16x8*)(dp + q * 8) = *(const s16x8*)(sp + q * 8);
}

// ---------------------------------------------------------------------------
// out_proj GEMM: Cout = A(bf16) @ W^T, fp32 out with optional reversed-row
// write / accumulate.
// ---------------------------------------------------------------------------
__global__ __launch_bounds__(256) void k_gemmo(
    const ushort* __restrict__ A, int lda,
    const float* __restrict__ W, int N, int K,
    float* __restrict__ Cout, int crev, int accflag)
{
  __shared__ __align__(16) ushort lds[8192];
  const int tid = threadIdx.x;
  const int lane = tid & 63;
  const int wid = tid >> 6;
  const int wr = wid >> 1, wc = wid & 1;
  const int m0 = blockIdx.x * 128, n0 = blockIdx.y * 128;

  const int tr = tid >> 1;
  const int th = tid & 1;
  const int gm = m0 + tr;
  const ushort* Arow = A + (size_t)gm * lda + th * 16;
  const int wn = n0 + tr;
  const float* Wrow = (wn < N) ? (W + (size_t)wn * K + th * 16) : nullptr;

  const int asw0 = tr * 32 + swz(tr, th * 2) * 8;
  const int asw1 = tr * 32 + swz(tr, th * 2 + 1) * 8;

  f32x4 acc[4][4];
#pragma unroll
  for (int i = 0; i < 4; ++i)
#pragma unroll
    for (int j = 0; j < 4; ++j) acc[i][j] = (f32x4){0.f, 0.f, 0.f, 0.f};

  int aoff[4], boff[4];
#pragma unroll
  for (int f = 0; f < 4; ++f) {
    const int ar = wr * 64 + f * 16 + (lane & 15);
    aoff[f] = ar * 32 + swz(ar, lane >> 4) * 8;
    const int br = wc * 64 + f * 16 + (lane & 15);
    boff[f] = 4096 + br * 32 + swz(br, lane >> 4) * 8;
  }

  s16x8 a0 = *(const s16x8*)(Arow);
  s16x8 a1 = *(const s16x8*)(Arow + 8);
  float4 b0 = make_float4(0.f, 0.f, 0.f, 0.f), b1 = b0, b2 = b0, b3 = b0;
  if (Wrow) {
    b0 = *(const float4*)(Wrow + 0); b1 = *(const float4*)(Wrow + 4);
    b2 = *(const float4*)(Wrow + 8); b3 = *(const float4*)(Wrow + 12);
  }

  for (int k0 = 0; k0 < K; k0 += 32) {
    __syncthreads();
    {
      s16x8 pb0, pb1, d0;
      cvt8(b0, b1, pb0, d0); cvt8(b2, b3, pb1, d0);
      *(s16x8*)&lds[asw0] = a0;
      *(s16x8*)&lds[asw1] = a1;
      *(s16x8*)&lds[4096 + asw0] = pb0;
      *(s16x8*)&lds[4096 + asw1] = pb1;
    }
    __syncthreads();
    if (k0 + 32 < K) {
      a0 = *(const s16x8*)(Arow + k0 + 32);
      a1 = *(const s16x8*)(Arow + k0 + 40);
      if (Wrow) {
        const float* Wp = Wrow + k0 + 32;
        b0 = *(const float4*)(Wp + 0); b1 = *(const float4*)(Wp + 4);
        b2 = *(const float4*)(Wp + 8); b3 = *(const float4*)(Wp + 12);
      }
    }
    s16x8 af[4], bf[4];
#pragma unroll
    for (int f = 0; f < 4; ++f) {
      af[f] = *(const s16x8*)&lds[aoff[f]];
      bf[f] = *(const s16x8*)&lds[boff[f]];
    }
#pragma unroll
    for (int i = 0; i < 4; ++i)
#pragma unroll
      for (int j = 0; j < 4; ++j)
        acc[i][j] = MFMA(af[i], bf[j], acc[i][j], 0, 0, 0);
  }

#pragma unroll
  for (int i = 0; i < 4; ++i) {
    const int rb = m0 + wr * 64 + i * 16 + (lane >> 4) * 4;
#pragma unroll
    for (int g = 0; g < 4; ++g) {
      const int row = rb + g;
      const int b2_ = row >> 11, t2 = row & 2047;
      const int tw = crev ? (2047 - t2) : t2;
      float* crow = Cout + ((size_t)((b2_ << 11) + tw)) * 256 + n0 + wc * 64 + (lane & 15);
#pragma unroll
      for (int j = 0; j < 4; ++j) {
        const float v = acc[i][j][g];
        if (accflag) crow[j * 16] += v; else crow[j * 16] = v;
      }
    }
  }
}

// dt = softplus(dtraw + dt_bias); dtA = dt * exp(A_log)
__global__ __launch_bounds__(256) void k_dt(
    const float* __restrict__ dtraw, const float* __restrict__ dt_bias,
    const float* __restrict__ A_log, float* __restrict__ dt,
    float* __restrict__ dtA)
{
  const int i = blockIdx.x * 256 + threadIdx.x;
  const int h = i & 7;
  const float v = dtraw[i] + dt_bias[h];
  const float sp = (v > 20.f) ? v : log1pf(expf(v));
  dt[i] = sp;
  dtA[i] = sp * expf(A_log[h]);
}

// causal depthwise conv (k=4, bf16 in) + bias + silu -> fp32 xc
__global__ __launch_bounds__(256) void k_conv(
    const ushort* __restrict__ xbc, const float* __restrict__ Wc,
    const float* __restrict__ bc, float* __restrict__ xc)
{
  const int t = threadIdx.x;
  const int cg = blockIdx.x * 8 + (t & 7);
  const int rowt = blockIdx.y * 32 + (t >> 3);
  const int l = rowt & 2047;
  const int c0 = cg * 8;
  float4 wv[8];
  const float4* wp = (const float4*)(Wc + c0 * 4);
#pragma unroll
  for (int e = 0; e < 8; ++e) wv[e] = wp[e];
  float acc[8];
#pragma unroll
  for (int e = 0; e < 8; ++e) acc[e] = bc[c0 + e];
#pragma unroll
  for (int k = 0; k < 4; ++k) {
    const int lt = l - 3 + k;
    if (lt < 0) continue;
    const s16x8 v = *(const s16x8*)(xbc + (size_t)(rowt - 3 + k) * 640 + c0);
#pragma unroll
    for (int e = 0; e < 8; ++e)
      acc[e] = fmaf(b2f((ushort)v[e]), ((const float*)&wv[e])[k], acc[e]);
  }
  float* op = xc + (size_t)rowt * 640 + c0;
  float4 o0, o1;
  o0.x = siluf(acc[0]); o0.y = siluf(acc[1]); o0.z = siluf(acc[2]); o0.w = siluf(acc[3]);
  o1.x = siluf(acc[4]); o1.y = siluf(acc[5]); o1.z = siluf(acc[6]); o1.w = siluf(acc[7]);
  *(float4*)op = o0; *(float4*)(op + 4) = o1;
}

// ---------------------------------------------------------------------------
// Chunked SSD pass 1 (split-bf16 MFMA). P4 now emits the chunk-local state
// contribution in PACKED split-bf16 MFMA-B-fragment layout:
//   off(p,n) = ((p>>4)*2 + (n>>5))*512 + (((n>>3)&3)*16 + (p&15))*8 + (n&7)
// hi plane at hin[chunk*4096 + off], lo plane at +HIOFF.
// ---------------------------------------------------------------------------
__global__ __launch_bounds__(256) void k_scan1(
    float* __restrict__ xc, const float* __restrict__ dt,
    const float* __restrict__ dtA, const float* __restrict__ Dp,
    ushort* __restrict__ hin, float* __restrict__ Sbuf,
    float* __restrict__ PT)
{
  const int c = blockIdx.x & (NC - 1);
  const int bhi = blockIdx.x >> 5;
  const int b = bhi >> 3, h = bhi & 7;
  const int tid = threadIdx.x;
  const int lane = tid & 63;
  const int wid = tid >> 6;
  const int r0 = b * 2048 + c * TC;
  const int hbase = h * 64;
  __shared__ __align__(16) ushort tiles[27648];
  __shared__ float Ssh[64], dtsh[64], vsh[64];
  const int OBH = 0, OBL = 4608, OCH = 9216, OCL = 13824, OXH = 18432;

  if (tid < 64) {
    float a = dtA[(size_t)(r0 + tid) * 8 + h];
    const float d = dt[(size_t)(r0 + tid) * 8 + h];
#pragma unroll
    for (int off = 1; off < 64; off <<= 1) {
      const float t = __shfl_up(a, off);
      if (tid >= off) a += t;
    }
    const float slast = __shfl(a, 63);
    Ssh[tid] = a;
    dtsh[tid] = d;
    vsh[tid] = expf(a - slast) * d;
    Sbuf[(size_t)bhi * 2048 + c * TC + tid] = a;
    if (tid == 63) PT[bhi * NC + c] = expf(-slast);
  }
  {
    const int r = tid >> 2, c0 = (tid & 3) * 16;
    const float* rowp = xc + (size_t)(r0 + r) * 640;
    stage16(tiles, rowp + 512, OBH, OBL, r, c0);
    stage16(tiles, rowp + 576, OCH, OCL, r, c0);
    stage16(tiles, rowp + hbase, OXH, OXH + 4608, r, c0);
  }
  __syncthreads();

  const int ib = wid * 16;
  const int frow = lane & 15;
  const int fk = (lane >> 4) * 8;

  // ---- P2: G = C.B^T, weight, restage G~ over C space ----
  s16x8 pah[2], pal[2];
#pragma unroll
  for (int ks = 0; ks < 2; ++ks) {
    pah[ks] = *(const s16x8*)&tiles[soff(OCH, ib + frow, ks * 32 + fk)];
    pal[ks] = *(const s16x8*)&tiles[soff(OCL, ib + frow, ks * 32 + fk)];
  }
  f32x4 acc[4];
#pragma unroll
  for (int jt = 0; jt < 4; ++jt) acc[jt] = (f32x4){0.f, 0.f, 0.f, 0.f};
#pragma unroll
  for (int jt = 0; jt < 4; ++jt) {
#pragma unroll
    for (int ks = 0; ks < 2; ++ks) {
      const s16x8 tbh = *(const s16x8*)&tiles[soff(OBH, jt * 16 + frow, ks * 32 + fk)];
      const s16x8 tbl = *(const s16x8*)&tiles[soff(OBL, jt * 16 + frow, ks * 32 + fk)];
      acc[jt] = MFMA(pah[ks], tbh, acc[jt], 0, 0, 0);
      acc[jt] = MFMA(pah[ks], tbl, acc[jt], 0, 0, 0);
      acc[jt] = MFMA(pal[ks], tbh, acc[jt], 0, 0, 0);
    }
  }
  float Si[4];
#pragma unroll
  for (int g = 0; g < 4; ++g) Si[g] = Ssh[ib + (lane >> 4) * 4 + g];
#pragma unroll
  for (int jt = 0; jt < 4; ++jt) {
    const int j = jt * 16 + frow;
    const float Sj = Ssh[j], dj = dtsh[j];
#pragma unroll
    for (int g = 0; g < 4; ++g) {
      const int i = ib + (lane >> 4) * 4 + g;
      const float w = (j <= i) ? __expf(Sj - Si[g]) * dj : 0.f;
      const float gt = acc[jt][g] * w;
      const ushort gh = f2b(gt);
      tiles[soff(OCH, i, j)] = gh;
      tiles[soff(OCL, i, j)] = f2b(gt - b2f(gh));
    }
  }
  __syncthreads();

  // ---- P3: Ylocal = G~.X  (+ Dp*x via RMW) ----
  s16x8 gah[2], gal[2];
#pragma unroll
  for (int ks = 0; ks < 2; ++ks) {
    gah[ks] = *(const s16x8*)&tiles[soff(OCH, ib + frow, ks * 32 + fk)];
    gal[ks] = *(const s16x8*)&tiles[soff(OCL, ib + frow, ks * 32 + fk)];
  }
  const float dpv = Dp[h];
#pragma unroll
  for (int pt = 0; pt < 4; ++pt) {
    f32x4 accY = (f32x4){0.f, 0.f, 0.f, 0.f};
    const int p = pt * 16 + frow;
#pragma unroll
    for (int ks = 0; ks < 2; ++ks) {
      const int J0 = ks * 32 + fk;
      const int cb = OXH + J0 * SPITCH + (p & 7);
      const int g0 = (((p >> 3) ^ ((J0 >> 3) & 7)) << 3);
      s16x8 xh, xl;
#pragma unroll
      for (int e = 0; e < 8; ++e) {
        const int ad = cb + e * SPITCH + (g0 ^ (e << 3));
        xh[e] = (short)tiles[ad];
        xl[e] = (short)tiles[ad + 4608];
      }
      accY = MFMA(gah[ks], xh, accY, 0, 0, 0);
      accY = MFMA(gah[ks], xl, accY, 0, 0, 0);
      accY = MFMA(gal[ks], xh, accY, 0, 0, 0);
    }
#pragma unroll
    for (int g = 0; g < 4; ++g) {
      const int i = ib + (lane >> 4) * 4 + g;
      float* ap = xc + (size_t)(r0 + i) * 640 + hbase + p;
      *ap = accY[g] + dpv * (*ap);
    }
  }

  // ---- P4: contrib[p][n] = sum_j (v_j X[j][p]) B[j][n], packed output ----
  s16x8 xvh[2], xvl[2];
#pragma unroll
  for (int ks = 0; ks < 2; ++ks) {
    const int J0 = ks * 32 + fk;
    const int p = ib + frow;
    const int cb = OXH + J0 * SPITCH + (p & 7);
    const int g0 = (((p >> 3) ^ ((J0 >> 3) & 7)) << 3);
#pragma unroll
    for (int e = 0; e < 8; ++e) {
      const int ad = cb + e * SPITCH + (g0 ^ (e << 3));
      const float xf = (b2f(tiles[ad]) + b2f(tiles[ad + 4608])) * vsh[J0 + e];
      const ushort nh = f2b(xf);
      xvh[ks][e] = (short)nh;
      xvl[ks][e] = (short)f2b(xf - b2f(nh));
    }
  }
  ushort* hbp = hin + (((size_t)(bhi * NC + c)) << 12);
#pragma unroll
  for (int nt = 0; nt < 4; ++nt) {
    f32x4 accC = (f32x4){0.f, 0.f, 0.f, 0.f};
    const int n = nt * 16 + frow;
#pragma unroll
    for (int ks = 0; ks < 2; ++ks) {
      const int J0 = ks * 32 + fk;
      const int cb = OBH + J0 * SPITCH + (n & 7);
      const int g0 = (((n >> 3) ^ ((J0 >> 3) & 7)) << 3);
      s16x8 tbh, tbl;
#pragma unroll
      for (int e = 0; e < 8; ++e) {
        const int ad = cb + e * SPITCH + (g0 ^ (e << 3));
        tbh[e] = (short)tiles[ad];
        tbl[e] = (short)tiles[ad + 4608];
      }
      accC = MFMA(xvh[ks], tbh, accC, 0, 0, 0);
      accC = MFMA(xvh[ks], tbl, accC, 0, 0, 0);
      accC = MFMA(xvl[ks], tbh, accC, 0, 0, 0);
    }
    const int kss = nt >> 1;
    const int nlo3 = (n >> 3) & 3, ne = n & 7;
#pragma unroll
    for (int g = 0; g < 4; ++g) {
      const int plo = (lane >> 4) * 4 + g;
      const int off = ((wid * 2 + kss) << 9) + (nlo3 * 16 + plo) * 8 + ne;
      const float v = accC[g];
      const ushort vh = f2b(v);
      hbp[off] = vh;
      hbp[off + HIOFF] = f2b(v - b2f(vh));
    }
  }
}

// Pass 2: cross-chunk state propagation on packed split-bf16 hin (in place,
// exclusive scan; fp32 running state in registers).
__global__ __launch_bounds__(256) void k_scan2(
    ushort* __restrict__ hin, const float* __restrict__ PT)
{
  const int bh = blockIdx.x >> 2, jt = blockIdx.x & 3;
  const int t = threadIdx.x;
  float hv[4] = {0.f, 0.f, 0.f, 0.f};
  for (int c = 0; c < NC; ++c) {
    ushort* base = hin + (((size_t)(bh * NC + c)) << 12) + (jt << 10) + t * 4;
    const float pt = PT[bh * NC + c];
    const ushort4 uh = *(const ushort4*)base;
    const ushort4 ul = *(const ushort4*)(base + HIOFF);
    const float vals[4] = {b2f(uh.x) + b2f(ul.x), b2f(uh.y) + b2f(ul.y),
                           b2f(uh.z) + b2f(ul.z), b2f(uh.w) + b2f(ul.w)};
    ushort4 nh, nl;
    ushort* nhp = (ushort*)&nh; ushort* nlp = (ushort*)&nl;
#pragma unroll
    for (int k = 0; k < 4; ++k) {
      const float old = hv[k];
      hv[k] = fmaf(pt, hv[k], vals[k]);
      const ushort oh = f2b(old);
      nhp[k] = oh;
      nlp[k] = f2b(old - b2f(oh));
    }
    *(ushort4*)base = nh;
    *(ushort4*)(base + HIOFF) = nl;
  }
}

// ---------------------------------------------------------------------------
// Fused pass 3: per (b,chunk) block, 8 waves (wave = head).
//   Yst = C . H^T via split-bf16 MFMA (H-fragments loaded straight from the
//   packed hin, no LDS staging); y = (ylocal + exp(-S_i)*Yst)*silu(z);
//   fused RMSNorm over all 512 cols; bf16 output for the out-proj GEMM.
// ---------------------------------------------------------------------------
__global__ __launch_bounds__(512) void k_scan3f(
    const float* __restrict__ xc, const ushort* __restrict__ z,
    const ushort* __restrict__ hin, const float* __restrict__ Sbuf,
    const float* __restrict__ normw, ushort* __restrict__ ybf)
{
  const int c = blockIdx.x & (NC - 1);
  const int b = blockIdx.x >> 5;
  const int tid = threadIdx.x;
  const int lane = tid & 63;
  const int h = tid >> 6;
  const int r0 = b * 2048 + c * TC;
  const int frow = lane & 15;
  const int fk = (lane >> 4) * 8;
  __shared__ __align__(16) ushort ybuf[64 * 524];   // union: C hi/lo planes first
  __shared__ float Esh[8][64];
  __shared__ float partial[64][9];
  __shared__ float scale[64];

  // stage C hi/lo into the (soon recycled) ybuf region
  {
    const int r = tid >> 3, c0 = (tid & 7) * 8;
    const float4 v0 = *(const float4*)(xc + (size_t)(r0 + r) * 640 + 576 + c0);
    const float4 v1 = *(const float4*)(xc + (size_t)(r0 + r) * 640 + 576 + c0 + 4);
    s16x8 hh, ll;
    cvt8(v0, v1, hh, ll);
    *(s16x8*)&ybuf[soff(0, r, c0)] = hh;
    *(s16x8*)&ybuf[soff(4608, r, c0)] = ll;
  }
  Esh[h][lane] = expf(-Sbuf[(size_t)((b * 8 + h) << 11) + c * TC + lane]);
  __syncthreads();

  // H fragments from packed global (coalesced 16B/lane)
  const size_t cbase = ((size_t)((b * 8 + h) * NC + c)) << 12;
  s16x8 Bh[4][2], Bl[4][2];
  const ushort* hb = hin + cbase + lane * 8;
#pragma unroll
  for (int jt = 0; jt < 4; ++jt)
#pragma unroll
    for (int ks = 0; ks < 2; ++ks) {
      Bh[jt][ks] = *(const s16x8*)(hb + ((jt * 2 + ks) << 9));
      Bl[jt][ks] = *(const s16x8*)(hb + ((jt * 2 + ks) << 9) + HIOFF);
    }
  // C fragments from LDS
  s16x8 Ah[4][2], Al[4][2];
#pragma unroll
  for (int it = 0; it < 4; ++it)
#pragma unroll
    for (int ks = 0; ks < 2; ++ks) {
      Ah[it][ks] = *(const s16x8*)&ybuf[soff(0, it * 16 + frow, ks * 32 + fk)];
      Al[it][ks] = *(const s16x8*)&ybuf[soff(4608, it * 16 + frow, ks * 32 + fk)];
    }

  f32x4 acc[4][4];
#pragma unroll
  for (int it = 0; it < 4; ++it)
#pragma unroll
    for (int jt = 0; jt < 4; ++jt) acc[it][jt] = (f32x4){0.f, 0.f, 0.f, 0.f};
#pragma unroll
  for (int it = 0; it < 4; ++it)
#pragma unroll
    for (int jt = 0; jt < 4; ++jt)
#pragma unroll
      for (int ks = 0; ks < 2; ++ks) {
        acc[it][jt] = MFMA(Ah[it][ks], Bh[jt][ks], acc[it][jt], 0, 0, 0);
        acc[it][jt] = MFMA(Ah[it][ks], Bl[jt][ks], acc[it][jt], 0, 0, 0);
        acc[it][jt] = MFMA(Al[it][ks], Bh[jt][ks], acc[it][jt], 0, 0, 0);
      }

  // y = (ylocal + E*Yst) * silu(z); accumulate row sums of y^2
  float rowsq[4][4];
#pragma unroll
  for (int it = 0; it < 4; ++it)
#pragma unroll
    for (int g = 0; g < 4; ++g) rowsq[it][g] = 0.f;
#pragma unroll
  for (int it = 0; it < 4; ++it)
#pragma unroll
    for (int jt = 0; jt < 4; ++jt) {
      const int gcol = h * 64 + jt * 16 + frow;
#pragma unroll
      for (int g = 0; g < 4; ++g) {
        const int row = it * 16 + (lane >> 4) * 4 + g;
        const float yl = xc[(size_t)(r0 + row) * 640 + gcol];
        const float zf = b2f(z[(size_t)(r0 + row) * 512 + gcol]);
        const float y = (yl + Esh[h][row] * acc[it][jt][g]) * siluf(zf);
        acc[it][jt][g] = y;
        rowsq[it][g] = fmaf(y, y, rowsq[it][g]);
      }
    }
#pragma unroll
  for (int it = 0; it < 4; ++it)
#pragma unroll
    for (int g = 0; g < 4; ++g) {
      float s = rowsq[it][g];
      s += __shfl_xor(s, 1);
      s += __shfl_xor(s, 2);
      s += __shfl_xor(s, 4);
      s += __shfl_xor(s, 8);
      if (frow == 0) partial[it * 16 + (lane >> 4) * 4 + g][h] = s;
    }
  __syncthreads();
  if (tid < 64) {
    float s = 0.f;
#pragma unroll
    for (int hh = 0; hh < 8; ++hh) s += partial[tid][hh];
    scale[tid] = rsqrtf(s * (1.f / 512.f) + 1e-5f);
  }
  __syncthreads();

  float wreg[4];
#pragma unroll
  for (int jt = 0; jt < 4; ++jt) wreg[jt] = normw[h * 64 + jt * 16 + frow];
#pragma unroll
  for (int it = 0; it < 4; ++it)
#pragma unroll
    for (int jt = 0; jt < 4; ++jt) {
      const int col = h * 64 + jt * 16 + frow;
#pragma unroll
      for (int g = 0; g < 4; ++g) {
        const int row = it * 16 + (lane >> 4) * 4 + g;
        ybuf[row * 524 + col] = f2b(acc[it][jt][g] * scale[row] * wreg[jt]);
      }
    }
  __syncthreads();
#pragma unroll
  for (int j = 0; j < 8; ++j) {
    const int flat = j * 4096 + tid * 8;
    const int row = flat >> 9, col = flat & 511;
    const ushort4 u0 = *(const ushort4*)&ybuf[row * 524 + col];
    const ushort4 u1 = *(const ushort4*)&ybuf[row * 524 + col + 4];
    s16x8 o;
    o[0] = (short)u0.x; o[1] = (short)u0.y; o[2] = (short)u0.z; o[3] = (short)u0.w;
    o[4] = (short)u1.x; o[5] = (short)u1.y; o[6] = (short)u1.z; o[7] = (short)u1.w;
    *(s16x8*)(ybf + (size_t)(r0 + row) * 512 + col) = o;
  }
}

__global__ __launch_bounds__(256) void k_hpart(
    const float* __restrict__ hf, const float* __restrict__ hb,
    float* __restrict__ part)
{
  const int g = blockIdx.x;
  const int b = g >> 5, seg = g & 31;
  const int m = threadIdx.x;
  float s = 0.f;
  for (int l = seg * 64; l < seg * 64 + 64; ++l) {
    const size_t idx = ((size_t)b * 2048 + l) * 256 + m;
    s += hf[idx] + hb[idx];
  }
  part[(size_t)g * 256 + m] = s;
}

__global__ __launch_bounds__(256) void k_hfinal(
    const float* __restrict__ part, float* __restrict__ H)
{
  const int b = blockIdx.x;
  const int m = threadIdx.x;
  float s = 0.f;
  for (int g = 0; g < 32; ++g) s += part[(size_t)(b * 32 + g) * 256 + m];
  H[b * 256 + m] = s * (1.f / 2048.f);
}

extern "C" void kernel_launch(void* const* d_in, const int* in_sizes, int n_in,
                              void* d_out, int out_size, void* d_ws, size_t ws_size,
                              hipStream_t stream) {
  const float* x_in = (const float*)d_in[0];
  const float* Win[2]    = {(const float*)d_in[1],  (const float*)d_in[9]};
  const float* Wconv[2]  = {(const float*)d_in[2],  (const float*)d_in[10]};
  const float* bconv[2]  = {(const float*)d_in[3],  (const float*)d_in[11]};
  const float* dtbias[2] = {(const float*)d_in[4],  (const float*)d_in[12]};
  const float* Alog[2]   = {(const float*)d_in[5],  (const float*)d_in[13]};
  const float* Dpar[2]   = {(const float*)d_in[6],  (const float*)d_in[14]};
  const float* normw[2]  = {(const float*)d_in[7],  (const float*)d_in[15]};
  const float* Wout[2]   = {(const float*)d_in[8],  (const float*)d_in[16]};

  float* ws = (float*)d_ws;
  ushort* zb    = (ushort*)ws;                       // 16384x512 bf16
  ushort* xbcb  = (ushort*)(ws + 4194304);           // 16384x640 bf16 (conv in)
  ushort* ybf   = xbcb;                              // reuse after conv: 16384x512 bf16
  ushort* hinp  = (ushort*)(ws + 9437184);           // packed hi/lo planes, 2x8,388,608 ushorts
  float* xc      = ws + 17825792;                    // 10485760
  float* dtraw   = ws + 28311552;                    // 131072
  float* dtb     = dtraw + 131072;
  float* dab     = dtb + 131072;
  float* Sbuf    = dab + 131072;                     // 131072
  float* xA      = Sbuf + 131072;                    // 4194304
  float* xB      = xA + 4194304;                     // 4194304
  float* part    = xB + 4194304;                     // 65536 (PT in first 2048)

  float* hF = (float*)d_out;
  float* hB = hF + (size_t)8 * 2048 * 256;
  float* Hm = hB + (size_t)8 * 2048 * 256;

  const float* cur = x_in;
  for (int layer = 0; layer < 4; ++layer) {
    float* nxt = (layer == 0) ? xA : (layer == 1) ? xB : (layer == 2) ? xA : nullptr;
    for (int dir = 0; dir < 2; ++dir) {
      const float* Wi = Win[dir]    + (size_t)layer * 1160 * 256;
      const float* Wc = Wconv[dir]  + (size_t)layer * 640 * 4;
      const float* bc = bconv[dir]  + (size_t)layer * 640;
      const float* db = dtbias[dir] + (size_t)layer * 8;
      const float* Al = Alog[dir]   + (size_t)layer * 8;
      const float* Dl = Dpar[dir]   + (size_t)layer * 8;
      const float* nw = normw[dir]  + (size_t)layer * 512;
      const float* Wo = Wout[dir]   + (size_t)layer * 256 * 512;

      k_gemmb<<<dim3(128, 10), 256, 0, stream>>>(cur, 256, dir, Wi, 1160, 256,
                                                 zb, xbcb, dtraw);
      k_dt<<<512, 256, 0, stream>>>(dtraw, db, Al, dtb, dab);
      k_conv<<<dim3(10, 512), 256, 0, stream>>>(xbcb, Wc, bc, xc);
      k_scan1<<<2048, 256, 0, stream>>>(xc, dtb, dab, Dl, hinp, Sbuf, part);
      k_scan2<<<256, 256, 0, stream>>>(hinp, part);
      k_scan3f<<<256, 512, 0, stream>>>(xc, zb, hinp, Sbuf, nw, ybf);
      float* outp;
      int accf;
      if (layer < 3) { outp = nxt; accf = dir; }
      else           { outp = dir ? hB : hF; accf = 0; }
      k_gemmo<<<dim3(128, 2), 256, 0, stream>>>(ybf, 512, Wo, 256, 512,
                                                outp, dir, accf);
    }
    cur = nxt;
  }
  k_hpart<<<256, 256, 0, stream>>>(hF, hB, part);
  k_hfinal<<<8, 256, 0, stream>>>(part, Hm);
}

// Round 6
// 1389.461 us; speedup vs baseline: 5.8753x; 1.0557x over previous
//
#include <hip/hip_runtime.h>
#include <math.h>

// MicroEncoder: 4-layer bidirectional Mamba2.
// B=8, L=2048, D_MODEL=256, D_INNER=512, NHEADS=8, HEADDIM=64, D_STATE=64,
// CONV_DIM=640, D_IN_PROJ=1160.
// Round 6: k_scan1 transposed operands (Xt, Bt) built ONCE in LDS via
// register-buffered in-place transpose; all P3/P4 fragments become swizzled
// ds_read_b128 (bank-uniform). 6-plane 48KB layout -> 3 blocks/CU.
// Everything else identical to round 5.

#define TC 64
#define NC 32
#define SPITCH 72
#define HIOFF 8388608   // ushort offset of the lo plane in packed hin

typedef __attribute__((ext_vector_type(4))) float f32x4;
typedef __attribute__((ext_vector_type(8))) short s16x8;

#define MFMA __builtin_amdgcn_mfma_f32_16x16x32_bf16

__device__ __forceinline__ float siluf(float x) { return x / (1.f + expf(-x)); }

// fp32 -> bf16 round-to-nearest-even (finite inputs)
__device__ __forceinline__ ushort f2b(float f) {
  union { float f; uint u; } v; v.f = f;
  return (ushort)((v.u + 0x7FFFu + ((v.u >> 16) & 1u)) >> 16);
}
__device__ __forceinline__ float b2f(ushort u) {
  union { uint u; float f; } v; v.u = ((uint)u) << 16; return v.f;
}
__device__ __forceinline__ int swz(int r, int c) { return c ^ (r & 3) ^ ((r >> 2) & 3); }

// scan3f LDS tile addressing (pitch-72, unchanged from round 5)
__device__ __forceinline__ int soff(int base, int r, int cc) {
  return base + r * SPITCH + ((((cc >> 3) ^ (r & 7) ^ ((r >> 3) & 7)) << 3) | (cc & 7));
}

// scan1 tile addressing: pitch-64 ushort rows, 8-elem (16B) chunks XOR-swizzled
// by row&7. b128 fragment reads land uniformly on banks (8 dwords/bank).
__device__ __forceinline__ int toff(int base, int r, int cc) {
  return base + r * 64 + ((((cc >> 3) ^ (r & 7)) << 3) | (cc & 7));
}

__device__ __forceinline__ void cvt8(const float4 v0, const float4 v1, s16x8& hh, s16x8& ll) {
  const float a[8] = {v0.x, v0.y, v0.z, v0.w, v1.x, v1.y, v1.z, v1.w};
#pragma unroll
  for (int e = 0; e < 8; ++e) {
    const ushort hb = f2b(a[e]);
    hh[e] = (short)hb;
    ll[e] = (short)f2b(a[e] - b2f(hb));
  }
}

// stage 16 fp32 -> hi/lo bf16 planes at (r, c0..c0+15), toff layout
__device__ __forceinline__ void stage16t(ushort* tiles, const float* src,
                                         int bh_, int bl_, int r, int c0) {
  const float4 v0 = *(const float4*)(src + c0);
  const float4 v1 = *(const float4*)(src + c0 + 4);
  const float4 v2 = *(const float4*)(src + c0 + 8);
  const float4 v3 = *(const float4*)(src + c0 + 12);
  s16x8 h0, l0, h1, l1;
  cvt8(v0, v1, h0, l0);
  cvt8(v2, v3, h1, l1);
  *(s16x8*)&tiles[toff(bh_, r, c0)]     = h0;
  *(s16x8*)&tiles[toff(bl_, r, c0)]     = l0;
  *(s16x8*)&tiles[toff(bh_, r, c0 + 8)] = h1;
  *(s16x8*)&tiles[toff(bl_, r, c0 + 8)] = l1;
}

// ---------------------------------------------------------------------------
// bf16 MFMA GEMM (in_proj): C = A @ W^T, A fp32 (optional row reversal).
// Epilogue routes z (bf16) / xBC (bf16) / dtraw (fp32).  (unchanged)
// ---------------------------------------------------------------------------
__global__ __launch_bounds__(256) void k_gemmb(
    const float* __restrict__ A, int lda, int arev,
    const float* __restrict__ W, int N, int K,
    ushort* __restrict__ zb, ushort* __restrict__ xbc, float* __restrict__ dtraw)
{
  __shared__ __align__(16) ushort lds[17408];
  const int tid = threadIdx.x;
  const int lane = tid & 63;
  const int wid = tid >> 6;
  const int wr = wid >> 1, wc = wid & 1;
  const int m0 = blockIdx.x * 128, n0 = blockIdx.y * 128;

  const int tr = tid >> 1;
  const int th = tid & 1;
  const int gm = m0 + tr;
  const int bb = gm >> 11, tt = gm & 2047;
  const int tphys = arev ? (2047 - tt) : tt;
  const float* Arow = A + (size_t)((bb << 11) + tphys) * lda + th * 16;
  const int wn = n0 + tr;
  const float* Wrow = (wn < N) ? (W + (size_t)wn * K + th * 16) : nullptr;

  const int asw0 = tr * 32 + swz(tr, th * 2) * 8;
  const int asw1 = tr * 32 + swz(tr, th * 2 + 1) * 8;

  f32x4 acc[4][4];
#pragma unroll
  for (int i = 0; i < 4; ++i)
#pragma unroll
    for (int j = 0; j < 4; ++j) acc[i][j] = (f32x4){0.f, 0.f, 0.f, 0.f};

  int aoff[4], boff[4];
#pragma unroll
  for (int f = 0; f < 4; ++f) {
    const int ar = wr * 64 + f * 16 + (lane & 15);
    aoff[f] = ar * 32 + swz(ar, lane >> 4) * 8;
    const int br = wc * 64 + f * 16 + (lane & 15);
    boff[f] = 4096 + br * 32 + swz(br, lane >> 4) * 8;
  }

  float4 a0, a1, a2, a3;
  float4 b0 = make_float4(0.f, 0.f, 0.f, 0.f), b1 = b0, b2 = b0, b3 = b0;
  a0 = *(const float4*)(Arow + 0); a1 = *(const float4*)(Arow + 4);
  a2 = *(const float4*)(Arow + 8); a3 = *(const float4*)(Arow + 12);
  if (Wrow) {
    b0 = *(const float4*)(Wrow + 0); b1 = *(const float4*)(Wrow + 4);
    b2 = *(const float4*)(Wrow + 8); b3 = *(const float4*)(Wrow + 12);
  }

  for (int k0 = 0; k0 < K; k0 += 32) {
    __syncthreads();
    {
      s16x8 pa0, pa1, pb0, pb1;
      s16x8 d0, d1;
      cvt8(a0, a1, pa0, d0); cvt8(a2, a3, pa1, d1);
      cvt8(b0, b1, pb0, d0); cvt8(b2, b3, pb1, d1);
      *(s16x8*)&lds[asw0] = pa0;
      *(s16x8*)&lds[asw1] = pa1;
      *(s16x8*)&lds[4096 + asw0] = pb0;
      *(s16x8*)&lds[4096 + asw1] = pb1;
    }
    __syncthreads();
    if (k0 + 32 < K) {
      const float* Ap = Arow + k0 + 32;
      a0 = *(const float4*)(Ap + 0); a1 = *(const float4*)(Ap + 4);
      a2 = *(const float4*)(Ap + 8); a3 = *(const float4*)(Ap + 12);
      if (Wrow) {
        const float* Wp = Wrow + k0 + 32;
        b0 = *(const float4*)(Wp + 0); b1 = *(const float4*)(Wp + 4);
        b2 = *(const float4*)(Wp + 8); b3 = *(const float4*)(Wp + 12);
      }
    }
    s16x8 af[4], bf[4];
#pragma unroll
    for (int f = 0; f < 4; ++f) {
      af[f] = *(const s16x8*)&lds[aoff[f]];
      bf[f] = *(const s16x8*)&lds[boff[f]];
    }
#pragma unroll
    for (int i = 0; i < 4; ++i)
#pragma unroll
      for (int j = 0; j < 4; ++j)
        acc[i][j] = MFMA(af[i], bf[j], acc[i][j], 0, 0, 0);
  }

  const int by = blockIdx.y;
  if (by == 9) {
    if (wc == 0 && (lane & 15) < 8) {
      const int cl = lane & 15;
#pragma unroll
      for (int i = 0; i < 4; ++i) {
        const int r = m0 + wr * 64 + i * 16 + (lane >> 4) * 4;
#pragma unroll
        for (int g = 0; g < 4; ++g)
          dtraw[(size_t)(r + g) * 8 + cl] = acc[i][0][g];
      }
    }
    return;
  }
  __syncthreads();
#pragma unroll
  for (int i = 0; i < 4; ++i) {
    const int r = wr * 64 + i * 16 + (lane >> 4) * 4;
#pragma unroll
    for (int j = 0; j < 4; ++j) {
      const int ccol = wc * 64 + j * 16 + (lane & 15);
#pragma unroll
      for (int g = 0; g < 4; ++g)
        lds[(r + g) * 136 + ccol] = f2b(acc[i][j][g]);
    }
  }
  __syncthreads();
  const int rr = tid >> 1, hf = tid & 1;
  const int grow = m0 + rr;
  ushort* dst; int stride, colb;
  if (by < 4) { dst = zb;  stride = 512; colb = n0; }
  else        { dst = xbc; stride = 640; colb = n0 - 512; }
  ushort* dp = dst + (size_t)grow * stride + colb + hf * 64;
  const ushort* sp = &lds[rr * 136 + hf * 64];
#pragma unroll
  for (int q = 0; q < 8; ++q)
    *(s16x8*)(dp + q * 8) = *(const s16x8*)(sp + q * 8);
}

// ---------------------------------------------------------------------------
// out_proj GEMM: Cout = A(bf16) @ W^T.  (unchanged)
// ---------------------------------------------------------------------------
__global__ __launch_bounds__(256) void k_gemmo(
    const ushort* __restrict__ A, int lda,
    const float* __restrict__ W, int N, int K,
    float* __restrict__ Cout, int crev, int accflag)
{
  __shared__ __align__(16) ushort lds[8192];
  const int tid = threadIdx.x;
  const int lane = tid & 63;
  const int wid = tid >> 6;
  const int wr = wid >> 1, wc = wid & 1;
  const int m0 = blockIdx.x * 128, n0 = blockIdx.y * 128;

  const int tr = tid >> 1;
  const int th = tid & 1;
  const int gm = m0 + tr;
  const ushort* Arow = A + (size_t)gm * lda + th * 16;
  const int wn = n0 + tr;
  const float* Wrow = (wn < N) ? (W + (size_t)wn * K + th * 16) : nullptr;

  const int asw0 = tr * 32 + swz(tr, th * 2) * 8;
  const int asw1 = tr * 32 + swz(tr, th * 2 + 1) * 8;

  f32x4 acc[4][4];
#pragma unroll
  for (int i = 0; i < 4; ++i)
#pragma unroll
    for (int j = 0; j < 4; ++j) acc[i][j] = (f32x4){0.f, 0.f, 0.f, 0.f};

  int aoff[4], boff[4];
#pragma unroll
  for (int f = 0; f < 4; ++f) {
    const int ar = wr * 64 + f * 16 + (lane & 15);
    aoff[f] = ar * 32 + swz(ar, lane >> 4) * 8;
    const int br = wc * 64 + f * 16 + (lane & 15);
    boff[f] = 4096 + br * 32 + swz(br, lane >> 4) * 8;
  }

  s16x8 a0 = *(const s16x8*)(Arow);
  s16x8 a1 = *(const s16x8*)(Arow + 8);
  float4 b0 = make_float4(0.f, 0.f, 0.f, 0.f), b1 = b0, b2 = b0, b3 = b0;
  if (Wrow) {
    b0 = *(const float4*)(Wrow + 0); b1 = *(const float4*)(Wrow + 4);
    b2 = *(const float4*)(Wrow + 8); b3 = *(const float4*)(Wrow + 12);
  }

  for (int k0 = 0; k0 < K; k0 += 32) {
    __syncthreads();
    {
      s16x8 pb0, pb1, d0;
      cvt8(b0, b1, pb0, d0); cvt8(b2, b3, pb1, d0);
      *(s16x8*)&lds[asw0] = a0;
      *(s16x8*)&lds[asw1] = a1;
      *(s16x8*)&lds[4096 + asw0] = pb0;
      *(s16x8*)&lds[4096 + asw1] = pb1;
    }
    __syncthreads();
    if (k0 + 32 < K) {
      a0 = *(const s16x8*)(Arow + k0 + 32);
      a1 = *(const s16x8*)(Arow + k0 + 40);
      if (Wrow) {
        const float* Wp = Wrow + k0 + 32;
        b0 = *(const float4*)(Wp + 0); b1 = *(const float4*)(Wp + 4);
        b2 = *(const float4*)(Wp + 8); b3 = *(const float4*)(Wp + 12);
      }
    }
    s16x8 af[4], bf[4];
#pragma unroll
    for (int f = 0; f < 4; ++f) {
      af[f] = *(const s16x8*)&lds[aoff[f]];
      bf[f] = *(const s16x8*)&lds[boff[f]];
    }
#pragma unroll
    for (int i = 0; i < 4; ++i)
#pragma unroll
      for (int j = 0; j < 4; ++j)
        acc[i][j] = MFMA(af[i], bf[j], acc[i][j], 0, 0, 0);
  }

#pragma unroll
  for (int i = 0; i < 4; ++i) {
    const int rb = m0 + wr * 64 + i * 16 + (lane >> 4) * 4;
#pragma unroll
    for (int g = 0; g < 4; ++g) {
      const int row = rb + g;
      const int b2_ = row >> 11, t2 = row & 2047;
      const int tw = crev ? (2047 - t2) : t2;
      float* crow = Cout + ((size_t)((b2_ << 11) + tw)) * 256 + n0 + wc * 64 + (lane & 15);
#pragma unroll
      for (int j = 0; j < 4; ++j) {
        const float v = acc[i][j][g];
        if (accflag) crow[j * 16] += v; else crow[j * 16] = v;
      }
    }
  }
}

// dt = softplus(dtraw + dt_bias); dtA = dt * exp(A_log)
__global__ __launch_bounds__(256) void k_dt(
    const float* __restrict__ dtraw, const float* __restrict__ dt_bias,
    const float* __restrict__ A_log, float* __restrict__ dt,
    float* __restrict__ dtA)
{
  const int i = blockIdx.x * 256 + threadIdx.x;
  const int h = i & 7;
  const float v = dtraw[i] + dt_bias[h];
  const float sp = (v > 20.f) ? v : log1pf(expf(v));
  dt[i] = sp;
  dtA[i] = sp * expf(A_log[h]);
}

// causal depthwise conv (k=4, bf16 in) + bias + silu -> fp32 xc  (unchanged)
__global__ __launch_bounds__(256) void k_conv(
    const ushort* __restrict__ xbc, const float* __restrict__ Wc,
    const float* __restrict__ bc, float* __restrict__ xc)
{
  const int t = threadIdx.x;
  const int cg = blockIdx.x * 8 + (t & 7);
  const int rowt = blockIdx.y * 32 + (t >> 3);
  const int l = rowt & 2047;
  const int c0 = cg * 8;
  float4 wv[8];
  const float4* wp = (const float4*)(Wc + c0 * 4);
#pragma unroll
  for (int e = 0; e < 8; ++e) wv[e] = wp[e];
  float acc[8];
#pragma unroll
  for (int e = 0; e < 8; ++e) acc[e] = bc[c0 + e];
#pragma unroll
  for (int k = 0; k < 4; ++k) {
    const int lt = l - 3 + k;
    if (lt < 0) continue;
    const s16x8 v = *(const s16x8*)(xbc + (size_t)(rowt - 3 + k) * 640 + c0);
#pragma unroll
    for (int e = 0; e < 8; ++e)
      acc[e] = fmaf(b2f((ushort)v[e]), ((const float*)&wv[e])[k], acc[e]);
  }
  float* op = xc + (size_t)rowt * 640 + c0;
  float4 o0, o1;
  o0.x = siluf(acc[0]); o0.y = siluf(acc[1]); o0.z = siluf(acc[2]); o0.w = siluf(acc[3]);
  o1.x = siluf(acc[4]); o1.y = siluf(acc[5]); o1.z = siluf(acc[6]); o1.w = siluf(acc[7]);
  *(float4*)op = o0; *(float4*)(op + 4) = o1;
}

// ---------------------------------------------------------------------------
// Chunked SSD pass 1 (split-bf16 MFMA, transposed-operand version).
// 6 LDS planes (4096 ushorts each, toff layout):
//   PCH/PCL: C hi/lo  -> overwritten by G~ hi/lo (own-slab, no hazard)
//   PBH/PBL: B hi/lo  -> overwritten by Bt hi/lo after sync2
//   PXH/PXL: X hi/lo  -> overwritten by Xt hi/lo after sync2
// Schedule: stage naturals; sync1; {transpose-gather Xt/Bt to regs | P2 MFMA
// + weight + G~ store}; sync2; write Xt/Bt; sync3; P3 (Y=G~.Xt), P4 (contrib).
// All fragment reads are swizzled ds_read_b128 (bank-uniform).
// ---------------------------------------------------------------------------
__global__ __launch_bounds__(256) void k_scan1(
    float* __restrict__ xc, const float* __restrict__ dt,
    const float* __restrict__ dtA, const float* __restrict__ Dp,
    ushort* __restrict__ hin, float* __restrict__ Sbuf,
    float* __restrict__ PT)
{
  const int c = blockIdx.x & (NC - 1);
  const int bhi = blockIdx.x >> 5;
  const int b = bhi >> 3, h = bhi & 7;
  const int tid = threadIdx.x;
  const int lane = tid & 63;
  const int wid = tid >> 6;
  const int r0 = b * 2048 + c * TC;
  const int hbase = h * 64;
  __shared__ __align__(16) ushort tiles[24576];
  __shared__ float Ssh[64], dtsh[64], vsh[64];
  enum { PCH = 0, PCL = 4096, PBH = 8192, PBL = 12288, PXH = 16384, PXL = 20480 };

  // P0: prefix sums over dtA (log-space decay), v_j weights
  if (tid < 64) {
    float a = dtA[(size_t)(r0 + tid) * 8 + h];
    const float d = dt[(size_t)(r0 + tid) * 8 + h];
#pragma unroll
    for (int off = 1; off < 64; off <<= 1) {
      const float t = __shfl_up(a, off);
      if (tid >= off) a += t;
    }
    const float slast = __shfl(a, 63);
    Ssh[tid] = a;
    dtsh[tid] = d;
    vsh[tid] = expf(a - slast) * d;
    Sbuf[(size_t)bhi * 2048 + c * TC + tid] = a;
    if (tid == 63) PT[bhi * NC + c] = expf(-slast);
  }
  // P1: stage B, C, X natural (hi/lo)
  {
    const int r = tid >> 2, c0 = (tid & 3) * 16;
    const float* rowp = xc + (size_t)(r0 + r) * 640;
    stage16t(tiles, rowp + 512, PBH, PBL, r, c0);
    stage16t(tiles, rowp + 576, PCH, PCL, r, c0);
    stage16t(tiles, rowp + hbase, PXH, PXL, r, c0);
  }
  __syncthreads();   // sync1

  const int ib = wid * 16;
  const int frow = lane & 15;
  const int fkc = lane >> 4;       // k sub-chunk 0..3

  // transpose-gather Xt/Bt shares into registers (reads Xn, B naturals)
  const int tp = tid >> 2;               // dest row (p or n)
  const int tj0 = (tid & 3) * 16;        // dest col base (two 8-chunks)
  s16x8 xtr[4], btr[4];                  // [chunk 0/1 hi, chunk 0/1 lo]
#pragma unroll
  for (int cc = 0; cc < 2; ++cc) {
    const int j0 = tj0 + cc * 8;
    s16x8 vh, vl, wh, wl;
#pragma unroll
    for (int e = 0; e < 8; ++e) {
      const int ax = toff(PXH, j0 + e, tp);
      vh[e] = (short)tiles[ax];
      vl[e] = (short)tiles[ax + 4096];
      const int ab = toff(PBH, j0 + e, tp);
      wh[e] = (short)tiles[ab];
      wl[e] = (short)tiles[ab + 4096];
    }
    xtr[cc] = vh; xtr[cc + 2] = vl;
    btr[cc] = wh; btr[cc + 2] = wl;
  }

  // ---- P2: G = C.B^T (split MFMA), weight, G~ store over C planes ----
  s16x8 pah[2], pal[2];
#pragma unroll
  for (int ks = 0; ks < 2; ++ks) {
    pah[ks] = *(const s16x8*)&tiles[toff(PCH, ib + frow, ks * 32 + fkc * 8)];
    pal[ks] = *(const s16x8*)&tiles[toff(PCL, ib + frow, ks * 32 + fkc * 8)];
  }
  f32x4 acc[4];
#pragma unroll
  for (int jt = 0; jt < 4; ++jt) acc[jt] = (f32x4){0.f, 0.f, 0.f, 0.f};
#pragma unroll
  for (int jt = 0; jt < 4; ++jt) {
#pragma unroll
    for (int ks = 0; ks < 2; ++ks) {
      const s16x8 tbh = *(const s16x8*)&tiles[toff(PBH, jt * 16 + frow, ks * 32 + fkc * 8)];
      const s16x8 tbl = *(const s16x8*)&tiles[toff(PBL, jt * 16 + frow, ks * 32 + fkc * 8)];
      acc[jt] = MFMA(pah[ks], tbh, acc[jt], 0, 0, 0);
      acc[jt] = MFMA(pah[ks], tbl, acc[jt], 0, 0, 0);
      acc[jt] = MFMA(pal[ks], tbh, acc[jt], 0, 0, 0);
    }
  }
  float Si[4];
#pragma unroll
  for (int g = 0; g < 4; ++g) Si[g] = Ssh[ib + fkc * 4 + g];
#pragma unroll
  for (int jt = 0; jt < 4; ++jt) {
    const int j = jt * 16 + frow;
    const float Sj = Ssh[j], dj = dtsh[j];
#pragma unroll
    for (int g = 0; g < 4; ++g) {
      const int i = ib + fkc * 4 + g;
      const float w = (j <= i) ? __expf(Sj - Si[g]) * dj : 0.f;
      const float gt = acc[jt][g] * w;
      const ushort gh = f2b(gt);
      tiles[toff(PCH, i, j)] = gh;
      tiles[toff(PCL, i, j)] = f2b(gt - b2f(gh));
    }
  }
  __syncthreads();   // sync2: naturals fully consumed

  // write Xt over X planes, Bt over B planes (b128, swizzled)
#pragma unroll
  for (int cc = 0; cc < 2; ++cc) {
    *(s16x8*)&tiles[toff(PXH, tp, tj0 + cc * 8)] = xtr[cc];
    *(s16x8*)&tiles[toff(PXL, tp, tj0 + cc * 8)] = xtr[cc + 2];
    *(s16x8*)&tiles[toff(PBH, tp, tj0 + cc * 8)] = btr[cc];
    *(s16x8*)&tiles[toff(PBL, tp, tj0 + cc * 8)] = btr[cc + 2];
  }
  __syncthreads();   // sync3

  // ---- P3: Ylocal = G~ . X  (B-op from Xt, all b128)  + Dp*x RMW ----
  s16x8 gah[2], gal[2];
#pragma unroll
  for (int ks = 0; ks < 2; ++ks) {
    gah[ks] = *(const s16x8*)&tiles[toff(PCH, ib + frow, ks * 32 + fkc * 8)];
    gal[ks] = *(const s16x8*)&tiles[toff(PCL, ib + frow, ks * 32 + fkc * 8)];
  }
  const float dpv = Dp[h];
#pragma unroll
  for (int pt = 0; pt < 4; ++pt) {
    f32x4 accY = (f32x4){0.f, 0.f, 0.f, 0.f};
#pragma unroll
    for (int ks = 0; ks < 2; ++ks) {
      const s16x8 xh = *(const s16x8*)&tiles[toff(PXH, pt * 16 + frow, ks * 32 + fkc * 8)];
      const s16x8 xl = *(const s16x8*)&tiles[toff(PXL, pt * 16 + frow, ks * 32 + fkc * 8)];
      accY = MFMA(gah[ks], xh, accY, 0, 0, 0);
      accY = MFMA(gah[ks], xl, accY, 0, 0, 0);
      accY = MFMA(gal[ks], xh, accY, 0, 0, 0);
    }
    const int p = pt * 16 + frow;
#pragma unroll
    for (int g = 0; g < 4; ++g) {
      const int i = ib + fkc * 4 + g;
      float* ap = xc + (size_t)(r0 + i) * 640 + hbase + p;
      *ap = accY[g] + dpv * (*ap);
    }
  }

  // ---- P4: contrib[p][n] = sum_j (v_j X[j][p]) B[j][n], packed output ----
  s16x8 xvh[2], xvl[2];
#pragma unroll
  for (int ks = 0; ks < 2; ++ks) {
    const int J0 = ks * 32 + fkc * 8;
    const s16x8 xh = *(const s16x8*)&tiles[toff(PXH, ib + frow, J0)];
    const s16x8 xl = *(const s16x8*)&tiles[toff(PXL, ib + frow, J0)];
#pragma unroll
    for (int e = 0; e < 8; ++e) {
      const float xf = (b2f((ushort)xh[e]) + b2f((ushort)xl[e])) * vsh[J0 + e];
      const ushort nh = f2b(xf);
      xvh[ks][e] = (short)nh;
      xvl[ks][e] = (short)f2b(xf - b2f(nh));
    }
  }
  ushort* hbp = hin + (((size_t)(bhi * NC + c)) << 12);
#pragma unroll
  for (int nt = 0; nt < 4; ++nt) {
    f32x4 accC = (f32x4){0.f, 0.f, 0.f, 0.f};
#pragma unroll
    for (int ks = 0; ks < 2; ++ks) {
      const s16x8 tbh = *(const s16x8*)&tiles[toff(PBH, nt * 16 + frow, ks * 32 + fkc * 8)];
      const s16x8 tbl = *(const s16x8*)&tiles[toff(PBL, nt * 16 + frow, ks * 32 + fkc * 8)];
      accC = MFMA(xvh[ks], tbh, accC, 0, 0, 0);
      accC = MFMA(xvh[ks], tbl, accC, 0, 0, 0);
      accC = MFMA(xvl[ks], tbh, accC, 0, 0, 0);
    }
    const int n = nt * 16 + frow;
    const int kss = nt >> 1;
    const int nlo3 = (n >> 3) & 3, ne = n & 7;
#pragma unroll
    for (int g = 0; g < 4; ++g) {
      const int plo = fkc * 4 + g;
      const int off = ((wid * 2 + kss) << 9) + (nlo3 * 16 + plo) * 8 + ne;
      const float v = accC[g];
      const ushort vh = f2b(v);
      hbp[off] = vh;
      hbp[off + HIOFF] = f2b(v - b2f(vh));
    }
  }
}

// Pass 2: cross-chunk state propagation on packed split-bf16 hin (unchanged).
__global__ __launch_bounds__(256) void k_scan2(
    ushort* __restrict__ hin, const float* __restrict__ PT)
{
  const int bh = blockIdx.x >> 2, jt = blockIdx.x & 3;
  const int t = threadIdx.x;
  float hv[4] = {0.f, 0.f, 0.f, 0.f};
  for (int c = 0; c < NC; ++c) {
    ushort* base = hin + (((size_t)(bh * NC + c)) << 12) + (jt << 10) + t * 4;
    const float pt = PT[bh * NC + c];
    const ushort4 uh = *(const ushort4*)base;
    const ushort4 ul = *(const ushort4*)(base + HIOFF);
    const float vals[4] = {b2f(uh.x) + b2f(ul.x), b2f(uh.y) + b2f(ul.y),
                           b2f(uh.z) + b2f(ul.z), b2f(uh.w) + b2f(ul.w)};
    ushort4 nh, nl;
    ushort* nhp = (ushort*)&nh; ushort* nlp = (ushort*)&nl;
#pragma unroll
    for (int k = 0; k < 4; ++k) {
      const float old = hv[k];
      hv[k] = fmaf(pt, hv[k], vals[k]);
      const ushort oh = f2b(old);
      nhp[k] = oh;
      nlp[k] = f2b(old - b2f(oh));
    }
    *(ushort4*)base = nh;
    *(ushort4*)(base + HIOFF) = nl;
  }
}

// ---------------------------------------------------------------------------
// Fused pass 3 (unchanged from round 5).
// ---------------------------------------------------------------------------
__global__ __launch_bounds__(512) void k_scan3f(
    const float* __restrict__ xc, const ushort* __restrict__ z,
    const ushort* __restrict__ hin, const float* __restrict__ Sbuf,
    const float* __restrict__ normw, ushort* __restrict__ ybf)
{
  const int c = blockIdx.x & (NC - 1);
  const int b = blockIdx.x >> 5;
  const int tid = threadIdx.x;
  const int lane = tid & 63;
  const int h = tid >> 6;
  const int r0 = b * 2048 + c * TC;
  const int frow = lane & 15;
  const int fk = (lane >> 4) * 8;
  __shared__ __align__(16) ushort ybuf[64 * 524];
  __shared__ float Esh[8][64];
  __shared__ float partial[64][9];
  __shared__ float scale[64];

  {
    const int r = tid >> 3, c0 = (tid & 7) * 8;
    const float4 v0 = *(const float4*)(xc + (size_t)(r0 + r) * 640 + 576 + c0);
    const float4 v1 = *(const float4*)(xc + (size_t)(r0 + r) * 640 + 576 + c0 + 4);
    s16x8 hh, ll;
    cvt8(v0, v1, hh, ll);
    *(s16x8*)&ybuf[soff(0, r, c0)] = hh;
    *(s16x8*)&ybuf[soff(4608, r, c0)] = ll;
  }
  Esh[h][lane] = expf(-Sbuf[(size_t)((b * 8 + h) << 11) + c * TC + lane]);
  __syncthreads();

  const size_t cbase = ((size_t)((b * 8 + h) * NC + c)) << 12;
  s16x8 Bh[4][2], Bl[4][2];
  const ushort* hb = hin + cbase + lane * 8;
#pragma unroll
  for (int jt = 0; jt < 4; ++jt)
#pragma unroll
    for (int ks = 0; ks < 2; ++ks) {
      Bh[jt][ks] = *(const s16x8*)(hb + ((jt * 2 + ks) << 9));
      Bl[jt][ks] = *(const s16x8*)(hb + ((jt * 2 + ks) << 9) + HIOFF);
    }
  s16x8 Ah[4][2], Al[4][2];
#pragma unroll
  for (int it = 0; it < 4; ++it)
#pragma unroll
    for (int ks = 0; ks < 2; ++ks) {
      Ah[it][ks] = *(const s16x8*)&ybuf[soff(0, it * 16 + frow, ks * 32 + fk)];
      Al[it][ks] = *(const s16x8*)&ybuf[soff(4608, it * 16 + frow, ks * 32 + fk)];
    }

  f32x4 acc[4][4];
#pragma unroll
  for (int it = 0; it < 4; ++it)
#pragma unroll
    for (int jt = 0; jt < 4; ++jt) acc[it][jt] = (f32x4){0.f, 0.f, 0.f, 0.f};
#pragma unroll
  for (int it = 0; it < 4; ++it)
#pragma unroll
    for (int jt = 0; jt < 4; ++jt)
#pragma unroll
      for (int ks = 0; ks < 2; ++ks) {
        acc[it][jt] = MFMA(Ah[it][ks], Bh[jt][ks], acc[it][jt], 0, 0, 0);
        acc[it][jt] = MFMA(Ah[it][ks], Bl[jt][ks], acc[it][jt], 0, 0, 0);
        acc[it][jt] = MFMA(Al[it][ks], Bh[jt][ks], acc[it][jt], 0, 0, 0);
      }

  float rowsq[4][4];
#pragma unroll
  for (int it = 0; it < 4; ++it)
#pragma unroll
    for (int g = 0; g < 4; ++g) rowsq[it][g] = 0.f;
#pragma unroll
  for (int it = 0; it < 4; ++it)
#pragma unroll
    for (int jt = 0; jt < 4; ++jt) {
      const int gcol = h * 64 + jt * 16 + frow;
#pragma unroll
      for (int g = 0; g < 4; ++g) {
        const int row = it * 16 + (lane >> 4) * 4 + g;
        const float yl = xc[(size_t)(r0 + row) * 640 + gcol];
        const float zf = b2f(z[(size_t)(r0 + row) * 512 + gcol]);
        const float y = (yl + Esh[h][row] * acc[it][jt][g]) * siluf(zf);
        acc[it][jt][g] = y;
        rowsq[it][g] = fmaf(y, y, rowsq[it][g]);
      }
    }
#pragma unroll
  for (int it = 0; it < 4; ++it)
#pragma unroll
    for (int g = 0; g < 4; ++g) {
      float s = rowsq[it][g];
      s += __shfl_xor(s, 1);
      s += __shfl_xor(s, 2);
      s += __shfl_xor(s, 4);
      s += __shfl_xor(s, 8);
      if (frow == 0) partial[it * 16 + (lane >> 4) * 4 + g][h] = s;
    }
  __syncthreads();
  if (tid < 64) {
    float s = 0.f;
#pragma unroll
    for (int hh = 0; hh < 8; ++hh) s += partial[tid][hh];
    scale[tid] = rsqrtf(s * (1.f / 512.f) + 1e-5f);
  }
  __syncthreads();

  float wreg[4];
#pragma unroll
  for (int jt = 0; jt < 4; ++jt) wreg[jt] = normw[h * 64 + jt * 16 + frow];
#pragma unroll
  for (int it = 0; it < 4; ++it)
#pragma unroll
    for (int jt = 0; jt < 4; ++jt) {
      const int col = h * 64 + jt * 16 + frow;
#pragma unroll
      for (int g = 0; g < 4; ++g) {
        const int row = it * 16 + (lane >> 4) * 4 + g;
        ybuf[row * 524 + col] = f2b(acc[it][jt][g] * scale[row] * wreg[jt]);
      }
    }
  __syncthreads();
#pragma unroll
  for (int j = 0; j < 8; ++j) {
    const int flat = j * 4096 + tid * 8;
    const int row = flat >> 9, col = flat & 511;
    const ushort4 u0 = *(const ushort4*)&ybuf[row * 524 + col];
    const ushort4 u1 = *(const ushort4*)&ybuf[row * 524 + col + 4];
    s16x8 o;
    o[0] = (short)u0.x; o[1] = (short)u0.y; o[2] = (short)u0.z; o[3] = (short)u0.w;
    o[4] = (short)u1.x; o[5] = (short)u1.y; o[6] = (short)u1.z; o[7] = (short)u1.w;
    *(s16x8*)(ybf + (size_t)(r0 + row) * 512 + col) = o;
  }
}

__global__ __launch_bounds__(256) void k_hpart(
    const float* __restrict__ hf, const float* __restrict__ hb,
    float* __restrict__ part)
{
  const int g = blockIdx.x;
  const int b = g >> 5, seg = g & 31;
  const int m = threadIdx.x;
  float s = 0.f;
  for (int l = seg * 64; l < seg * 64 + 64; ++l) {
    const size_t idx = ((size_t)b * 2048 + l) * 256 + m;
    s += hf[idx] + hb[idx];
  }
  part[(size_t)g * 256 + m] = s;
}

__global__ __launch_bounds__(256) void k_hfinal(
    const float* __restrict__ part, float* __restrict__ H)
{
  const int b = blockIdx.x;
  const int m = threadIdx.x;
  float s = 0.f;
  for (int g = 0; g < 32; ++g) s += part[(size_t)(b * 32 + g) * 256 + m];
  H[b * 256 + m] = s * (1.f / 2048.f);
}

extern "C" void kernel_launch(void* const* d_in, const int* in_sizes, int n_in,
                              void* d_out, int out_size, void* d_ws, size_t ws_size,
                              hipStream_t stream) {
  const float* x_in = (const float*)d_in[0];
  const float* Win[2]    = {(const float*)d_in[1],  (const float*)d_in[9]};
  const float* Wconv[2]  = {(const float*)d_in[2],  (const float*)d_in[10]};
  const float* bconv[2]  = {(const float*)d_in[3],  (const float*)d_in[11]};
  const float* dtbias[2] = {(const float*)d_in[4],  (const float*)d_in[12]};
  const float* Alog[2]   = {(const float*)d_in[5],  (const float*)d_in[13]};
  const float* Dpar[2]   = {(const float*)d_in[6],  (const float*)d_in[14]};
  const float* normw[2]  = {(const float*)d_in[7],  (const float*)d_in[15]};
  const float* Wout[2]   = {(const float*)d_in[8],  (const float*)d_in[16]};

  float* ws = (float*)d_ws;
  ushort* zb    = (ushort*)ws;                       // 16384x512 bf16
  ushort* xbcb  = (ushort*)(ws + 4194304);           // 16384x640 bf16 (conv in)
  ushort* ybf   = xbcb;                              // reuse after conv
  ushort* hinp  = (ushort*)(ws + 9437184);           // packed hi/lo planes
  float* xc      = ws + 17825792;                    // 10485760
  float* dtraw   = ws + 28311552;                    // 131072
  float* dtb     = dtraw + 131072;
  float* dab     = dtb + 131072;
  float* Sbuf    = dab + 131072;                     // 131072
  float* xA      = Sbuf + 131072;                    // 4194304
  float* xB      = xA + 4194304;                     // 4194304
  float* part    = xB + 4194304;                     // 65536 (PT in first 2048)

  float* hF = (float*)d_out;
  float* hB = hF + (size_t)8 * 2048 * 256;
  float* Hm = hB + (size_t)8 * 2048 * 256;

  const float* cur = x_in;
  for (int layer = 0; layer < 4; ++layer) {
    float* nxt = (layer == 0) ? xA : (layer == 1) ? xB : (layer == 2) ? xA : nullptr;
    for (int dir = 0; dir < 2; ++dir) {
      const float* Wi = Win[dir]    + (size_t)layer * 1160 * 256;
      const float* Wc = Wconv[dir]  + (size_t)layer * 640 * 4;
      const float* bc = bconv[dir]  + (size_t)layer * 640;
      const float* db = dtbias[dir] + (size_t)layer * 8;
      const float* Al = Alog[dir]   + (size_t)layer * 8;
      const float* Dl = Dpar[dir]   + (size_t)layer * 8;
      const float* nw = normw[dir]  + (size_t)layer * 512;
      const float* Wo = Wout[dir]   + (size_t)layer * 256 * 512;

      k_gemmb<<<dim3(128, 10), 256, 0, stream>>>(cur, 256, dir, Wi, 1160, 256,
                                                 zb, xbcb, dtraw);
      k_dt<<<512, 256, 0, stream>>>(dtraw, db, Al, dtb, dab);
      k_conv<<<dim3(10, 512), 256, 0, stream>>>(xbcb, Wc, bc, xc);
      k_scan1<<<2048, 256, 0, stream>>>(xc, dtb, dab, Dl, hinp, Sbuf, part);
      k_scan2<<<256, 256, 0, stream>>>(hinp, part);
      k_scan3f<<<256, 512, 0, stream>>>(xc, zb, hinp, Sbuf, nw, ybf);
      float* outp;
      int accf;
      if (layer < 3) { outp = nxt; accf = dir; }
      else           { outp = dir ? hB : hF; accf = 0; }
      k_gemmo<<<dim3(128, 2), 256, 0, stream>>>(ybf, 512, Wo, 256, 512,
                                                outp, dir, accf);
    }
    cur = nxt;
  }
  k_hpart<<<256, 256, 0, stream>>>(hF, hB, part);
  k_hfinal<<<8, 256, 0, stream>>>(part, Hm);
}

// Round 7
// 1331.917 us; speedup vs baseline: 6.1291x; 1.0432x over previous
//
#include <hip/hip_runtime.h>
#include <math.h>

// MicroEncoder: 4-layer bidirectional Mamba2.
// B=8, L=2048, D_MODEL=256, D_INNER=512, NHEADS=8, HEADDIM=64, D_STATE=64,
// CONV_DIM=640, D_IN_PROJ=1160.
// Round 7: bf16-everywhere GEMM inputs. Weights and activations pre-rounded
// to bf16 ONCE (bit-identical to the in-kernel rounding they replace):
//  - k_cvt converts Win/Wout (all layers+dirs) and x_in at launch start.
//  - k_gemmb stages bf16 A/W directly (no VALU cvt in the K-loop); dt/dA
//    (softplus) fused into its by==9 epilogue -> k_dt kernel eliminated.
//  - k_gemmo emits the next layer's bf16 activation from its accumulate
//    epilogue (fp32 store skipped for that path).
// scan pipeline unchanged from round 6.

#define TC 64
#define NC 32
#define SPITCH 72
#define HIOFF 8388608   // ushort offset of the lo plane in packed hin

typedef __attribute__((ext_vector_type(4))) float f32x4;
typedef __attribute__((ext_vector_type(8))) short s16x8;

#define MFMA __builtin_amdgcn_mfma_f32_16x16x32_bf16

__device__ __forceinline__ float siluf(float x) { return x / (1.f + expf(-x)); }

// fp32 -> bf16 round-to-nearest-even (finite inputs)
__device__ __forceinline__ ushort f2b(float f) {
  union { float f; uint u; } v; v.f = f;
  return (ushort)((v.u + 0x7FFFu + ((v.u >> 16) & 1u)) >> 16);
}
__device__ __forceinline__ float b2f(ushort u) {
  union { uint u; float f; } v; v.u = ((uint)u) << 16; return v.f;
}
__device__ __forceinline__ int swz(int r, int c) { return c ^ (r & 3) ^ ((r >> 2) & 3); }

// scan3f LDS tile addressing (pitch-72)
__device__ __forceinline__ int soff(int base, int r, int cc) {
  return base + r * SPITCH + ((((cc >> 3) ^ (r & 7) ^ ((r >> 3) & 7)) << 3) | (cc & 7));
}

// scan1 tile addressing: pitch-64 ushort rows, 8-elem (16B) chunks XOR-swizzled
__device__ __forceinline__ int toff(int base, int r, int cc) {
  return base + r * 64 + ((((cc >> 3) ^ (r & 7)) << 3) | (cc & 7));
}

__device__ __forceinline__ void cvt8(const float4 v0, const float4 v1, s16x8& hh, s16x8& ll) {
  const float a[8] = {v0.x, v0.y, v0.z, v0.w, v1.x, v1.y, v1.z, v1.w};
#pragma unroll
  for (int e = 0; e < 8; ++e) {
    const ushort hb = f2b(a[e]);
    hh[e] = (short)hb;
    ll[e] = (short)f2b(a[e] - b2f(hb));
  }
}

// stage 16 fp32 -> hi/lo bf16 planes at (r, c0..c0+15), toff layout
__device__ __forceinline__ void stage16t(ushort* tiles, const float* src,
                                         int bh_, int bl_, int r, int c0) {
  const float4 v0 = *(const float4*)(src + c0);
  const float4 v1 = *(const float4*)(src + c0 + 4);
  const float4 v2 = *(const float4*)(src + c0 + 8);
  const float4 v3 = *(const float4*)(src + c0 + 12);
  s16x8 h0, l0, h1, l1;
  cvt8(v0, v1, h0, l0);
  cvt8(v2, v3, h1, l1);
  *(s16x8*)&tiles[toff(bh_, r, c0)]     = h0;
  *(s16x8*)&tiles[toff(bl_, r, c0)]     = l0;
  *(s16x8*)&tiles[toff(bh_, r, c0 + 8)] = h1;
  *(s16x8*)&tiles[toff(bl_, r, c0 + 8)] = l1;
}

// fp32 -> bf16 bulk conversion (8 elems/thread)
__global__ __launch_bounds__(256) void k_cvt(
    const float* __restrict__ src, ushort* __restrict__ dst, int n8)
{
  const int i = blockIdx.x * 256 + threadIdx.x;
  if (i >= n8) return;
  const float4 v0 = *(const float4*)(src + (size_t)i * 8);
  const float4 v1 = *(const float4*)(src + (size_t)i * 8 + 4);
  s16x8 h;
#pragma unroll
  for (int e = 0; e < 4; ++e) h[e] = (short)f2b(((const float*)&v0)[e]);
#pragma unroll
  for (int e = 0; e < 4; ++e) h[e + 4] = (short)f2b(((const float*)&v1)[e]);
  *(s16x8*)(dst + (size_t)i * 8) = h;
}

// ---------------------------------------------------------------------------
// in_proj GEMM: C = A(bf16, optional row reversal) @ W(bf16)^T.
// Epilogue: z (bf16) / xBC (bf16) / fused dt: softplus(+bias) -> dtb, dab.
// ---------------------------------------------------------------------------
__global__ __launch_bounds__(256) void k_gemmb(
    const ushort* __restrict__ A, int arev,
    const ushort* __restrict__ W, int N, int K,
    ushort* __restrict__ zb, ushort* __restrict__ xbc,
    const float* __restrict__ dt_bias, const float* __restrict__ A_log,
    float* __restrict__ dtb, float* __restrict__ dab)
{
  __shared__ __align__(16) ushort lds[17408];
  const int tid = threadIdx.x;
  const int lane = tid & 63;
  const int wid = tid >> 6;
  const int wr = wid >> 1, wc = wid & 1;
  const int m0 = blockIdx.x * 128, n0 = blockIdx.y * 128;

  const int tr = tid >> 1;
  const int th = tid & 1;
  const int gm = m0 + tr;
  const int bb = gm >> 11, tt = gm & 2047;
  const int tphys = arev ? (2047 - tt) : tt;
  const ushort* Arow = A + (size_t)((bb << 11) + tphys) * 256 + th * 16;
  const int wn = n0 + tr;
  const ushort* Wrow = (wn < N) ? (W + (size_t)wn * K + th * 16) : nullptr;

  const int asw0 = tr * 32 + swz(tr, th * 2) * 8;
  const int asw1 = tr * 32 + swz(tr, th * 2 + 1) * 8;

  f32x4 acc[4][4];
#pragma unroll
  for (int i = 0; i < 4; ++i)
#pragma unroll
    for (int j = 0; j < 4; ++j) acc[i][j] = (f32x4){0.f, 0.f, 0.f, 0.f};

  int aoff[4], boff[4];
#pragma unroll
  for (int f = 0; f < 4; ++f) {
    const int ar = wr * 64 + f * 16 + (lane & 15);
    aoff[f] = ar * 32 + swz(ar, lane >> 4) * 8;
    const int br = wc * 64 + f * 16 + (lane & 15);
    boff[f] = 4096 + br * 32 + swz(br, lane >> 4) * 8;
  }

  const s16x8 zz = (s16x8){0, 0, 0, 0, 0, 0, 0, 0};
  s16x8 a0 = *(const s16x8*)(Arow);
  s16x8 a1 = *(const s16x8*)(Arow + 8);
  s16x8 b0 = zz, b1 = zz;
  if (Wrow) {
    b0 = *(const s16x8*)(Wrow);
    b1 = *(const s16x8*)(Wrow + 8);
  }

  for (int k0 = 0; k0 < K; k0 += 32) {
    __syncthreads();
    *(s16x8*)&lds[asw0] = a0;
    *(s16x8*)&lds[asw1] = a1;
    *(s16x8*)&lds[4096 + asw0] = b0;
    *(s16x8*)&lds[4096 + asw1] = b1;
    __syncthreads();
    if (k0 + 32 < K) {
      a0 = *(const s16x8*)(Arow + k0 + 32);
      a1 = *(const s16x8*)(Arow + k0 + 40);
      if (Wrow) {
        b0 = *(const s16x8*)(Wrow + k0 + 32);
        b1 = *(const s16x8*)(Wrow + k0 + 40);
      }
    }
    s16x8 af[4], bf[4];
#pragma unroll
    for (int f = 0; f < 4; ++f) {
      af[f] = *(const s16x8*)&lds[aoff[f]];
      bf[f] = *(const s16x8*)&lds[boff[f]];
    }
#pragma unroll
    for (int i = 0; i < 4; ++i)
#pragma unroll
      for (int j = 0; j < 4; ++j)
        acc[i][j] = MFMA(af[i], bf[j], acc[i][j], 0, 0, 0);
  }

  const int by = blockIdx.y;
  if (by == 9) {
    // fused dt: cols 1152..1159 -> softplus(+bias), dA
    if (wc == 0 && (lane & 15) < 8) {
      const int cl = lane & 15;
      const float bias = dt_bias[cl];
      const float eAl = expf(A_log[cl]);
#pragma unroll
      for (int i = 0; i < 4; ++i) {
        const int r = m0 + wr * 64 + i * 16 + (lane >> 4) * 4;
#pragma unroll
        for (int g = 0; g < 4; ++g) {
          const float v = acc[i][0][g] + bias;
          const float sp = (v > 20.f) ? v : log1pf(expf(v));
          dtb[(size_t)(r + g) * 8 + cl] = sp;
          dab[(size_t)(r + g) * 8 + cl] = sp * eAl;
        }
      }
    }
    return;
  }
  __syncthreads();
#pragma unroll
  for (int i = 0; i < 4; ++i) {
    const int r = wr * 64 + i * 16 + (lane >> 4) * 4;
#pragma unroll
    for (int j = 0; j < 4; ++j) {
      const int ccol = wc * 64 + j * 16 + (lane & 15);
#pragma unroll
      for (int g = 0; g < 4; ++g)
        lds[(r + g) * 136 + ccol] = f2b(acc[i][j][g]);
    }
  }
  __syncthreads();
  const int rr = tid >> 1, hf = tid & 1;
  const int grow = m0 + rr;
  ushort* dst; int stride, colb;
  if (by < 4) { dst = zb;  stride = 512; colb = n0; }
  else        { dst = xbc; stride = 640; colb = n0 - 512; }
  ushort* dp = dst + (size_t)grow * stride + colb + hf * 64;
  const ushort* sp = &lds[rr * 136 + hf * 64];
#pragma unroll
  for (int q = 0; q < 8; ++q)
    *(s16x8*)(dp + q * 8) = *(const s16x8*)(sp + q * 8);
}

// ---------------------------------------------------------------------------
// out_proj GEMM: Cout = A(bf16) @ W(bf16)^T, fp32 out with optional reversed
// row write / accumulate. If dupb != null, also emits f2b(result) (and when
// accumulating, skips the now-dead fp32 store).
// ---------------------------------------------------------------------------
__global__ __launch_bounds__(256) void k_gemmo(
    const ushort* __restrict__ A, int lda,
    const ushort* __restrict__ W, int N, int K,
    float* __restrict__ Cout, ushort* __restrict__ dupb,
    int crev, int accflag)
{
  __shared__ __align__(16) ushort lds[8192];
  const int tid = threadIdx.x;
  const int lane = tid & 63;
  const int wid = tid >> 6;
  const int wr = wid >> 1, wc = wid & 1;
  const int m0 = blockIdx.x * 128, n0 = blockIdx.y * 128;

  const int tr = tid >> 1;
  const int th = tid & 1;
  const int gm = m0 + tr;
  const ushort* Arow = A + (size_t)gm * lda + th * 16;
  const int wn = n0 + tr;
  const ushort* Wrow = (wn < N) ? (W + (size_t)wn * K + th * 16) : nullptr;

  const int asw0 = tr * 32 + swz(tr, th * 2) * 8;
  const int asw1 = tr * 32 + swz(tr, th * 2 + 1) * 8;

  f32x4 acc[4][4];
#pragma unroll
  for (int i = 0; i < 4; ++i)
#pragma unroll
    for (int j = 0; j < 4; ++j) acc[i][j] = (f32x4){0.f, 0.f, 0.f, 0.f};

  int aoff[4], boff[4];
#pragma unroll
  for (int f = 0; f < 4; ++f) {
    const int ar = wr * 64 + f * 16 + (lane & 15);
    aoff[f] = ar * 32 + swz(ar, lane >> 4) * 8;
    const int br = wc * 64 + f * 16 + (lane & 15);
    boff[f] = 4096 + br * 32 + swz(br, lane >> 4) * 8;
  }

  const s16x8 zz = (s16x8){0, 0, 0, 0, 0, 0, 0, 0};
  s16x8 a0 = *(const s16x8*)(Arow);
  s16x8 a1 = *(const s16x8*)(Arow + 8);
  s16x8 b0 = zz, b1 = zz;
  if (Wrow) {
    b0 = *(const s16x8*)(Wrow);
    b1 = *(const s16x8*)(Wrow + 8);
  }

  for (int k0 = 0; k0 < K; k0 += 32) {
    __syncthreads();
    *(s16x8*)&lds[asw0] = a0;
    *(s16x8*)&lds[asw1] = a1;
    *(s16x8*)&lds[4096 + asw0] = b0;
    *(s16x8*)&lds[4096 + asw1] = b1;
    __syncthreads();
    if (k0 + 32 < K) {
      a0 = *(const s16x8*)(Arow + k0 + 32);
      a1 = *(const s16x8*)(Arow + k0 + 40);
      if (Wrow) {
        b0 = *(const s16x8*)(Wrow + k0 + 32);
        b1 = *(const s16x8*)(Wrow + k0 + 40);
      }
    }
    s16x8 af[4], bf[4];
#pragma unroll
    for (int f = 0; f < 4; ++f) {
      af[f] = *(const s16x8*)&lds[aoff[f]];
      bf[f] = *(const s16x8*)&lds[boff[f]];
    }
#pragma unroll
    for (int i = 0; i < 4; ++i)
#pragma unroll
      for (int j = 0; j < 4; ++j)
        acc[i][j] = MFMA(af[i], bf[j], acc[i][j], 0, 0, 0);
  }

#pragma unroll
  for (int i = 0; i < 4; ++i) {
    const int rb = m0 + wr * 64 + i * 16 + (lane >> 4) * 4;
#pragma unroll
    for (int g = 0; g < 4; ++g) {
      const int row = rb + g;
      const int b2_ = row >> 11, t2 = row & 2047;
      const int tw = crev ? (2047 - t2) : t2;
      const size_t rbase = ((size_t)((b2_ << 11) + tw)) * 256 + n0 + wc * 64 + (lane & 15);
      float* crow = Cout + rbase;
#pragma unroll
      for (int j = 0; j < 4; ++j) {
        float v = acc[i][j][g];
        if (accflag) v += crow[j * 16];
        if (dupb) dupb[rbase + j * 16] = f2b(v);
        if (!(accflag && dupb)) crow[j * 16] = v;
      }
    }
  }
}

// causal depthwise conv (k=4, bf16 in) + bias + silu -> fp32 xc  (unchanged)
__global__ __launch_bounds__(256) void k_conv(
    const ushort* __restrict__ xbc, const float* __restrict__ Wc,
    const float* __restrict__ bc, float* __restrict__ xc)
{
  const int t = threadIdx.x;
  const int cg = blockIdx.x * 8 + (t & 7);
  const int rowt = blockIdx.y * 32 + (t >> 3);
  const int l = rowt & 2047;
  const int c0 = cg * 8;
  float4 wv[8];
  const float4* wp = (const float4*)(Wc + c0 * 4);
#pragma unroll
  for (int e = 0; e < 8; ++e) wv[e] = wp[e];
  float acc[8];
#pragma unroll
  for (int e = 0; e < 8; ++e) acc[e] = bc[c0 + e];
#pragma unroll
  for (int k = 0; k < 4; ++k) {
    const int lt = l - 3 + k;
    if (lt < 0) continue;
    const s16x8 v = *(const s16x8*)(xbc + (size_t)(rowt - 3 + k) * 640 + c0);
#pragma unroll
    for (int e = 0; e < 8; ++e)
      acc[e] = fmaf(b2f((ushort)v[e]), ((const float*)&wv[e])[k], acc[e]);
  }
  float* op = xc + (size_t)rowt * 640 + c0;
  float4 o0, o1;
  o0.x = siluf(acc[0]); o0.y = siluf(acc[1]); o0.z = siluf(acc[2]); o0.w = siluf(acc[3]);
  o1.x = siluf(acc[4]); o1.y = siluf(acc[5]); o1.z = siluf(acc[6]); o1.w = siluf(acc[7]);
  *(float4*)op = o0; *(float4*)(op + 4) = o1;
}

// ---------------------------------------------------------------------------
// Chunked SSD pass 1 (split-bf16 MFMA, transposed-operand; unchanged r6).
// ---------------------------------------------------------------------------
__global__ __launch_bounds__(256) void k_scan1(
    float* __restrict__ xc, const float* __restrict__ dt,
    const float* __restrict__ dtA, const float* __restrict__ Dp,
    ushort* __restrict__ hin, float* __restrict__ Sbuf,
    float* __restrict__ PT)
{
  const int c = blockIdx.x & (NC - 1);
  const int bhi = blockIdx.x >> 5;
  const int b = bhi >> 3, h = bhi & 7;
  const int tid = threadIdx.x;
  const int lane = tid & 63;
  const int wid = tid >> 6;
  const int r0 = b * 2048 + c * TC;
  const int hbase = h * 64;
  __shared__ __align__(16) ushort tiles[24576];
  __shared__ float Ssh[64], dtsh[64], vsh[64];
  enum { PCH = 0, PCL = 4096, PBH = 8192, PBL = 12288, PXH = 16384, PXL = 20480 };

  if (tid < 64) {
    float a = dtA[(size_t)(r0 + tid) * 8 + h];
    const float d = dt[(size_t)(r0 + tid) * 8 + h];
#pragma unroll
    for (int off = 1; off < 64; off <<= 1) {
      const float t = __shfl_up(a, off);
      if (tid >= off) a += t;
    }
    const float slast = __shfl(a, 63);
    Ssh[tid] = a;
    dtsh[tid] = d;
    vsh[tid] = expf(a - slast) * d;
    Sbuf[(size_t)bhi * 2048 + c * TC + tid] = a;
    if (tid == 63) PT[bhi * NC + c] = expf(-slast);
  }
  {
    const int r = tid >> 2, c0 = (tid & 3) * 16;
    const float* rowp = xc + (size_t)(r0 + r) * 640;
    stage16t(tiles, rowp + 512, PBH, PBL, r, c0);
    stage16t(tiles, rowp + 576, PCH, PCL, r, c0);
    stage16t(tiles, rowp + hbase, PXH, PXL, r, c0);
  }
  __syncthreads();   // sync1

  const int ib = wid * 16;
  const int frow = lane & 15;
  const int fkc = lane >> 4;

  const int tp = tid >> 2;
  const int tj0 = (tid & 3) * 16;
  s16x8 xtr[4], btr[4];
#pragma unroll
  for (int cc = 0; cc < 2; ++cc) {
    const int j0 = tj0 + cc * 8;
    s16x8 vh, vl, wh, wl;
#pragma unroll
    for (int e = 0; e < 8; ++e) {
      const int ax = toff(PXH, j0 + e, tp);
      vh[e] = (short)tiles[ax];
      vl[e] = (short)tiles[ax + 4096];
      const int ab = toff(PBH, j0 + e, tp);
      wh[e] = (short)tiles[ab];
      wl[e] = (short)tiles[ab + 4096];
    }
    xtr[cc] = vh; xtr[cc + 2] = vl;
    btr[cc] = wh; btr[cc + 2] = wl;
  }

  s16x8 pah[2], pal[2];
#pragma unroll
  for (int ks = 0; ks < 2; ++ks) {
    pah[ks] = *(const s16x8*)&tiles[toff(PCH, ib + frow, ks * 32 + fkc * 8)];
    pal[ks] = *(const s16x8*)&tiles[toff(PCL, ib + frow, ks * 32 + fkc * 8)];
  }
  f32x4 acc[4];
#pragma unroll
  for (int jt = 0; jt < 4; ++jt) acc[jt] = (f32x4){0.f, 0.f, 0.f, 0.f};
#pragma unroll
  for (int jt = 0; jt < 4; ++jt) {
#pragma unroll
    for (int ks = 0; ks < 2; ++ks) {
      const s16x8 tbh = *(const s16x8*)&tiles[toff(PBH, jt * 16 + frow, ks * 32 + fkc * 8)];
      const s16x8 tbl = *(const s16x8*)&tiles[toff(PBL, jt * 16 + frow, ks * 32 + fkc * 8)];
      acc[jt] = MFMA(pah[ks], tbh, acc[jt], 0, 0, 0);
      acc[jt] = MFMA(pah[ks], tbl, acc[jt], 0, 0, 0);
      acc[jt] = MFMA(pal[ks], tbh, acc[jt], 0, 0, 0);
    }
  }
  float Si[4];
#pragma unroll
  for (int g = 0; g < 4; ++g) Si[g] = Ssh[ib + fkc * 4 + g];
#pragma unroll
  for (int jt = 0; jt < 4; ++jt) {
    const int j = jt * 16 + frow;
    const float Sj = Ssh[j], dj = dtsh[j];
#pragma unroll
    for (int g = 0; g < 4; ++g) {
      const int i = ib + fkc * 4 + g;
      const float w = (j <= i) ? __expf(Sj - Si[g]) * dj : 0.f;
      const float gt = acc[jt][g] * w;
      const ushort gh = f2b(gt);
      tiles[toff(PCH, i, j)] = gh;
      tiles[toff(PCL, i, j)] = f2b(gt - b2f(gh));
    }
  }
  __syncthreads();   // sync2

#pragma unroll
  for (int cc = 0; cc < 2; ++cc) {
    *(s16x8*)&tiles[toff(PXH, tp, tj0 + cc * 8)] = xtr[cc];
    *(s16x8*)&tiles[toff(PXL, tp, tj0 + cc * 8)] = xtr[cc + 2];
    *(s16x8*)&tiles[toff(PBH, tp, tj0 + cc * 8)] = btr[cc];
    *(s16x8*)&tiles[toff(PBL, tp, tj0 + cc * 8)] = btr[cc + 2];
  }
  __syncthreads();   // sync3

  s16x8 gah[2], gal[2];
#pragma unroll
  for (int ks = 0; ks < 2; ++ks) {
    gah[ks] = *(const s16x8*)&tiles[toff(PCH, ib + frow, ks * 32 + fkc * 8)];
    gal[ks] = *(const s16x8*)&tiles[toff(PCL, ib + frow, ks * 32 + fkc * 8)];
  }
  const float dpv = Dp[h];
#pragma unroll
  for (int pt = 0; pt < 4; ++pt) {
    f32x4 accY = (f32x4){0.f, 0.f, 0.f, 0.f};
#pragma unroll
    for (int ks = 0; ks < 2; ++ks) {
      const s16x8 xh = *(const s16x8*)&tiles[toff(PXH, pt * 16 + frow, ks * 32 + fkc * 8)];
      const s16x8 xl = *(const s16x8*)&tiles[toff(PXL, pt * 16 + frow, ks * 32 + fkc * 8)];
      accY = MFMA(gah[ks], xh, accY, 0, 0, 0);
      accY = MFMA(gah[ks], xl, accY, 0, 0, 0);
      accY = MFMA(gal[ks], xh, accY, 0, 0, 0);
    }
    const int p = pt * 16 + frow;
#pragma unroll
    for (int g = 0; g < 4; ++g) {
      const int i = ib + fkc * 4 + g;
      float* ap = xc + (size_t)(r0 + i) * 640 + hbase + p;
      *ap = accY[g] + dpv * (*ap);
    }
  }

  s16x8 xvh[2], xvl[2];
#pragma unroll
  for (int ks = 0; ks < 2; ++ks) {
    const int J0 = ks * 32 + fkc * 8;
    const s16x8 xh = *(const s16x8*)&tiles[toff(PXH, ib + frow, J0)];
    const s16x8 xl = *(const s16x8*)&tiles[toff(PXL, ib + frow, J0)];
#pragma unroll
    for (int e = 0; e < 8; ++e) {
      const float xf = (b2f((ushort)xh[e]) + b2f((ushort)xl[e])) * vsh[J0 + e];
      const ushort nh = f2b(xf);
      xvh[ks][e] = (short)nh;
      xvl[ks][e] = (short)f2b(xf - b2f(nh));
    }
  }
  ushort* hbp = hin + (((size_t)(bhi * NC + c)) << 12);
#pragma unroll
  for (int nt = 0; nt < 4; ++nt) {
    f32x4 accC = (f32x4){0.f, 0.f, 0.f, 0.f};
#pragma unroll
    for (int ks = 0; ks < 2; ++ks) {
      const s16x8 tbh = *(const s16x8*)&tiles[toff(PBH, nt * 16 + frow, ks * 32 + fkc * 8)];
      const s16x8 tbl = *(const s16x8*)&tiles[toff(PBL, nt * 16 + frow, ks * 32 + fkc * 8)];
      accC = MFMA(xvh[ks], tbh, accC, 0, 0, 0);
      accC = MFMA(xvh[ks], tbl, accC, 0, 0, 0);
      accC = MFMA(xvl[ks], tbh, accC, 0, 0, 0);
    }
    const int n = nt * 16 + frow;
    const int kss = nt >> 1;
    const int nlo3 = (n >> 3) & 3, ne = n & 7;
#pragma unroll
    for (int g = 0; g < 4; ++g) {
      const int plo = fkc * 4 + g;
      const int off = ((wid * 2 + kss) << 9) + (nlo3 * 16 + plo) * 8 + ne;
      const float v = accC[g];
      const ushort vh = f2b(v);
      hbp[off] = vh;
      hbp[off + HIOFF] = f2b(v - b2f(vh));
    }
  }
}

// Pass 2: cross-chunk state propagation (unchanged).
__global__ __launch_bounds__(256) void k_scan2(
    ushort* __restrict__ hin, const float* __restrict__ PT)
{
  const int bh = blockIdx.x >> 2, jt = blockIdx.x & 3;
  const int t = threadIdx.x;
  float hv[4] = {0.f, 0.f, 0.f, 0.f};
  for (int c = 0; c < NC; ++c) {
    ushort* base = hin + (((size_t)(bh * NC + c)) << 12) + (jt << 10) + t * 4;
    const float pt = PT[bh * NC + c];
    const ushort4 uh = *(const ushort4*)base;
    const ushort4 ul = *(const ushort4*)(base + HIOFF);
    const float vals[4] = {b2f(uh.x) + b2f(ul.x), b2f(uh.y) + b2f(ul.y),
                           b2f(uh.z) + b2f(ul.z), b2f(uh.w) + b2f(ul.w)};
    ushort4 nh, nl;
    ushort* nhp = (ushort*)&nh; ushort* nlp = (ushort*)&nl;
#pragma unroll
    for (int k = 0; k < 4; ++k) {
      const float old = hv[k];
      hv[k] = fmaf(pt, hv[k], vals[k]);
      const ushort oh = f2b(old);
      nhp[k] = oh;
      nlp[k] = f2b(old - b2f(oh));
    }
    *(ushort4*)base = nh;
    *(ushort4*)(base + HIOFF) = nl;
  }
}

// ---------------------------------------------------------------------------
// Fused pass 3 (unchanged from round 5/6).
// ---------------------------------------------------------------------------
__global__ __launch_bounds__(512) void k_scan3f(
    const float* __restrict__ xc, const ushort* __restrict__ z,
    const ushort* __restrict__ hin, const float* __restrict__ Sbuf,
    const float* __restrict__ normw, ushort* __restrict__ ybf)
{
  const int c = blockIdx.x & (NC - 1);
  const int b = blockIdx.x >> 5;
  const int tid = threadIdx.x;
  const int lane = tid & 63;
  const int h = tid >> 6;
  const int r0 = b * 2048 + c * TC;
  const int frow = lane & 15;
  const int fk = (lane >> 4) * 8;
  __shared__ __align__(16) ushort ybuf[64 * 524];
  __shared__ float Esh[8][64];
  __shared__ float partial[64][9];
  __shared__ float scale[64];

  {
    const int r = tid >> 3, c0 = (tid & 7) * 8;
    const float4 v0 = *(const float4*)(xc + (size_t)(r0 + r) * 640 + 576 + c0);
    const float4 v1 = *(const float4*)(xc + (size_t)(r0 + r) * 640 + 576 + c0 + 4);
    s16x8 hh, ll;
    cvt8(v0, v1, hh, ll);
    *(s16x8*)&ybuf[soff(0, r, c0)] = hh;
    *(s16x8*)&ybuf[soff(4608, r, c0)] = ll;
  }
  Esh[h][lane] = expf(-Sbuf[(size_t)((b * 8 + h) << 11) + c * TC + lane]);
  __syncthreads();

  const size_t cbase = ((size_t)((b * 8 + h) * NC + c)) << 12;
  s16x8 Bh[4][2], Bl[4][2];
  const ushort* hb = hin + cbase + lane * 8;
#pragma unroll
  for (int jt = 0; jt < 4; ++jt)
#pragma unroll
    for (int ks = 0; ks < 2; ++ks) {
      Bh[jt][ks] = *(const s16x8*)(hb + ((jt * 2 + ks) << 9));
      Bl[jt][ks] = *(const s16x8*)(hb + ((jt * 2 + ks) << 9) + HIOFF);
    }
  s16x8 Ah[4][2], Al[4][2];
#pragma unroll
  for (int it = 0; it < 4; ++it)
#pragma unroll
    for (int ks = 0; ks < 2; ++ks) {
      Ah[it][ks] = *(const s16x8*)&ybuf[soff(0, it * 16 + frow, ks * 32 + fk)];
      Al[it][ks] = *(const s16x8*)&ybuf[soff(4608, it * 16 + frow, ks * 32 + fk)];
    }

  f32x4 acc[4][4];
#pragma unroll
  for (int it = 0; it < 4; ++it)
#pragma unroll
    for (int jt = 0; jt < 4; ++jt) acc[it][jt] = (f32x4){0.f, 0.f, 0.f, 0.f};
#pragma unroll
  for (int it = 0; it < 4; ++it)
#pragma unroll
    for (int jt = 0; jt < 4; ++jt)
#pragma unroll
      for (int ks = 0; ks < 2; ++ks) {
        acc[it][jt] = MFMA(Ah[it][ks], Bh[jt][ks], acc[it][jt], 0, 0, 0);
        acc[it][jt] = MFMA(Ah[it][ks], Bl[jt][ks], acc[it][jt], 0, 0, 0);
        acc[it][jt] = MFMA(Al[it][ks], Bh[jt][ks], acc[it][jt], 0, 0, 0);
      }

  float rowsq[4][4];
#pragma unroll
  for (int it = 0; it < 4; ++it)
#pragma unroll
    for (int g = 0; g < 4; ++g) rowsq[it][g] = 0.f;
#pragma unroll
  for (int it = 0; it < 4; ++it)
#pragma unroll
    for (int jt = 0; jt < 4; ++jt) {
      const int gcol = h * 64 + jt * 16 + frow;
#pragma unroll
      for (int g = 0; g < 4; ++g) {
        const int row = it * 16 + (lane >> 4) * 4 + g;
        const float yl = xc[(size_t)(r0 + row) * 640 + gcol];
        const float zf = b2f(z[(size_t)(r0 + row) * 512 + gcol]);
        const float y = (yl + Esh[h][row] * acc[it][jt][g]) * siluf(zf);
        acc[it][jt][g] = y;
        rowsq[it][g] = fmaf(y, y, rowsq[it][g]);
      }
    }
#pragma unroll
  for (int it = 0; it < 4; ++it)
#pragma unroll
    for (int g = 0; g < 4; ++g) {
      float s = rowsq[it][g];
      s += __shfl_xor(s, 1);
      s += __shfl_xor(s, 2);
      s += __shfl_xor(s, 4);
      s += __shfl_xor(s, 8);
      if (frow == 0) partial[it * 16 + (lane >> 4) * 4 + g][h] = s;
    }
  __syncthreads();
  if (tid < 64) {
    float s = 0.f;
#pragma unroll
    for (int hh = 0; hh < 8; ++hh) s += partial[tid][hh];
    scale[tid] = rsqrtf(s * (1.f / 512.f) + 1e-5f);
  }
  __syncthreads();

  float wreg[4];
#pragma unroll
  for (int jt = 0; jt < 4; ++jt) wreg[jt] = normw[h * 64 + jt * 16 + frow];
#pragma unroll
  for (int it = 0; it < 4; ++it)
#pragma unroll
    for (int jt = 0; jt < 4; ++jt) {
      const int col = h * 64 + jt * 16 + frow;
#pragma unroll
      for (int g = 0; g < 4; ++g) {
        const int row = it * 16 + (lane >> 4) * 4 + g;
        ybuf[row * 524 + col] = f2b(acc[it][jt][g] * scale[row] * wreg[jt]);
      }
    }
  __syncthreads();
#pragma unroll
  for (int j = 0; j < 8; ++j) {
    const int flat = j * 4096 + tid * 8;
    const int row = flat >> 9, col = flat & 511;
    const ushort4 u0 = *(const ushort4*)&ybuf[row * 524 + col];
    const ushort4 u1 = *(const ushort4*)&ybuf[row * 524 + col + 4];
    s16x8 o;
    o[0] = (short)u0.x; o[1] = (short)u0.y; o[2] = (short)u0.z; o[3] = (short)u0.w;
    o[4] = (short)u1.x; o[5] = (short)u1.y; o[6] = (short)u1.z; o[7] = (short)u1.w;
    *(s16x8*)(ybf + (size_t)(r0 + row) * 512 + col) = o;
  }
}

__global__ __launch_bounds__(256) void k_hpart(
    const float* __restrict__ hf, const float* __restrict__ hb,
    float* __restrict__ part)
{
  const int g = blockIdx.x;
  const int b = g >> 5, seg = g & 31;
  const int m = threadIdx.x;
  float s = 0.f;
  for (int l = seg * 64; l < seg * 64 + 64; ++l) {
    const size_t idx = ((size_t)b * 2048 + l) * 256 + m;
    s += hf[idx] + hb[idx];
  }
  part[(size_t)g * 256 + m] = s;
}

__global__ __launch_bounds__(256) void k_hfinal(
    const float* __restrict__ part, float* __restrict__ H)
{
  const int b = blockIdx.x;
  const int m = threadIdx.x;
  float s = 0.f;
  for (int g = 0; g < 32; ++g) s += part[(size_t)(b * 32 + g) * 256 + m];
  H[b * 256 + m] = s * (1.f / 2048.f);
}

extern "C" void kernel_launch(void* const* d_in, const int* in_sizes, int n_in,
                              void* d_out, int out_size, void* d_ws, size_t ws_size,
                              hipStream_t stream) {
  const float* x_in = (const float*)d_in[0];
  const float* Win[2]    = {(const float*)d_in[1],  (const float*)d_in[9]};
  const float* Wconv[2]  = {(const float*)d_in[2],  (const float*)d_in[10]};
  const float* bconv[2]  = {(const float*)d_in[3],  (const float*)d_in[11]};
  const float* dtbias[2] = {(const float*)d_in[4],  (const float*)d_in[12]};
  const float* Alog[2]   = {(const float*)d_in[5],  (const float*)d_in[13]};
  const float* Dpar[2]   = {(const float*)d_in[6],  (const float*)d_in[14]};
  const float* normw[2]  = {(const float*)d_in[7],  (const float*)d_in[15]};
  const float* Wout[2]   = {(const float*)d_in[8],  (const float*)d_in[16]};

  float* ws = (float*)d_ws;
  // layout (float offsets)
  ushort* zb    = (ushort*)ws;                        // 16384x512 bf16
  ushort* xbcb  = (ushort*)(ws + 4194304);            // 16384x640 bf16 (conv in)
  ushort* ybf   = xbcb;                               // alias after conv
  ushort* hinp  = (ushort*)(ws + 9437184);            // packed hi/lo planes
  float* xc      = ws + 17825792;                     // 10,485,760
  float* dtb     = ws + 28311552;                     // 131,072
  float* dab     = ws + 28442624;                     // 131,072
  float* Sbuf    = ws + 28573696;                     // 131,072
  float* acc32   = ws + 28704768;                     // 4,194,304 (fp32 inter-layer accum)
  ushort* xbf    = (ushort*)(ws + 32899072);          // 16384x256 bf16 activation
  float* part    = ws + 34996224;                     // 65,536 (PT in first 2048)
  ushort* Winb   = (ushort*)(ws + 35061760);          // 2 x 4 x 1160 x 256 bf16
  ushort* Woutb  = (ushort*)(ws + 36249600);          // 2 x 4 x 256 x 512 bf16
  // end: 36,773,888 floats = 147.1 MB

  float* hF = (float*)d_out;
  float* hB = hF + (size_t)8 * 2048 * 256;
  float* Hm = hB + (size_t)8 * 2048 * 256;

  // one-time bf16 conversions (bit-identical to the in-kernel rounding removed)
  k_cvt<<<580, 256, 0, stream>>>(Win[0], Winb, 148480);
  k_cvt<<<580, 256, 0, stream>>>(Win[1], Winb + 1187840, 148480);
  k_cvt<<<256, 256, 0, stream>>>(Wout[0], Woutb, 65536);
  k_cvt<<<256, 256, 0, stream>>>(Wout[1], Woutb + 524288, 65536);
  k_cvt<<<2048, 256, 0, stream>>>(x_in, xbf, 524288);

  for (int layer = 0; layer < 4; ++layer) {
    for (int dir = 0; dir < 2; ++dir) {
      const ushort* Wi = Winb + ((size_t)dir * 4 + layer) * 1160 * 256;
      const ushort* Wo = Woutb + ((size_t)dir * 4 + layer) * 256 * 512;
      const float* Wc = Wconv[dir]  + (size_t)layer * 640 * 4;
      const float* bc = bconv[dir]  + (size_t)layer * 640;
      const float* db = dtbias[dir] + (size_t)layer * 8;
      const float* Al = Alog[dir]   + (size_t)layer * 8;
      const float* Dl = Dpar[dir]   + (size_t)layer * 8;
      const float* nw = normw[dir]  + (size_t)layer * 512;

      k_gemmb<<<dim3(128, 10), 256, 0, stream>>>(xbf, dir, Wi, 1160, 256,
                                                 zb, xbcb, db, Al, dtb, dab);
      k_conv<<<dim3(10, 512), 256, 0, stream>>>(xbcb, Wc, bc, xc);
      k_scan1<<<2048, 256, 0, stream>>>(xc, dtb, dab, Dl, hinp, Sbuf, part);
      k_scan2<<<256, 256, 0, stream>>>(hinp, part);
      k_scan3f<<<256, 512, 0, stream>>>(xc, zb, hinp, Sbuf, nw, ybf);

      float* outp; ushort* dupb; int accf;
      if (layer < 3) {
        outp = acc32; accf = dir;
        dupb = dir ? xbf : nullptr;     // dir1: emit bf16 next-layer input
      } else {
        outp = dir ? hB : hF; accf = 0; dupb = nullptr;
      }
      k_gemmo<<<dim3(128, 2), 256, 0, stream>>>(ybf, 512, Wo, 256, 512,
                                                outp, dupb, dir, accf);
    }
  }
  k_hpart<<<256, 256, 0, stream>>>(hF, hB, part);
  k_hfinal<<<8, 256, 0, stream>>>(part, Hm);
}